// Round 4
// baseline (2658.617 us; speedup 1.0000x reference)
//
#include <hip/hip_runtime.h>
#include <math.h>

// Problem constants (fixed by reference setup)
#define NN 50000
#define EE 400000
#define CINV 32
#define KKEEP 25000          // ceil(0.5*N)
#define SEQL 5
#define HASH_BITS 20
#define HASH_SIZE (1u<<HASH_BITS)
#define HASH_MASK (HASH_SIZE-1u)
#define HEMPTY 0xFFFFFFFFu
#define PSB 196              // ceil(NN/256)

typedef float vf4 __attribute__((ext_vector_type(4)));

__device__ __forceinline__ float sigm(float x){ return 1.f/(1.f+__expf(-x)); }

// ---------------- merged init ----------------
__global__ void k_init(uint2* __restrict__ hash, unsigned* __restrict__ hist,
                       int* __restrict__ degcnt, int* __restrict__ diagint,
                       int* __restrict__ ts, int* __restrict__ cs,
                       int* __restrict__ fillc, int* __restrict__ minv,
                       unsigned* scal, unsigned long long* selp){
  int i = blockIdx.x*256 + threadIdx.x;
  if (i < (int)HASH_SIZE) hash[i] = make_uint2(HEMPTY, 0u);
  if (i < 4*65536) hist[i] = 0u;
  if (i < NN){ degcnt[i]=0; diagint[i]=0; ts[i]=0; cs[i]=0; fillc[i]=0; minv[i]=-1; }
  if (i == 0){ scal[0]=0u; scal[1]=0u; scal[3]=KKEEP; selp[0]=0ull; }
}

// ---------------- degcnt + hash build + mask-dtype detect ----------------
__global__ void k_phase2(const int* __restrict__ row, const int* __restrict__ col,
                         const int* __restrict__ mp, int* __restrict__ degcnt,
                         uint2* __restrict__ tab, unsigned* scal){
  int e = blockIdx.x*256 + threadIdx.x;
  if (e < EE){
    int c = col[e];
    atomicAdd(&degcnt[c], 1);
    unsigned key = (unsigned)row[e]*50000u + (unsigned)c;
    unsigned h = (key*2654435761u) >> (32-HASH_BITS);
    for(;;){
      unsigned old = atomicCAS(&tab[h].x, HEMPTY, key);
      if (old==HEMPTY || old==key){ atomicAdd(&tab[h].y, 1u); break; }
      h = (h+1)&HASH_MASK;
    }
  }
  if (e < NN/4){ if ((unsigned)mp[e] > 1u) atomicOr(&scal[1], 1u); }
}

// ---------------- prefix sum (indptr) + dinv0 ----------------
__global__ void k_psum1(const int* __restrict__ deg, int* __restrict__ part,
                        int* __restrict__ bsum, float* __restrict__ dinv){
  __shared__ int sc[256];
  int b = blockIdx.x, t = threadIdx.x, i = b*256+t;
  int v = (i<NN) ? deg[i] : 0;
  if (i < NN) dinv[i] = rsqrtf((float)v + 2.0f);
  sc[t] = v; __syncthreads();
  for (int o=1;o<256;o<<=1){
    int x = (t>=o) ? sc[t-o] : 0;
    __syncthreads();
    sc[t] += x;
    __syncthreads();
  }
  if (i < NN) part[i] = sc[t]-v;
  if (t == 255) bsum[b] = sc[255];
}
__global__ void k_psum2(const int* __restrict__ bsum, int* __restrict__ boff){
  __shared__ int sc[256];
  int t = threadIdx.x;
  int v = (t<PSB) ? bsum[t] : 0;
  sc[t] = v; __syncthreads();
  for (int o=1;o<256;o<<=1){
    int x = (t>=o) ? sc[t-o] : 0;
    __syncthreads();
    sc[t] += x;
    __syncthreads();
  }
  if (t < PSB) boff[t] = sc[t]-v;
}
__global__ void k_psum3(const int* __restrict__ part, const int* __restrict__ boff,
                        int* __restrict__ indptr){
  int i = blockIdx.x*256 + threadIdx.x;
  if (i < NN) indptr[i] = part[i] + boff[blockIdx.x];
  if (i == 0) indptr[NN] = EE;
}

// ---------------- csr fill + A^2 diag + mask compact ----------------
__global__ void k_phase4(const int* __restrict__ row, const int* __restrict__ col,
                         const int* __restrict__ indptr, int* __restrict__ fillc,
                         int* __restrict__ csr_r, const uint2* __restrict__ tab,
                         int* __restrict__ diagint, const void* __restrict__ mp,
                         unsigned* scal, int* __restrict__ mlist, int* __restrict__ minv){
  int idx = blockIdx.x*256 + threadIdx.x;
  if (idx < EE){
    int r = row[idx], c = col[idx];
    int pos = indptr[c] + atomicAdd(&fillc[c], 1);
    csr_r[pos] = r;
    unsigned rkey = (unsigned)c*50000u + (unsigned)r;
    unsigned h = (rkey*2654435761u) >> (32-HASH_BITS);
    for(;;){
      unsigned kk = tab[h].x;
      if (kk==rkey){ atomicAdd(&diagint[r], (int)tab[h].y); break; }
      if (kk==HEMPTY) break;
      h = (h+1)&HASH_MASK;
    }
  } else {
    int i = idx - EE;
    if (i < NN){
      int mv = scal[1] ? (int)((const unsigned char*)mp)[i] : ((const int*)mp)[i];
      if (mv){ int p = (int)atomicAdd(&scal[0], 1u); mlist[p] = i; minv[i] = p; }
    }
  }
}

// ---------------- matmuls (float4 outputs) ----------------
__global__ void k_mm_h0v(const float* __restrict__ X, const float* __restrict__ W, float* __restrict__ Y){
  int idx = blockIdx.x*256 + threadIdx.x;
  if (idx >= NN*16) return;
  int i = idx>>4, fq = idx&15;
  const vf4* X4 = (const vf4*)&X[i*CINV];
  const vf4* W4 = (const vf4*)W;
  vf4 acc = {0.f,0.f,0.f,0.f};
  #pragma unroll
  for (int kq=0;kq<CINV/4;kq++){
    vf4 xv = X4[kq];
    #pragma unroll
    for (int u=0;u<4;u++) acc += xv[u] * W4[(kq*4+u)*16+fq];
  }
  ((vf4*)Y)[i*16+fq] = acc;
}
__global__ void k_mm64v(const float* __restrict__ X, const float* __restrict__ W, float* __restrict__ Y){
  int idx = blockIdx.x*256 + threadIdx.x;
  if (idx >= NN*16) return;
  int i = idx>>4, fq = idx&15;
  const vf4* X4 = (const vf4*)&X[i*64];
  const vf4* W4 = (const vf4*)W;
  vf4 acc = {0.f,0.f,0.f,0.f};
  #pragma unroll
  for (int kq=0;kq<16;kq++){
    vf4 xv = X4[kq];
    #pragma unroll
    for (int u=0;u<4;u++) acc += xv[u] * W4[(kq*4+u)*16+fq];
  }
  ((vf4*)Y)[i*16+fq] = acc;
}
__global__ void k_mm64sv(const float* __restrict__ X, const float* __restrict__ W,
                         const float* __restrict__ sc, const int* __restrict__ kp,
                         float* __restrict__ Y){
  int idx = blockIdx.x*256 + threadIdx.x;
  if (idx >= NN*16) return;
  int i = idx>>4, fq = idx&15;
  if (!kp[i]) return;
  const vf4* X4 = (const vf4*)&X[i*64];
  const vf4* W4 = (const vf4*)W;
  vf4 acc = {0.f,0.f,0.f,0.f};
  #pragma unroll
  for (int kq=0;kq<16;kq++){
    vf4 xv = X4[kq];
    #pragma unroll
    for (int u=0;u<4;u++) acc += xv[u] * W4[(kq*4+u)*16+fq];
  }
  float s = sc[i];
  acc *= s;
  ((vf4*)Y)[i*16+fq] = acc;
}

// ---------------- CSR gather GCN kernels (wave per node) ----------------
__global__ void g_gcn0(const int* __restrict__ indptr, const int* __restrict__ csr_r,
                       const float* __restrict__ dinv, const float* __restrict__ H,
                       const float* __restrict__ b, float* __restrict__ out){
  int node = blockIdx.x*4 + (threadIdx.x>>6), lane = threadIdx.x&63;
  if (node >= NN) return;
  int s = __builtin_amdgcn_readfirstlane(indptr[node]);
  int e = __builtin_amdgcn_readfirstlane(indptr[node+1]);
  float acc = 0.f;
  for (int j=s;j<e;j++){
    int r = __builtin_amdgcn_readfirstlane(csr_r[j]);
    acc += dinv[r]*H[r*64+lane];
  }
  float di = dinv[node];
  float v = di*acc + 2.f*di*di*H[node*64+lane] + b[lane];
  out[node*64+lane] = fmaxf(v, 0.f);
}
__global__ void g_t2(const int* __restrict__ indptr, const int* __restrict__ csr_r,
                     const float* __restrict__ dinv1, const float* __restrict__ hp,
                     float* __restrict__ t2){
  int node = blockIdx.x*4 + (threadIdx.x>>6), lane = threadIdx.x&63;
  if (node >= NN) return;
  int s = __builtin_amdgcn_readfirstlane(indptr[node]);
  int e = __builtin_amdgcn_readfirstlane(indptr[node+1]);
  float acc = dinv1[node]*hp[node*64+lane];        // self loop
  for (int j=s;j<e;j++){
    int r = __builtin_amdgcn_readfirstlane(csr_r[j]);
    float dr = dinv1[r];
    if (dr != 0.f) acc += dr*hp[r*64+lane];
  }
  t2[node*64+lane] = acc;
}
// D[i] = (masked ? H0[minv[i]] : C[i]) + (kept ? relu(x2_i) : 0)
__global__ void g_agg2y(const int* __restrict__ indptr, const int* __restrict__ csr_r,
                        const float* __restrict__ t2, const float* __restrict__ hp,
                        const float* __restrict__ dinv1, const int* __restrict__ diagint,
                        const int* __restrict__ kp, const float* __restrict__ b1,
                        const float* __restrict__ C, const float* __restrict__ Hbuf,
                        const int* __restrict__ minv, float* __restrict__ D){
  int node = blockIdx.x*4 + (threadIdx.x>>6), lane = threadIdx.x&63;
  if (node >= NN) return;
  int mv = minv[node];
  float base = (mv >= 0) ? Hbuf[(size_t)mv*64+lane] : C[node*64+lane];
  float add = 0.f;
  if (kp[node]){
    int s = __builtin_amdgcn_readfirstlane(indptr[node]);
    int e = __builtin_amdgcn_readfirstlane(indptr[node+1]);
    float acc = t2[node*64+lane];                  // self loop
    for (int j=s;j<e;j++){
      int r = __builtin_amdgcn_readfirstlane(csr_r[j]);
      acc += t2[r*64+lane];
    }
    float di = dinv1[node], hv = hp[node*64+lane];
    float diag = (float)(diagint[node] + 1);
    float v = di*(acc - diag*di*hv) + 2.f*di*di*hv + b1[lane];
    add = fmaxf(v, 0.f);
  }
  D[node*64+lane] = base + add;
}
__global__ void g_up(const int* __restrict__ indptr, const int* __restrict__ csr_r,
                     const float* __restrict__ dinv, const float* __restrict__ H,
                     const float* __restrict__ b, float* __restrict__ xo, float* __restrict__ out){
  int node = blockIdx.x*4 + (threadIdx.x>>6), lane = threadIdx.x&63;
  if (node >= NN) return;
  int s = __builtin_amdgcn_readfirstlane(indptr[node]);
  int e = __builtin_amdgcn_readfirstlane(indptr[node+1]);
  float acc = 0.f;
  for (int j=s;j<e;j++){
    int r = __builtin_amdgcn_readfirstlane(csr_r[j]);
    acc += dinv[r]*H[r*64+lane];
  }
  float di = dinv[node];
  float v = di*acc + 2.f*di*di*H[node*64+lane] + b[lane];
  xo[node*64+lane] = v; out[node*64+lane] = v;
}

// ---------------- TopK selection ----------------
__global__ void k_scorekey(const float* __restrict__ x1, const float* __restrict__ pw,
                           unsigned long long* __restrict__ keys, float* __restrict__ score){
  int node = blockIdx.x*4 + (threadIdx.x>>6);
  int lane = threadIdx.x & 63;
  if (node >= NN) return;
  float pv = pw[lane];
  float nq = pv*pv;
  for (int o=32;o;o>>=1) nq += __shfl_down(nq, o, 64);
  float nrm = sqrtf(__shfl(nq, 0, 64));
  float v = x1[node*64+lane]*pv;
  for (int o=32;o;o>>=1) v += __shfl_down(v, o, 64);
  if (lane==0){
    float s = tanhf(v / nrm);
    s = s + 0.0f;                 // canonicalize -0 -> +0
    score[node] = s;
    unsigned u = __float_as_uint(s);
    unsigned asc = (u>>31) ? ~u : (u | 0x80000000u);
    keys[node] = (((unsigned long long)(~asc))<<32) | (unsigned)node;
  }
}
__global__ void k_hist(const unsigned long long* __restrict__ keys, unsigned* __restrict__ hist,
                       const unsigned long long* __restrict__ selp, int round){
  int i = blockIdx.x*256 + threadIdx.x;
  if (i >= NN) return;
  unsigned long long key = keys[i];
  int shift = 48 - 16*round;
  if (round==0 || (key>>(shift+16)) == selp[0])
    atomicAdd(&hist[(unsigned)((key>>shift)&0xFFFFull)], 1u);
}
__global__ void k_pick(const unsigned* __restrict__ hist, unsigned long long* selp, unsigned* scal){
  __shared__ unsigned csum[256];
  __shared__ unsigned bins[256];
  __shared__ int schunk;
  int t = threadIdx.x;
  const uint4* h4 = (const uint4*)(hist + t*256);
  unsigned s = 0;
  #pragma unroll 8
  for (int j=0;j<64;j++){ uint4 v = h4[j]; s += v.x+v.y+v.z+v.w; }
  csum[t] = s;
  __syncthreads();
  if (t==0){
    unsigned rem = scal[3];
    int chunk = 255;
    for (int c2=0;c2<256;c2++){ unsigned cc=csum[c2]; if (rem>cc) rem-=cc; else { chunk=c2; break; } }
    schunk = chunk; scal[3] = rem;
  }
  __syncthreads();
  bins[t] = hist[schunk*256 + t];
  __syncthreads();
  if (t==0){
    unsigned rem = scal[3];
    int bin = schunk*256 + 255;
    for (int b=0;b<256;b++){ unsigned hv=bins[b]; if (rem>hv) rem-=hv; else { bin = schunk*256 + b; break; } }
    selp[0] = (selp[0]<<16) | (unsigned long long)(unsigned)bin;
    scal[3] = rem;
  }
}
// kpmark + pooled-degree first SpMV (ts)
__global__ void k_mid(const int* __restrict__ row, const int* __restrict__ col,
                      const unsigned long long* __restrict__ keys,
                      const unsigned long long* __restrict__ selp,
                      int* __restrict__ kp, int* __restrict__ ts){
  int idx = blockIdx.x*256 + threadIdx.x;
  unsigned long long sp = selp[0];
  if (idx < EE){
    if (keys[row[idx]] <= sp) atomicAdd(&ts[col[idx]], 1);
  } else {
    int i = idx - EE;
    if (i < NN){
      int k = (keys[i] <= sp) ? 1 : 0;
      kp[i] = k;
      if (k) atomicAdd(&ts[i], 1);
    }
  }
}
__global__ void k_colsum(const int* __restrict__ row, const int* __restrict__ col,
                         const int* __restrict__ ts, int* __restrict__ cs){
  int idx = blockIdx.x*256 + threadIdx.x;
  if (idx < EE){ int v = ts[row[idx]]; if (v) atomicAdd(&cs[col[idx]], v); }
  else { int i = idx-EE; if (i < NN){ int v = ts[i]; if (v) atomicAdd(&cs[i], v); } }
}
__global__ void k_dinv1(const int* __restrict__ cs, const int* __restrict__ diagint,
                        const int* __restrict__ kp, float* __restrict__ dinv1){
  int i = blockIdx.x*256 + threadIdx.x;
  if (i >= NN) return;
  dinv1[i] = kp[i] ? rsqrtf((float)(cs[i] - diagint[i] - 1) + 2.0f) : 0.f;
}

// ---------------- LSTM part 1: XW = src @ W_ih^T + (b_ih+b_hh) ----------------
// LDS-tiled GEMM, register blocked 4 nodes x 8 gates per thread:
// per k: 3 ds_read_b128 -> 32 FMAs (FMA-issue bound). LDS 77 KB -> 2 blocks/CU.
__global__ __launch_bounds__(256) void k_xw(const float* __restrict__ src,
        const float* __restrict__ wih, const float* __restrict__ bih,
        const float* __restrict__ bhh, float* __restrict__ XW){
  __shared__ float WT[64][260];   // WT[k][g] = wih[g][k]
  __shared__ float XT[64][36];    // XT[k][n]
  __shared__ float sbias[256];
  int t = threadIdx.x;
  for (int u=t; u<256*64; u+=256) WT[u&63][u>>6] = wih[u];
  sbias[t] = bih[t] + bhh[t];
  int ng = t>>5, gg = t&31;
  __syncthreads();
  vf4 b0 = *(const vf4*)&sbias[gg*8];
  vf4 b1 = *(const vf4*)&sbias[gg*8+4];
  for (int tile = blockIdx.x; tile*32 < NN; tile += gridDim.x){
    int nbase = tile*32;
    __syncthreads();
    for (int u=t; u<32*64; u+=256){
      int n = u>>6, k = u&63;
      int node = nbase+n;
      XT[k][n] = (node < NN) ? src[node*64+k] : 0.f;
    }
    __syncthreads();
    vf4 a00=b0,a01=b1,a10=b0,a11=b1,a20=b0,a21=b1,a30=b0,a31=b1;
    #pragma unroll
    for (int k=0;k<64;k++){
      vf4 xq = *(const vf4*)&XT[k][ng*4];
      vf4 w0 = *(const vf4*)&WT[k][gg*8];
      vf4 w1 = *(const vf4*)&WT[k][gg*8+4];
      a00 += xq.x*w0; a01 += xq.x*w1;
      a10 += xq.y*w0; a11 += xq.y*w1;
      a20 += xq.z*w0; a21 += xq.z*w1;
      a30 += xq.w*w0; a31 += xq.w*w1;
    }
    int n0 = nbase + ng*4;
    if (n0+0 < NN){ *(vf4*)&XW[(size_t)(n0+0)*256+gg*8] = a00; *(vf4*)&XW[(size_t)(n0+0)*256+gg*8+4] = a01; }
    if (n0+1 < NN){ *(vf4*)&XW[(size_t)(n0+1)*256+gg*8] = a10; *(vf4*)&XW[(size_t)(n0+1)*256+gg*8+4] = a11; }
    if (n0+2 < NN){ *(vf4*)&XW[(size_t)(n0+2)*256+gg*8] = a20; *(vf4*)&XW[(size_t)(n0+2)*256+gg*8+4] = a21; }
    if (n0+3 < NN){ *(vf4*)&XW[(size_t)(n0+3)*256+gg*8] = a30; *(vf4*)&XW[(size_t)(n0+3)*256+gg*8+4] = a31; }
  }
}

// ---------------- LSTM part 2: recurrence (hh-half only) ----------------
// 4 nodes/block; wave w holds W_hh rows [w*64+lane] (16 vf4 = 64 VGPRs) and
// computes gate chunk w for all 4 nodes. Gate-x terms read from XW (coalesced).
// __launch_bounds__(256,4): 4 waves/SIMD -> VGPR cap 128 (weights + acc fit).
__global__ __launch_bounds__(256,4) void k_rec(const float* __restrict__ XW,
        const float* __restrict__ whh, const float* __restrict__ bih,
        const float* __restrict__ bhh, const int* __restrict__ mlist,
        const unsigned* __restrict__ scal, float* __restrict__ dst, int scatter){
  int M = (int)scal[0];
  int w = threadIdx.x>>6, lane = threadIdx.x&63;
  int r = w*64 + lane;
  const vf4* g4 = (const vf4*)&whh[(size_t)r*64];
  vf4 wh[16];
  #pragma unroll
  for (int j=0;j<16;j++) wh[j] = g4[j];
  __shared__ float sbias[256];
  __shared__ float sh[4][64];
  __shared__ float gates[4][4][64];
  sbias[threadIdx.x] = bih[threadIdx.x] + bhh[threadIdx.x];
  __syncthreads();
  int ntask = (M+3)>>2;
  for (int task = blockIdx.x; task < ntask; task += gridDim.x){
    int m = task*4 + w;
    bool valid = (m < M);
    int node = mlist[valid ? m : (M-1)];
    float c, h;
    {   // t = 0: h==0, gates = XW row (or bias if padded row)
      int rowi = node - (SEQL-1);
      float g0,g1,g2,g3;
      if (rowi >= 0){
        const float* p = &XW[(size_t)rowi*256];
        g0=p[lane]; g1=p[64+lane]; g2=p[128+lane]; g3=p[192+lane];
      } else {
        g0=sbias[lane]; g1=sbias[64+lane]; g2=sbias[128+lane]; g3=sbias[192+lane];
      }
      c = sigm(g0)*tanhf(g2);
      h = sigm(g3)*tanhf(c);
      sh[w][lane] = h;
    }
    __syncthreads();
    for (int t=1;t<SEQL;t++){
      vf4 a0={0,0,0,0}, a1={0,0,0,0}, a2={0,0,0,0}, a3={0,0,0,0};
      #pragma unroll
      for (int j=0;j<16;j++){
        vf4 wj = wh[j];
        a0 += (*(const vf4*)&sh[0][j*4]) * wj;
        a1 += (*(const vf4*)&sh[1][j*4]) * wj;
        a2 += (*(const vf4*)&sh[2][j*4]) * wj;
        a3 += (*(const vf4*)&sh[3][j*4]) * wj;
      }
      gates[0][w][lane] = a0.x+a0.y+a0.z+a0.w;
      gates[1][w][lane] = a1.x+a1.y+a1.z+a1.w;
      gates[2][w][lane] = a2.x+a2.y+a2.z+a2.w;
      gates[3][w][lane] = a3.x+a3.y+a3.z+a3.w;
      __syncthreads();
      int rowi = node - (SEQL-1) + t;
      float x0,x1,x2,x3;
      if (rowi >= 0){
        const float* p = &XW[(size_t)rowi*256];
        x0=p[lane]; x1=p[64+lane]; x2=p[128+lane]; x3=p[192+lane];
      } else {
        x0=sbias[lane]; x1=sbias[64+lane]; x2=sbias[128+lane]; x3=sbias[192+lane];
      }
      float gi = gates[w][0][lane] + x0;
      float gf = gates[w][1][lane] + x1;
      float gg = gates[w][2][lane] + x2;
      float go = gates[w][3][lane] + x3;
      c = sigm(gf)*c + sigm(gi)*tanhf(gg);
      h = sigm(go)*tanhf(c);
      sh[w][lane] = h;
      __syncthreads();
    }
    if (valid){
      size_t o = scatter ? ((size_t)node*64 + lane) : ((size_t)m*64 + lane);
      dst[o] = h;
    }
  }
}

// ==========================================================================
extern "C" void kernel_launch(void* const* d_in, const int* in_sizes, int n_in,
                              void* d_out, int out_size, void* d_ws, size_t ws_size,
                              hipStream_t stream) {
  const float* x   = (const float*)d_in[0];
  const int*   ei  = (const int*)d_in[1];
  const int*   row = ei;
  const int*   col = ei + EE;
  const void*  mp  = d_in[2];
  const float* W0  = (const float*)d_in[3];
  const float* b0  = (const float*)d_in[4];
  const float* W1  = (const float*)d_in[5];
  const float* b1  = (const float*)d_in[6];
  const float* pw  = (const float*)d_in[7];
  const float* Wu  = (const float*)d_in[8];
  const float* bu  = (const float*)d_in[9];
  const float* l0wih=(const float*)d_in[10];
  const float* l0whh=(const float*)d_in[11];
  const float* l0bih=(const float*)d_in[12];
  const float* l0bhh=(const float*)d_in[13];
  const float* lfwih=(const float*)d_in[14];
  const float* lfwhh=(const float*)d_in[15];
  const float* lfbih=(const float*)d_in[16];
  const float* lfbhh=(const float*)d_in[17];

  char* wp = (char*)d_ws;
  auto alloc = [&](size_t bytes)->char*{ char* p = wp; wp += ((bytes+255)/256)*256; return p; };
  float* A     = (float*)alloc((size_t)NN*64*4);   // h0 -> t2
  float* B     = (float*)alloc((size_t)NN*64*4);   // xo
  float* C     = (float*)alloc((size_t)NN*64*4);   // x1
  float* D     = (float*)alloc((size_t)NN*64*4);   // y
  float* Ebuf  = (float*)alloc((size_t)NN*64*4);   // hp -> up-GCN input
  float* Hbuf  = (float*)alloc((size_t)NN*64*4);   // LSTM0 compact output
  float* XW    = (float*)alloc((size_t)NN*256*4);  // gate-x precompute (51.2 MB)
  float* score = (float*)alloc((size_t)NN*4);
  float* dinv0 = (float*)alloc((size_t)NN*4);
  float* dinv1 = (float*)alloc((size_t)NN*4);
  unsigned long long* keys = (unsigned long long*)alloc((size_t)NN*8);
  int* degcnt  = (int*)alloc((size_t)NN*4);
  int* diagint = (int*)alloc((size_t)NN*4);
  int* ts      = (int*)alloc((size_t)NN*4);
  int* cs      = (int*)alloc((size_t)NN*4);
  int* kp      = (int*)alloc((size_t)NN*4);
  int* mlist   = (int*)alloc((size_t)NN*4);
  int* minv    = (int*)alloc((size_t)NN*4);
  int* indptr  = (int*)alloc((size_t)(NN+1)*4);
  int* part    = (int*)alloc((size_t)NN*4);
  int* fillc   = (int*)alloc((size_t)NN*4);
  int* bsum    = (int*)alloc((size_t)256*4);
  int* boff    = (int*)alloc((size_t)256*4);
  int* csr_r   = (int*)alloc((size_t)EE*4);
  uint2* hash  = (uint2*)alloc((size_t)HASH_SIZE*8);
  unsigned* hist=(unsigned*)alloc((size_t)4*65536*4);
  unsigned* scal=(unsigned*)alloc(256);
  unsigned long long* selp = (unsigned long long*)(scal + 4);

  #define GRID1(n) dim3(((n)+255)/256), dim3(256), 0, stream
  #define GRIDW dim3((NN+3)/4), dim3(256), 0, stream

  // 1. merged init (hash, hist, per-node arrays, scalars)
  k_init<<<GRID1(HASH_SIZE)>>>(hash, hist, degcnt, diagint, ts, cs, fillc, minv, scal, selp);
  // 2. degcnt + hash build + mask-dtype detect
  k_phase2<<<GRID1(EE)>>>(row, col, (const int*)mp, degcnt, hash, scal);
  // 3-5. indptr prefix sum (+dinv0)
  k_psum1<<<dim3(PSB),dim3(256),0,stream>>>(degcnt, part, bsum, dinv0);
  k_psum2<<<dim3(1),dim3(256),0,stream>>>(bsum, boff);
  k_psum3<<<dim3(PSB),dim3(256),0,stream>>>(part, boff, indptr);
  // 6. csr fill + A^2 diag + mask compact
  k_phase4<<<GRID1(EE+NN)>>>(row, col, indptr, fillc, csr_r, hash, diagint, mp, scal, mlist, minv);

  // GCN0
  k_mm_h0v<<<GRID1(NN*16)>>>(x, W0, A);
  g_gcn0<<<GRIDW>>>(indptr, csr_r, dinv0, A, b0, C);

  // TopK selection (set only; labeling is equivariant)
  k_scorekey<<<GRIDW>>>(C, pw, keys, score);
  for (int r2=0;r2<4;r2++){
    k_hist<<<GRID1(NN)>>>(keys, hist + r2*65536, selp, r2);
    k_pick<<<dim3(1),dim3(256),0,stream>>>(hist + r2*65536, selp, scal);
  }
  // kpmark + pooled ts
  k_mid<<<GRID1(EE+NN)>>>(row, col, keys, selp, kp, ts);
  k_colsum<<<GRID1(EE+NN)>>>(row, col, ts, cs);
  k_dinv1<<<GRID1(NN)>>>(cs, diagint, kp, dinv1);

  // pooled GCN: hp then two gather passes
  k_mm64sv<<<GRID1(NN*16)>>>(C, W1, score, kp, Ebuf);
  g_t2<<<GRIDW>>>(indptr, csr_r, dinv1, Ebuf, A);

  // LSTM0 on x1 windows -> Hbuf (compact)
  k_xw<<<dim3(512),dim3(256),0,stream>>>(C, l0wih, l0bih, l0bhh, XW);
  k_rec<<<dim3(1024),dim3(256),0,stream>>>(XW, l0whh, l0bih, l0bhh, mlist, scal, Hbuf, 0);

  // y = res + up (fused: base select + relu(x2))
  g_agg2y<<<GRIDW>>>(indptr, csr_r, A, Ebuf, dinv1, diagint, kp, b1, C, Hbuf, minv, D);

  // up-GCN -> xo (B) and d_out
  k_mm64v<<<GRID1(NN*16)>>>(D, Wu, Ebuf);
  g_up<<<GRIDW>>>(indptr, csr_r, dinv0, Ebuf, bu, B, (float*)d_out);

  // final LSTM on xo windows, scatter into d_out masked rows
  k_xw<<<dim3(512),dim3(256),0,stream>>>(B, lfwih, lfbih, lfbhh, XW);
  k_rec<<<dim3(1024),dim3(256),0,stream>>>(XW, lfwhh, lfbih, lfbhh, mlist, scal, (float*)d_out, 1);
  #undef GRIDW
  #undef GRID1
}

// Round 5
// 918.284 us; speedup vs baseline: 2.8952x; 2.8952x over previous
//
#include <hip/hip_runtime.h>
#include <math.h>

// Problem constants (fixed by reference setup)
#define NN 50000
#define EE 400000
#define CINV 32
#define KKEEP 25000          // ceil(0.5*N)
#define SEQL 5
#define HASH_BITS 20
#define HASH_SIZE (1u<<HASH_BITS)
#define HASH_MASK (HASH_SIZE-1u)
#define HEMPTY 0xFFFFFFFFu
#define PSB 196              // ceil(NN/256)

typedef float vf4 __attribute__((ext_vector_type(4)));

__device__ __forceinline__ float sigm(float x){ return 1.f/(1.f+__expf(-x)); }

// ---------------- merged init ----------------
__global__ void k_init(uint2* __restrict__ hash, unsigned* __restrict__ hist,
                       int* __restrict__ degcnt, int* __restrict__ diagint,
                       int* __restrict__ ts, int* __restrict__ cs,
                       int* __restrict__ fillc, int* __restrict__ minv,
                       unsigned* scal, unsigned long long* selp){
  int i = blockIdx.x*256 + threadIdx.x;
  if (i < (int)HASH_SIZE) hash[i] = make_uint2(HEMPTY, 0u);
  if (i < 4*65536) hist[i] = 0u;
  if (i < NN){ degcnt[i]=0; diagint[i]=0; ts[i]=0; cs[i]=0; fillc[i]=0; minv[i]=-1; }
  if (i == 0){ scal[0]=0u; scal[1]=0u; scal[3]=KKEEP; selp[0]=0ull; }
}

// ---------------- LSTM weight prep: WT[k][g] = wih[g][k], bsum = bih+bhh ----------------
__global__ void k_wprep(const float* __restrict__ w0, const float* __restrict__ b0i,
                        const float* __restrict__ b0h, const float* __restrict__ wf,
                        const float* __restrict__ bfi, const float* __restrict__ bfh,
                        float* __restrict__ WT0, float* __restrict__ WTf,
                        float* __restrict__ bs0, float* __restrict__ bsf){
  int idx = blockIdx.x*256 + threadIdx.x;
  if (idx < 256*64){
    int g = idx>>6, k = idx&63;
    WT0[k*256+g] = w0[idx];
    WTf[k*256+g] = wf[idx];
  }
  if (idx < 256){ bs0[idx]=b0i[idx]+b0h[idx]; bsf[idx]=bfi[idx]+bfh[idx]; }
}

// ---------------- degcnt + hash build + mask-dtype detect ----------------
__global__ void k_phase2(const int* __restrict__ row, const int* __restrict__ col,
                         const int* __restrict__ mp, int* __restrict__ degcnt,
                         uint2* __restrict__ tab, unsigned* scal){
  int e = blockIdx.x*256 + threadIdx.x;
  if (e < EE){
    int c = col[e];
    atomicAdd(&degcnt[c], 1);
    unsigned key = (unsigned)row[e]*50000u + (unsigned)c;
    unsigned h = (key*2654435761u) >> (32-HASH_BITS);
    for(;;){
      unsigned old = atomicCAS(&tab[h].x, HEMPTY, key);
      if (old==HEMPTY || old==key){ atomicAdd(&tab[h].y, 1u); break; }
      h = (h+1)&HASH_MASK;
    }
  }
  if (e < NN/4){ if ((unsigned)mp[e] > 1u) atomicOr(&scal[1], 1u); }
}

// ---------------- prefix sum (indptr) + dinv0 ----------------
__global__ void k_psum1(const int* __restrict__ deg, int* __restrict__ part,
                        int* __restrict__ bsum, float* __restrict__ dinv){
  __shared__ int sc[256];
  int b = blockIdx.x, t = threadIdx.x, i = b*256+t;
  int v = (i<NN) ? deg[i] : 0;
  if (i < NN) dinv[i] = rsqrtf((float)v + 2.0f);
  sc[t] = v; __syncthreads();
  for (int o=1;o<256;o<<=1){
    int x = (t>=o) ? sc[t-o] : 0;
    __syncthreads();
    sc[t] += x;
    __syncthreads();
  }
  if (i < NN) part[i] = sc[t]-v;
  if (t == 255) bsum[b] = sc[255];
}
__global__ void k_psum2(const int* __restrict__ bsum, int* __restrict__ boff){
  __shared__ int sc[256];
  int t = threadIdx.x;
  int v = (t<PSB) ? bsum[t] : 0;
  sc[t] = v; __syncthreads();
  for (int o=1;o<256;o<<=1){
    int x = (t>=o) ? sc[t-o] : 0;
    __syncthreads();
    sc[t] += x;
    __syncthreads();
  }
  if (t < PSB) boff[t] = sc[t]-v;
}
__global__ void k_psum3(const int* __restrict__ part, const int* __restrict__ boff,
                        int* __restrict__ indptr){
  int i = blockIdx.x*256 + threadIdx.x;
  if (i < NN) indptr[i] = part[i] + boff[blockIdx.x];
  if (i == 0) indptr[NN] = EE;
}

// ---------------- csr fill + A^2 diag + mask compact ----------------
__global__ void k_phase4(const int* __restrict__ row, const int* __restrict__ col,
                         const int* __restrict__ indptr, int* __restrict__ fillc,
                         int* __restrict__ csr_r, const uint2* __restrict__ tab,
                         int* __restrict__ diagint, const void* __restrict__ mp,
                         unsigned* scal, int* __restrict__ mlist, int* __restrict__ minv){
  int idx = blockIdx.x*256 + threadIdx.x;
  if (idx < EE){
    int r = row[idx], c = col[idx];
    int pos = indptr[c] + atomicAdd(&fillc[c], 1);
    csr_r[pos] = r;
    unsigned rkey = (unsigned)c*50000u + (unsigned)r;
    unsigned h = (rkey*2654435761u) >> (32-HASH_BITS);
    for(;;){
      unsigned kk = tab[h].x;
      if (kk==rkey){ atomicAdd(&diagint[r], (int)tab[h].y); break; }
      if (kk==HEMPTY) break;
      h = (h+1)&HASH_MASK;
    }
  } else {
    int i = idx - EE;
    if (i < NN){
      int mv = scal[1] ? (int)((const unsigned char*)mp)[i] : ((const int*)mp)[i];
      if (mv){ int p = (int)atomicAdd(&scal[0], 1u); mlist[p] = i; minv[i] = p; }
    }
  }
}

// ---------------- matmuls (float4 outputs) ----------------
__global__ void k_mm_h0v(const float* __restrict__ X, const float* __restrict__ W, float* __restrict__ Y){
  int idx = blockIdx.x*256 + threadIdx.x;
  if (idx >= NN*16) return;
  int i = idx>>4, fq = idx&15;
  const vf4* X4 = (const vf4*)&X[i*CINV];
  const vf4* W4 = (const vf4*)W;
  vf4 acc = {0.f,0.f,0.f,0.f};
  #pragma unroll
  for (int kq=0;kq<CINV/4;kq++){
    vf4 xv = X4[kq];
    #pragma unroll
    for (int u=0;u<4;u++) acc += xv[u] * W4[(kq*4+u)*16+fq];
  }
  ((vf4*)Y)[i*16+fq] = acc;
}
__global__ void k_mm64v(const float* __restrict__ X, const float* __restrict__ W, float* __restrict__ Y){
  int idx = blockIdx.x*256 + threadIdx.x;
  if (idx >= NN*16) return;
  int i = idx>>4, fq = idx&15;
  const vf4* X4 = (const vf4*)&X[i*64];
  const vf4* W4 = (const vf4*)W;
  vf4 acc = {0.f,0.f,0.f,0.f};
  #pragma unroll
  for (int kq=0;kq<16;kq++){
    vf4 xv = X4[kq];
    #pragma unroll
    for (int u=0;u<4;u++) acc += xv[u] * W4[(kq*4+u)*16+fq];
  }
  ((vf4*)Y)[i*16+fq] = acc;
}
__global__ void k_mm64sv(const float* __restrict__ X, const float* __restrict__ W,
                         const float* __restrict__ sc, const int* __restrict__ kp,
                         float* __restrict__ Y){
  int idx = blockIdx.x*256 + threadIdx.x;
  if (idx >= NN*16) return;
  int i = idx>>4, fq = idx&15;
  if (!kp[i]) return;
  const vf4* X4 = (const vf4*)&X[i*64];
  const vf4* W4 = (const vf4*)W;
  vf4 acc = {0.f,0.f,0.f,0.f};
  #pragma unroll
  for (int kq=0;kq<16;kq++){
    vf4 xv = X4[kq];
    #pragma unroll
    for (int u=0;u<4;u++) acc += xv[u] * W4[(kq*4+u)*16+fq];
  }
  float s = sc[i];
  acc *= s;
  ((vf4*)Y)[i*16+fq] = acc;
}

// ---------------- CSR gather GCN kernels (wave per node) ----------------
__global__ void g_gcn0(const int* __restrict__ indptr, const int* __restrict__ csr_r,
                       const float* __restrict__ dinv, const float* __restrict__ H,
                       const float* __restrict__ b, float* __restrict__ out){
  int node = blockIdx.x*4 + (threadIdx.x>>6), lane = threadIdx.x&63;
  if (node >= NN) return;
  int s = __builtin_amdgcn_readfirstlane(indptr[node]);
  int e = __builtin_amdgcn_readfirstlane(indptr[node+1]);
  float acc = 0.f;
  for (int j=s;j<e;j++){
    int r = __builtin_amdgcn_readfirstlane(csr_r[j]);
    acc += dinv[r]*H[r*64+lane];
  }
  float di = dinv[node];
  float v = di*acc + 2.f*di*di*H[node*64+lane] + b[lane];
  out[node*64+lane] = fmaxf(v, 0.f);
}
__global__ void g_t2(const int* __restrict__ indptr, const int* __restrict__ csr_r,
                     const float* __restrict__ dinv1, const float* __restrict__ hp,
                     float* __restrict__ t2){
  int node = blockIdx.x*4 + (threadIdx.x>>6), lane = threadIdx.x&63;
  if (node >= NN) return;
  int s = __builtin_amdgcn_readfirstlane(indptr[node]);
  int e = __builtin_amdgcn_readfirstlane(indptr[node+1]);
  float acc = dinv1[node]*hp[node*64+lane];        // self loop
  for (int j=s;j<e;j++){
    int r = __builtin_amdgcn_readfirstlane(csr_r[j]);
    float dr = dinv1[r];
    if (dr != 0.f) acc += dr*hp[r*64+lane];
  }
  t2[node*64+lane] = acc;
}
// D[i] = (masked ? H0[minv[i]] : C[i]) + (kept ? relu(x2_i) : 0)
__global__ void g_agg2y(const int* __restrict__ indptr, const int* __restrict__ csr_r,
                        const float* __restrict__ t2, const float* __restrict__ hp,
                        const float* __restrict__ dinv1, const int* __restrict__ diagint,
                        const int* __restrict__ kp, const float* __restrict__ b1,
                        const float* __restrict__ C, const float* __restrict__ Hbuf,
                        const int* __restrict__ minv, float* __restrict__ D){
  int node = blockIdx.x*4 + (threadIdx.x>>6), lane = threadIdx.x&63;
  if (node >= NN) return;
  int mv = minv[node];
  float base = (mv >= 0) ? Hbuf[(size_t)mv*64+lane] : C[node*64+lane];
  float add = 0.f;
  if (kp[node]){
    int s = __builtin_amdgcn_readfirstlane(indptr[node]);
    int e = __builtin_amdgcn_readfirstlane(indptr[node+1]);
    float acc = t2[node*64+lane];                  // self loop
    for (int j=s;j<e;j++){
      int r = __builtin_amdgcn_readfirstlane(csr_r[j]);
      acc += t2[r*64+lane];
    }
    float di = dinv1[node], hv = hp[node*64+lane];
    float diag = (float)(diagint[node] + 1);
    float v = di*(acc - diag*di*hv) + 2.f*di*di*hv + b1[lane];
    add = fmaxf(v, 0.f);
  }
  D[node*64+lane] = base + add;
}
__global__ void g_up(const int* __restrict__ indptr, const int* __restrict__ csr_r,
                     const float* __restrict__ dinv, const float* __restrict__ H,
                     const float* __restrict__ b, float* __restrict__ xo, float* __restrict__ out){
  int node = blockIdx.x*4 + (threadIdx.x>>6), lane = threadIdx.x&63;
  if (node >= NN) return;
  int s = __builtin_amdgcn_readfirstlane(indptr[node]);
  int e = __builtin_amdgcn_readfirstlane(indptr[node+1]);
  float acc = 0.f;
  for (int j=s;j<e;j++){
    int r = __builtin_amdgcn_readfirstlane(csr_r[j]);
    acc += dinv[r]*H[r*64+lane];
  }
  float di = dinv[node];
  float v = di*acc + 2.f*di*di*H[node*64+lane] + b[lane];
  xo[node*64+lane] = v; out[node*64+lane] = v;
}

// ---------------- TopK selection ----------------
__global__ void k_scorekey(const float* __restrict__ x1, const float* __restrict__ pw,
                           unsigned long long* __restrict__ keys, float* __restrict__ score){
  int node = blockIdx.x*4 + (threadIdx.x>>6);
  int lane = threadIdx.x & 63;
  if (node >= NN) return;
  float pv = pw[lane];
  float nq = pv*pv;
  for (int o=32;o;o>>=1) nq += __shfl_down(nq, o, 64);
  float nrm = sqrtf(__shfl(nq, 0, 64));
  float v = x1[node*64+lane]*pv;
  for (int o=32;o;o>>=1) v += __shfl_down(v, o, 64);
  if (lane==0){
    float s = tanhf(v / nrm);
    s = s + 0.0f;                 // canonicalize -0 -> +0
    score[node] = s;
    unsigned u = __float_as_uint(s);
    unsigned asc = (u>>31) ? ~u : (u | 0x80000000u);
    keys[node] = (((unsigned long long)(~asc))<<32) | (unsigned)node;
  }
}
__global__ void k_hist(const unsigned long long* __restrict__ keys, unsigned* __restrict__ hist,
                       const unsigned long long* __restrict__ selp, int round){
  int i = blockIdx.x*256 + threadIdx.x;
  if (i >= NN) return;
  unsigned long long key = keys[i];
  int shift = 48 - 16*round;
  if (round==0 || (key>>(shift+16)) == selp[0])
    atomicAdd(&hist[(unsigned)((key>>shift)&0xFFFFull)], 1u);
}
__global__ void k_pick(const unsigned* __restrict__ hist, unsigned long long* selp, unsigned* scal){
  __shared__ unsigned csum[256];
  __shared__ unsigned bins[256];
  __shared__ int schunk;
  int t = threadIdx.x;
  const uint4* h4 = (const uint4*)(hist + t*256);
  unsigned s = 0;
  #pragma unroll 8
  for (int j=0;j<64;j++){ uint4 v = h4[j]; s += v.x+v.y+v.z+v.w; }
  csum[t] = s;
  __syncthreads();
  if (t==0){
    unsigned rem = scal[3];
    int chunk = 255;
    for (int c2=0;c2<256;c2++){ unsigned cc=csum[c2]; if (rem>cc) rem-=cc; else { chunk=c2; break; } }
    schunk = chunk; scal[3] = rem;
  }
  __syncthreads();
  bins[t] = hist[schunk*256 + t];
  __syncthreads();
  if (t==0){
    unsigned rem = scal[3];
    int bin = schunk*256 + 255;
    for (int b=0;b<256;b++){ unsigned hv=bins[b]; if (rem>hv) rem-=hv; else { bin = schunk*256 + b; break; } }
    selp[0] = (selp[0]<<16) | (unsigned long long)(unsigned)bin;
    scal[3] = rem;
  }
}
// kpmark + pooled-degree first SpMV (ts)
__global__ void k_mid(const int* __restrict__ row, const int* __restrict__ col,
                      const unsigned long long* __restrict__ keys,
                      const unsigned long long* __restrict__ selp,
                      int* __restrict__ kp, int* __restrict__ ts){
  int idx = blockIdx.x*256 + threadIdx.x;
  unsigned long long sp = selp[0];
  if (idx < EE){
    if (keys[row[idx]] <= sp) atomicAdd(&ts[col[idx]], 1);
  } else {
    int i = idx - EE;
    if (i < NN){
      int k = (keys[i] <= sp) ? 1 : 0;
      kp[i] = k;
      if (k) atomicAdd(&ts[i], 1);
    }
  }
}
__global__ void k_colsum(const int* __restrict__ row, const int* __restrict__ col,
                         const int* __restrict__ ts, int* __restrict__ cs){
  int idx = blockIdx.x*256 + threadIdx.x;
  if (idx < EE){ int v = ts[row[idx]]; if (v) atomicAdd(&cs[col[idx]], v); }
  else { int i = idx-EE; if (i < NN){ int v = ts[i]; if (v) atomicAdd(&cs[i], v); } }
}
__global__ void k_dinv1(const int* __restrict__ cs, const int* __restrict__ diagint,
                        const int* __restrict__ kp, float* __restrict__ dinv1){
  int i = blockIdx.x*256 + threadIdx.x;
  if (i >= NN) return;
  dinv1[i] = kp[i] ? rsqrtf((float)(cs[i] - diagint[i] - 1) + 2.0f) : 0.f;
}

// ---------------- LSTM part 1: XW[n] = src[n] @ W_ih^T + (b_ih+b_hh) ----------------
// One wave per node: X reads are wave-uniform broadcasts, WT reads perfectly
// coalesced (WT[k][g] pre-transposed). No LDS, no spill (k_mm64v pattern).
__global__ __launch_bounds__(256) void k_xw(const float* __restrict__ src,
        const float* __restrict__ WT, const float* __restrict__ bsum,
        float* __restrict__ XW){
  int idx = blockIdx.x*256 + threadIdx.x;
  if (idx >= NN*64) return;
  int i = idx>>6, fq = idx&63;
  const vf4* X4 = (const vf4*)&src[(size_t)i*64];
  const vf4* W4 = (const vf4*)WT;
  vf4 acc = ((const vf4*)bsum)[fq];
  #pragma unroll
  for (int kq=0;kq<16;kq++){
    vf4 xv = X4[kq];
    #pragma unroll
    for (int u=0;u<4;u++) acc += xv[u] * W4[(size_t)(kq*4+u)*64 + fq];
  }
  ((vf4*)XW)[(size_t)i*64 + fq] = acc;
}

// ---------------- LSTM part 2: recurrence (hh-half only) ----------------
// 4 nodes/block; wave w holds W_hh rows [w*64+lane] (16 vf4 = 64 VGPRs) and
// computes gate chunk w for all 4 nodes. Gate-x terms read from XW (coalesced).
// No occupancy bound: allow up to 256 VGPRs so weights stay in VGPRs.
__global__ __launch_bounds__(256) void k_rec(const float* __restrict__ XW,
        const float* __restrict__ whh, const float* __restrict__ bsum,
        const int* __restrict__ mlist, const unsigned* __restrict__ scal,
        float* __restrict__ dst, int scatter){
  int M = (int)scal[0];
  if (M < 0 || M > NN) M = 0;          // defensive (rocprof replay poisons scal)
  int w = threadIdx.x>>6, lane = threadIdx.x&63;
  int r = w*64 + lane;
  const vf4* g4 = (const vf4*)&whh[(size_t)r*64];
  vf4 wh[16];
  #pragma unroll
  for (int j=0;j<16;j++) wh[j] = g4[j];
  __shared__ float sh[4][64];
  __shared__ float gates[4][4][64];
  int ntask = (M+3)>>2;
  for (int task = blockIdx.x; task < ntask; task += gridDim.x){
    int m = task*4 + w;
    bool valid = (m < M);
    int node = mlist[valid ? m : (M-1)];
    float c, h;
    {   // t = 0: h==0, gates = XW row (bias-only row if left-padded: node<4)
      int rowi = node - (SEQL-1);
      float g0,g1,g2,g3;
      if (rowi >= 0){
        const float* p = &XW[(size_t)rowi*256];
        g0=p[lane]; g1=p[64+lane]; g2=p[128+lane]; g3=p[192+lane];
      } else {
        g0=bsum[lane]; g1=bsum[64+lane]; g2=bsum[128+lane]; g3=bsum[192+lane];
      }
      c = sigm(g0)*tanhf(g2);
      h = sigm(g3)*tanhf(c);
      sh[w][lane] = h;
    }
    __syncthreads();
    for (int t=1;t<SEQL;t++){
      vf4 a0={0,0,0,0}, a1={0,0,0,0}, a2={0,0,0,0}, a3={0,0,0,0};
      #pragma unroll
      for (int j=0;j<16;j++){
        vf4 wj = wh[j];
        a0 += (*(const vf4*)&sh[0][j*4]) * wj;
        a1 += (*(const vf4*)&sh[1][j*4]) * wj;
        a2 += (*(const vf4*)&sh[2][j*4]) * wj;
        a3 += (*(const vf4*)&sh[3][j*4]) * wj;
      }
      gates[0][w][lane] = a0.x+a0.y+a0.z+a0.w;
      gates[1][w][lane] = a1.x+a1.y+a1.z+a1.w;
      gates[2][w][lane] = a2.x+a2.y+a2.z+a2.w;
      gates[3][w][lane] = a3.x+a3.y+a3.z+a3.w;
      __syncthreads();
      int rowi = node - (SEQL-1) + t;
      float x0,x1,x2,x3;
      if (rowi >= 0){
        const float* p = &XW[(size_t)rowi*256];
        x0=p[lane]; x1=p[64+lane]; x2=p[128+lane]; x3=p[192+lane];
      } else {
        x0=bsum[lane]; x1=bsum[64+lane]; x2=bsum[128+lane]; x3=bsum[192+lane];
      }
      float gi = gates[w][0][lane] + x0;
      float gf = gates[w][1][lane] + x1;
      float gg = gates[w][2][lane] + x2;
      float go = gates[w][3][lane] + x3;
      c = sigm(gf)*c + sigm(gi)*tanhf(gg);
      h = sigm(go)*tanhf(c);
      sh[w][lane] = h;
      __syncthreads();
    }
    if (valid){
      size_t o = scatter ? ((size_t)node*64 + lane) : ((size_t)m*64 + lane);
      dst[o] = h;
    }
  }
}

// ==========================================================================
extern "C" void kernel_launch(void* const* d_in, const int* in_sizes, int n_in,
                              void* d_out, int out_size, void* d_ws, size_t ws_size,
                              hipStream_t stream) {
  const float* x   = (const float*)d_in[0];
  const int*   ei  = (const int*)d_in[1];
  const int*   row = ei;
  const int*   col = ei + EE;
  const void*  mp  = d_in[2];
  const float* W0  = (const float*)d_in[3];
  const float* b0  = (const float*)d_in[4];
  const float* W1  = (const float*)d_in[5];
  const float* b1  = (const float*)d_in[6];
  const float* pw  = (const float*)d_in[7];
  const float* Wu  = (const float*)d_in[8];
  const float* bu  = (const float*)d_in[9];
  const float* l0wih=(const float*)d_in[10];
  const float* l0whh=(const float*)d_in[11];
  const float* l0bih=(const float*)d_in[12];
  const float* l0bhh=(const float*)d_in[13];
  const float* lfwih=(const float*)d_in[14];
  const float* lfwhh=(const float*)d_in[15];
  const float* lfbih=(const float*)d_in[16];
  const float* lfbhh=(const float*)d_in[17];

  char* wp = (char*)d_ws;
  auto alloc = [&](size_t bytes)->char*{ char* p = wp; wp += ((bytes+255)/256)*256; return p; };
  float* A     = (float*)alloc((size_t)NN*64*4);   // h0 -> t2
  float* B     = (float*)alloc((size_t)NN*64*4);   // xo
  float* C     = (float*)alloc((size_t)NN*64*4);   // x1
  float* D     = (float*)alloc((size_t)NN*64*4);   // y
  float* Ebuf  = (float*)alloc((size_t)NN*64*4);   // hp -> up-GCN input
  float* Hbuf  = (float*)alloc((size_t)NN*64*4);   // LSTM0 compact output
  float* XW    = (float*)alloc((size_t)NN*256*4);  // gate-x precompute (51.2 MB)
  float* WT0   = (float*)alloc((size_t)256*64*4);
  float* WTf   = (float*)alloc((size_t)256*64*4);
  float* bs0   = (float*)alloc((size_t)256*4);
  float* bsf   = (float*)alloc((size_t)256*4);
  float* score = (float*)alloc((size_t)NN*4);
  float* dinv0 = (float*)alloc((size_t)NN*4);
  float* dinv1 = (float*)alloc((size_t)NN*4);
  unsigned long long* keys = (unsigned long long*)alloc((size_t)NN*8);
  int* degcnt  = (int*)alloc((size_t)NN*4);
  int* diagint = (int*)alloc((size_t)NN*4);
  int* ts      = (int*)alloc((size_t)NN*4);
  int* cs      = (int*)alloc((size_t)NN*4);
  int* kp      = (int*)alloc((size_t)NN*4);
  int* mlist   = (int*)alloc((size_t)NN*4);
  int* minv    = (int*)alloc((size_t)NN*4);
  int* indptr  = (int*)alloc((size_t)(NN+1)*4);
  int* part    = (int*)alloc((size_t)NN*4);
  int* fillc   = (int*)alloc((size_t)NN*4);
  int* bsum    = (int*)alloc((size_t)256*4);
  int* boff    = (int*)alloc((size_t)256*4);
  int* csr_r   = (int*)alloc((size_t)EE*4);
  uint2* hash  = (uint2*)alloc((size_t)HASH_SIZE*8);
  unsigned* hist=(unsigned*)alloc((size_t)4*65536*4);
  unsigned* scal=(unsigned*)alloc(256);
  unsigned long long* selp = (unsigned long long*)(scal + 4);

  #define GRID1(n) dim3(((n)+255)/256), dim3(256), 0, stream
  #define GRIDW dim3((NN+3)/4), dim3(256), 0, stream

  // 1. merged init (hash, hist, per-node arrays, scalars) + LSTM weight prep
  k_init<<<GRID1(HASH_SIZE)>>>(hash, hist, degcnt, diagint, ts, cs, fillc, minv, scal, selp);
  k_wprep<<<dim3(64),dim3(256),0,stream>>>(l0wih, l0bih, l0bhh, lfwih, lfbih, lfbhh, WT0, WTf, bs0, bsf);
  // 2. degcnt + hash build + mask-dtype detect
  k_phase2<<<GRID1(EE)>>>(row, col, (const int*)mp, degcnt, hash, scal);
  // 3-5. indptr prefix sum (+dinv0)
  k_psum1<<<dim3(PSB),dim3(256),0,stream>>>(degcnt, part, bsum, dinv0);
  k_psum2<<<dim3(1),dim3(256),0,stream>>>(bsum, boff);
  k_psum3<<<dim3(PSB),dim3(256),0,stream>>>(part, boff, indptr);
  // 6. csr fill + A^2 diag + mask compact
  k_phase4<<<GRID1(EE+NN)>>>(row, col, indptr, fillc, csr_r, hash, diagint, mp, scal, mlist, minv);

  // GCN0
  k_mm_h0v<<<GRID1(NN*16)>>>(x, W0, A);
  g_gcn0<<<GRIDW>>>(indptr, csr_r, dinv0, A, b0, C);

  // TopK selection (set only; labeling is equivariant)
  k_scorekey<<<GRIDW>>>(C, pw, keys, score);
  for (int r2=0;r2<4;r2++){
    k_hist<<<GRID1(NN)>>>(keys, hist + r2*65536, selp, r2);
    k_pick<<<dim3(1),dim3(256),0,stream>>>(hist + r2*65536, selp, scal);
  }
  // kpmark + pooled ts
  k_mid<<<GRID1(EE+NN)>>>(row, col, keys, selp, kp, ts);
  k_colsum<<<GRID1(EE+NN)>>>(row, col, ts, cs);
  k_dinv1<<<GRID1(NN)>>>(cs, diagint, kp, dinv1);

  // pooled GCN: hp then two gather passes
  k_mm64sv<<<GRID1(NN*16)>>>(C, W1, score, kp, Ebuf);
  g_t2<<<GRIDW>>>(indptr, csr_r, dinv1, Ebuf, A);

  // LSTM0 on x1 windows -> Hbuf (compact)
  k_xw<<<GRID1(NN*64)>>>(C, WT0, bs0, XW);
  k_rec<<<dim3(1024),dim3(256),0,stream>>>(XW, l0whh, bs0, mlist, scal, Hbuf, 0);

  // y = res + up (fused: base select + relu(x2))
  g_agg2y<<<GRIDW>>>(indptr, csr_r, A, Ebuf, dinv1, diagint, kp, b1, C, Hbuf, minv, D);

  // up-GCN -> xo (B) and d_out
  k_mm64v<<<GRID1(NN*16)>>>(D, Wu, Ebuf);
  g_up<<<GRIDW>>>(indptr, csr_r, dinv0, Ebuf, bu, B, (float*)d_out);

  // final LSTM on xo windows, scatter into d_out masked rows
  k_xw<<<GRID1(NN*64)>>>(B, WTf, bsf, XW);
  k_rec<<<dim3(1024),dim3(256),0,stream>>>(XW, lfwhh, bsf, mlist, scal, (float*)d_out, 1);
  #undef GRIDW
  #undef GRID1
}

// Round 6
// 769.973 us; speedup vs baseline: 3.4529x; 1.1926x over previous
//
#include <hip/hip_runtime.h>
#include <math.h>

// Problem constants (fixed by reference setup)
#define NN 50000
#define EE 400000
#define CINV 32
#define KKEEP 25000          // ceil(0.5*N)
#define SEQL 5
#define HASH_BITS 20
#define HASH_SIZE (1u<<HASH_BITS)
#define HASH_MASK (HASH_SIZE-1u)
#define HEMPTY 0xFFFFFFFFu
#define PSB 196              // ceil(NN/256)

typedef float vf4 __attribute__((ext_vector_type(4)));

__device__ __forceinline__ float sigm(float x){ return 1.f/(1.f+__expf(-x)); }

// ---------------- merged init (+ LSTM weight prep) ----------------
__global__ void k_init(uint2* __restrict__ hash, unsigned* __restrict__ hist,
                       int* __restrict__ degcnt, int* __restrict__ diagint,
                       int* __restrict__ ts, int* __restrict__ cs,
                       int* __restrict__ fillc, int* __restrict__ minv,
                       unsigned* scal, unsigned long long* selp,
                       const float* __restrict__ w0, const float* __restrict__ b0i,
                       const float* __restrict__ b0h, const float* __restrict__ wf,
                       const float* __restrict__ bfi, const float* __restrict__ bfh,
                       float* __restrict__ WT0, float* __restrict__ WTf,
                       float* __restrict__ bs0, float* __restrict__ bsf){
  int i = blockIdx.x*256 + threadIdx.x;
  if (i < (int)HASH_SIZE) hash[i] = make_uint2(HEMPTY, 0u);
  if (i < 4*65536) hist[i] = 0u;
  if (i < NN){ degcnt[i]=0; diagint[i]=0; ts[i]=0; cs[i]=0; fillc[i]=0; minv[i]=-1; }
  if (i < 256*64){
    int g = i>>6, k = i&63;
    WT0[k*256+g] = w0[i];
    WTf[k*256+g] = wf[i];
  }
  if (i < 256){ bs0[i]=b0i[i]+b0h[i]; bsf[i]=bfi[i]+bfh[i]; }
  if (i == 0){ scal[0]=0u; scal[1]=0u; scal[3]=KKEEP; selp[0]=0ull; }
}

// ---------------- degcnt + hash build + mask-dtype detect ----------------
__global__ void k_phase2(const int* __restrict__ row, const int* __restrict__ col,
                         const int* __restrict__ mp, int* __restrict__ degcnt,
                         uint2* __restrict__ tab, unsigned* scal){
  int e = blockIdx.x*256 + threadIdx.x;
  if (e < EE){
    int c = col[e];
    atomicAdd(&degcnt[c], 1);
    unsigned key = (unsigned)row[e]*50000u + (unsigned)c;
    unsigned h = (key*2654435761u) >> (32-HASH_BITS);
    for(;;){
      unsigned old = atomicCAS(&tab[h].x, HEMPTY, key);
      if (old==HEMPTY || old==key){ atomicAdd(&tab[h].y, 1u); break; }
      h = (h+1)&HASH_MASK;
    }
  }
  if (e < NN/4){ if ((unsigned)mp[e] > 1u) atomicOr(&scal[1], 1u); }
}

// ---------------- prefix sum (indptr) + dinv0 ----------------
__global__ void k_psum1(const int* __restrict__ deg, int* __restrict__ part,
                        int* __restrict__ bsum, float* __restrict__ dinv){
  __shared__ int sc[256];
  int b = blockIdx.x, t = threadIdx.x, i = b*256+t;
  int v = (i<NN) ? deg[i] : 0;
  if (i < NN) dinv[i] = rsqrtf((float)v + 2.0f);
  sc[t] = v; __syncthreads();
  for (int o=1;o<256;o<<=1){
    int x = (t>=o) ? sc[t-o] : 0;
    __syncthreads();
    sc[t] += x;
    __syncthreads();
  }
  if (i < NN) part[i] = sc[t]-v;
  if (t == 255) bsum[b] = sc[255];
}
__global__ void k_psum2(const int* __restrict__ bsum, int* __restrict__ boff){
  __shared__ int sc[256];
  int t = threadIdx.x;
  int v = (t<PSB) ? bsum[t] : 0;
  sc[t] = v; __syncthreads();
  for (int o=1;o<256;o<<=1){
    int x = (t>=o) ? sc[t-o] : 0;
    __syncthreads();
    sc[t] += x;
    __syncthreads();
  }
  if (t < PSB) boff[t] = sc[t]-v;
}
__global__ void k_psum3(const int* __restrict__ part, const int* __restrict__ boff,
                        int* __restrict__ indptr){
  int i = blockIdx.x*256 + threadIdx.x;
  if (i < NN) indptr[i] = part[i] + boff[blockIdx.x];
  if (i == 0) indptr[NN] = EE;
}

// ---------------- csr fill + A^2 diag + mask compact ----------------
__global__ void k_phase4(const int* __restrict__ row, const int* __restrict__ col,
                         const int* __restrict__ indptr, int* __restrict__ fillc,
                         int* __restrict__ csr_r, const uint2* __restrict__ tab,
                         int* __restrict__ diagint, const void* __restrict__ mp,
                         unsigned* scal, int* __restrict__ mlist, int* __restrict__ minv){
  int idx = blockIdx.x*256 + threadIdx.x;
  if (idx < EE){
    int r = row[idx], c = col[idx];
    int pos = indptr[c] + atomicAdd(&fillc[c], 1);
    csr_r[pos] = r;
    unsigned rkey = (unsigned)c*50000u + (unsigned)r;
    unsigned h = (rkey*2654435761u) >> (32-HASH_BITS);
    for(;;){
      unsigned kk = tab[h].x;
      if (kk==rkey){ atomicAdd(&diagint[r], (int)tab[h].y); break; }
      if (kk==HEMPTY) break;
      h = (h+1)&HASH_MASK;
    }
  } else {
    int i = idx - EE;
    if (i < NN){
      int mv = scal[1] ? (int)((const unsigned char*)mp)[i] : ((const int*)mp)[i];
      if (mv){ int p = (int)atomicAdd(&scal[0], 1u); mlist[p] = i; minv[i] = p; }
    }
  }
}

// ---------------- matmuls (float4 outputs) ----------------
__global__ void k_mm_h0v(const float* __restrict__ X, const float* __restrict__ W, float* __restrict__ Y){
  int idx = blockIdx.x*256 + threadIdx.x;
  if (idx >= NN*16) return;
  int i = idx>>4, fq = idx&15;
  const vf4* X4 = (const vf4*)&X[i*CINV];
  const vf4* W4 = (const vf4*)W;
  vf4 acc = {0.f,0.f,0.f,0.f};
  #pragma unroll
  for (int kq=0;kq<CINV/4;kq++){
    vf4 xv = X4[kq];
    #pragma unroll
    for (int u=0;u<4;u++) acc += xv[u] * W4[(kq*4+u)*16+fq];
  }
  ((vf4*)Y)[i*16+fq] = acc;
}
__global__ void k_mm64v(const float* __restrict__ X, const float* __restrict__ W, float* __restrict__ Y){
  int idx = blockIdx.x*256 + threadIdx.x;
  if (idx >= NN*16) return;
  int i = idx>>4, fq = idx&15;
  const vf4* X4 = (const vf4*)&X[i*64];
  const vf4* W4 = (const vf4*)W;
  vf4 acc = {0.f,0.f,0.f,0.f};
  #pragma unroll
  for (int kq=0;kq<16;kq++){
    vf4 xv = X4[kq];
    #pragma unroll
    for (int u=0;u<4;u++) acc += xv[u] * W4[(kq*4+u)*16+fq];
  }
  ((vf4*)Y)[i*16+fq] = acc;
}
__global__ void k_mm64sv(const float* __restrict__ X, const float* __restrict__ W,
                         const float* __restrict__ sc, const int* __restrict__ kp,
                         float* __restrict__ Y){
  int idx = blockIdx.x*256 + threadIdx.x;
  if (idx >= NN*16) return;
  int i = idx>>4, fq = idx&15;
  if (!kp[i]) return;
  const vf4* X4 = (const vf4*)&X[i*64];
  const vf4* W4 = (const vf4*)W;
  vf4 acc = {0.f,0.f,0.f,0.f};
  #pragma unroll
  for (int kq=0;kq<16;kq++){
    vf4 xv = X4[kq];
    #pragma unroll
    for (int u=0;u<4;u++) acc += xv[u] * W4[(kq*4+u)*16+fq];
  }
  float s = sc[i];
  acc *= s;
  ((vf4*)Y)[i*16+fq] = acc;
}

// ---------------- CSR gather GCN kernels (wave per node) ----------------
// g_gcn0 fused with TopK score/key computation (uses x1 value still in regs).
__global__ void g_gcn0(const int* __restrict__ indptr, const int* __restrict__ csr_r,
                       const float* __restrict__ dinv, const float* __restrict__ H,
                       const float* __restrict__ b, const float* __restrict__ pw,
                       float* __restrict__ out, unsigned long long* __restrict__ keys,
                       float* __restrict__ score){
  int node = blockIdx.x*4 + (threadIdx.x>>6), lane = threadIdx.x&63;
  if (node >= NN) return;
  int s = __builtin_amdgcn_readfirstlane(indptr[node]);
  int e = __builtin_amdgcn_readfirstlane(indptr[node+1]);
  float acc = 0.f;
  for (int j=s;j<e;j++){
    int r = __builtin_amdgcn_readfirstlane(csr_r[j]);
    acc += dinv[r]*H[r*64+lane];
  }
  float di = dinv[node];
  float v = di*acc + 2.f*di*di*H[node*64+lane] + b[lane];
  float x1v = fmaxf(v, 0.f);
  out[node*64+lane] = x1v;
  // fused TopK score: s = tanh((x1 . pw)/||pw||)
  float pv = pw[lane];
  float nq = pv*pv;
  float dq = x1v*pv;
  for (int o=32;o;o>>=1){ nq += __shfl_down(nq, o, 64); dq += __shfl_down(dq, o, 64); }
  if (lane==0){
    float sv = tanhf(dq / sqrtf(nq));
    sv = sv + 0.0f;               // canonicalize -0 -> +0
    score[node] = sv;
    unsigned u = __float_as_uint(sv);
    unsigned asc = (u>>31) ? ~u : (u | 0x80000000u);
    keys[node] = (((unsigned long long)(~asc))<<32) | (unsigned)node;
  }
}
__global__ void g_t2(const int* __restrict__ indptr, const int* __restrict__ csr_r,
                     const float* __restrict__ dinv1, const float* __restrict__ hp,
                     float* __restrict__ t2){
  int node = blockIdx.x*4 + (threadIdx.x>>6), lane = threadIdx.x&63;
  if (node >= NN) return;
  int s = __builtin_amdgcn_readfirstlane(indptr[node]);
  int e = __builtin_amdgcn_readfirstlane(indptr[node+1]);
  float acc = dinv1[node]*hp[node*64+lane];        // self loop
  for (int j=s;j<e;j++){
    int r = __builtin_amdgcn_readfirstlane(csr_r[j]);
    float dr = dinv1[r];
    if (dr != 0.f) acc += dr*hp[r*64+lane];
  }
  t2[node*64+lane] = acc;
}
// D[i] = (masked ? H0[minv[i]] : C[i]) + (kept ? relu(x2_i) : 0)
__global__ void g_agg2y(const int* __restrict__ indptr, const int* __restrict__ csr_r,
                        const float* __restrict__ t2, const float* __restrict__ hp,
                        const float* __restrict__ dinv1, const int* __restrict__ diagint,
                        const int* __restrict__ kp, const float* __restrict__ b1,
                        const float* __restrict__ C, const float* __restrict__ Hbuf,
                        const int* __restrict__ minv, float* __restrict__ D){
  int node = blockIdx.x*4 + (threadIdx.x>>6), lane = threadIdx.x&63;
  if (node >= NN) return;
  int mv = minv[node];
  float base = (mv >= 0) ? Hbuf[(size_t)mv*64+lane] : C[node*64+lane];
  float add = 0.f;
  if (kp[node]){
    int s = __builtin_amdgcn_readfirstlane(indptr[node]);
    int e = __builtin_amdgcn_readfirstlane(indptr[node+1]);
    float acc = t2[node*64+lane];                  // self loop
    for (int j=s;j<e;j++){
      int r = __builtin_amdgcn_readfirstlane(csr_r[j]);
      acc += t2[r*64+lane];
    }
    float di = dinv1[node], hv = hp[node*64+lane];
    float diag = (float)(diagint[node] + 1);
    float v = di*(acc - diag*di*hv) + 2.f*di*di*hv + b1[lane];
    add = fmaxf(v, 0.f);
  }
  D[node*64+lane] = base + add;
}
__global__ void g_up(const int* __restrict__ indptr, const int* __restrict__ csr_r,
                     const float* __restrict__ dinv, const float* __restrict__ H,
                     const float* __restrict__ b, float* __restrict__ xo, float* __restrict__ out){
  int node = blockIdx.x*4 + (threadIdx.x>>6), lane = threadIdx.x&63;
  if (node >= NN) return;
  int s = __builtin_amdgcn_readfirstlane(indptr[node]);
  int e = __builtin_amdgcn_readfirstlane(indptr[node+1]);
  float acc = 0.f;
  for (int j=s;j<e;j++){
    int r = __builtin_amdgcn_readfirstlane(csr_r[j]);
    acc += dinv[r]*H[r*64+lane];
  }
  float di = dinv[node];
  float v = di*acc + 2.f*di*di*H[node*64+lane] + b[lane];
  xo[node*64+lane] = v; out[node*64+lane] = v;
}

// ---------------- TopK radix select ----------------
__global__ void k_hist(const unsigned long long* __restrict__ keys, unsigned* __restrict__ hist,
                       const unsigned long long* __restrict__ selp, int round){
  int i = blockIdx.x*256 + threadIdx.x;
  if (i >= NN) return;
  unsigned long long key = keys[i];
  int shift = 48 - 16*round;
  if (round==0 || (key>>(shift+16)) == selp[0])
    atomicAdd(&hist[(unsigned)((key>>shift)&0xFFFFull)], 1u);
}
__global__ void k_pick(const unsigned* __restrict__ hist, unsigned long long* selp, unsigned* scal){
  __shared__ unsigned csum[256];
  __shared__ unsigned bins[256];
  __shared__ int schunk;
  int t = threadIdx.x;
  const uint4* h4 = (const uint4*)(hist + t*256);
  unsigned s = 0;
  #pragma unroll 8
  for (int j=0;j<64;j++){ uint4 v = h4[j]; s += v.x+v.y+v.z+v.w; }
  csum[t] = s;
  __syncthreads();
  if (t==0){
    unsigned rem = scal[3];
    int chunk = 255;
    for (int c2=0;c2<256;c2++){ unsigned cc=csum[c2]; if (rem>cc) rem-=cc; else { chunk=c2; break; } }
    schunk = chunk; scal[3] = rem;
  }
  __syncthreads();
  bins[t] = hist[schunk*256 + t];
  __syncthreads();
  if (t==0){
    unsigned rem = scal[3];
    int bin = schunk*256 + 255;
    for (int b=0;b<256;b++){ unsigned hv=bins[b]; if (rem>hv) rem-=hv; else { bin = schunk*256 + b; break; } }
    selp[0] = (selp[0]<<16) | (unsigned long long)(unsigned)bin;
    scal[3] = rem;
  }
}
// kpmark + pooled-degree first SpMV (ts)
__global__ void k_mid(const int* __restrict__ row, const int* __restrict__ col,
                      const unsigned long long* __restrict__ keys,
                      const unsigned long long* __restrict__ selp,
                      int* __restrict__ kp, int* __restrict__ ts){
  int idx = blockIdx.x*256 + threadIdx.x;
  unsigned long long sp = selp[0];
  if (idx < EE){
    if (keys[row[idx]] <= sp) atomicAdd(&ts[col[idx]], 1);
  } else {
    int i = idx - EE;
    if (i < NN){
      int k = (keys[i] <= sp) ? 1 : 0;
      kp[i] = k;
      if (k) atomicAdd(&ts[i], 1);
    }
  }
}
__global__ void k_colsum(const int* __restrict__ row, const int* __restrict__ col,
                         const int* __restrict__ ts, int* __restrict__ cs){
  int idx = blockIdx.x*256 + threadIdx.x;
  if (idx < EE){ int v = ts[row[idx]]; if (v) atomicAdd(&cs[col[idx]], v); }
  else { int i = idx-EE; if (i < NN){ int v = ts[i]; if (v) atomicAdd(&cs[i], v); } }
}
__global__ void k_dinv1(const int* __restrict__ cs, const int* __restrict__ diagint,
                        const int* __restrict__ kp, float* __restrict__ dinv1){
  int i = blockIdx.x*256 + threadIdx.x;
  if (i >= NN) return;
  dinv1[i] = kp[i] ? rsqrtf((float)(cs[i] - diagint[i] - 1) + 2.0f) : 0.f;
}

// ---------------- LSTM part 1: XW[n] = src[n] @ W_ih^T + (b_ih+b_hh) ----------------
// Weights staged ONCE per block in 64 KB LDS (2 blocks/CU); waves grid-stride
// over nodes reading weights at LDS bandwidth instead of re-streaming 64 KB
// from L2 per node (R5's 3.2 GB L2 traffic -> ~0). X row reads are
// wave-uniform broadcasts; accumulator is a single vf4 (no spill risk).
__global__ __launch_bounds__(256) void k_xw(const float* __restrict__ src,
        const float* __restrict__ WT, const float* __restrict__ bsum,
        float* __restrict__ XW){
  __shared__ vf4 Wl[4096];              // 64 KB: WT[k][g] as vf4[(k*4+u)*64+fq]
  int t = threadIdx.x;
  const vf4* Wg = (const vf4*)WT;
  for (int u=t; u<4096; u+=256) Wl[u] = Wg[u];
  int fq = t & 63, wv = t >> 6;
  vf4 bias = ((const vf4*)bsum)[fq];
  __syncthreads();
  for (int node = blockIdx.x*4 + wv; node < NN; node += gridDim.x*4){
    const vf4* X4 = (const vf4*)&src[(size_t)node*64];
    vf4 acc = bias;
    #pragma unroll 4
    for (int kq=0;kq<16;kq++){
      vf4 xv = X4[kq];
      acc += xv.x * Wl[(kq*4+0)*64+fq];
      acc += xv.y * Wl[(kq*4+1)*64+fq];
      acc += xv.z * Wl[(kq*4+2)*64+fq];
      acc += xv.w * Wl[(kq*4+3)*64+fq];
    }
    ((vf4*)XW)[(size_t)node*64+fq] = acc;
  }
}

// ---------------- LSTM part 2: recurrence (hh-half only) ----------------
// 4 nodes/block; wave w holds W_hh rows [w*64+lane] (16 vf4 = 64 VGPRs) and
// computes gate chunk w for all 4 nodes. Gate-x terms read from XW (coalesced).
__global__ __launch_bounds__(256) void k_rec(const float* __restrict__ XW,
        const float* __restrict__ whh, const float* __restrict__ bsum,
        const int* __restrict__ mlist, const unsigned* __restrict__ scal,
        float* __restrict__ dst, int scatter){
  int M = (int)scal[0];
  if (M < 0 || M > NN) M = 0;          // defensive (rocprof replay poisons scal)
  int w = threadIdx.x>>6, lane = threadIdx.x&63;
  int r = w*64 + lane;
  const vf4* g4 = (const vf4*)&whh[(size_t)r*64];
  vf4 wh[16];
  #pragma unroll
  for (int j=0;j<16;j++) wh[j] = g4[j];
  __shared__ float sh[4][64];
  __shared__ float gates[4][4][64];
  int ntask = (M+3)>>2;
  for (int task = blockIdx.x; task < ntask; task += gridDim.x){
    int m = task*4 + w;
    bool valid = (m < M);
    int node = mlist[valid ? m : (M-1)];
    float c, h;
    {   // t = 0: h==0, gates = XW row (bias-only row if left-padded: node<4)
      int rowi = node - (SEQL-1);
      float g0,g1,g2,g3;
      if (rowi >= 0){
        const float* p = &XW[(size_t)rowi*256];
        g0=p[lane]; g1=p[64+lane]; g2=p[128+lane]; g3=p[192+lane];
      } else {
        g0=bsum[lane]; g1=bsum[64+lane]; g2=bsum[128+lane]; g3=bsum[192+lane];
      }
      c = sigm(g0)*tanhf(g2);
      h = sigm(g3)*tanhf(c);
      sh[w][lane] = h;
    }
    __syncthreads();
    for (int t=1;t<SEQL;t++){
      vf4 a0={0,0,0,0}, a1={0,0,0,0}, a2={0,0,0,0}, a3={0,0,0,0};
      #pragma unroll
      for (int j=0;j<16;j++){
        vf4 wj = wh[j];
        a0 += (*(const vf4*)&sh[0][j*4]) * wj;
        a1 += (*(const vf4*)&sh[1][j*4]) * wj;
        a2 += (*(const vf4*)&sh[2][j*4]) * wj;
        a3 += (*(const vf4*)&sh[3][j*4]) * wj;
      }
      gates[0][w][lane] = a0.x+a0.y+a0.z+a0.w;
      gates[1][w][lane] = a1.x+a1.y+a1.z+a1.w;
      gates[2][w][lane] = a2.x+a2.y+a2.z+a2.w;
      gates[3][w][lane] = a3.x+a3.y+a3.z+a3.w;
      __syncthreads();
      int rowi = node - (SEQL-1) + t;
      float x0,x1,x2,x3;
      if (rowi >= 0){
        const float* p = &XW[(size_t)rowi*256];
        x0=p[lane]; x1=p[64+lane]; x2=p[128+lane]; x3=p[192+lane];
      } else {
        x0=bsum[lane]; x1=bsum[64+lane]; x2=bsum[128+lane]; x3=bsum[192+lane];
      }
      float gi = gates[w][0][lane] + x0;
      float gf = gates[w][1][lane] + x1;
      float gg = gates[w][2][lane] + x2;
      float go = gates[w][3][lane] + x3;
      c = sigm(gf)*c + sigm(gi)*tanhf(gg);
      h = sigm(go)*tanhf(c);
      sh[w][lane] = h;
      __syncthreads();
    }
    if (valid){
      size_t o = scatter ? ((size_t)node*64 + lane) : ((size_t)m*64 + lane);
      dst[o] = h;
    }
  }
}

// ==========================================================================
extern "C" void kernel_launch(void* const* d_in, const int* in_sizes, int n_in,
                              void* d_out, int out_size, void* d_ws, size_t ws_size,
                              hipStream_t stream) {
  const float* x   = (const float*)d_in[0];
  const int*   ei  = (const int*)d_in[1];
  const int*   row = ei;
  const int*   col = ei + EE;
  const void*  mp  = d_in[2];
  const float* W0  = (const float*)d_in[3];
  const float* b0  = (const float*)d_in[4];
  const float* W1  = (const float*)d_in[5];
  const float* b1  = (const float*)d_in[6];
  const float* pw  = (const float*)d_in[7];
  const float* Wu  = (const float*)d_in[8];
  const float* bu  = (const float*)d_in[9];
  const float* l0wih=(const float*)d_in[10];
  const float* l0whh=(const float*)d_in[11];
  const float* l0bih=(const float*)d_in[12];
  const float* l0bhh=(const float*)d_in[13];
  const float* lfwih=(const float*)d_in[14];
  const float* lfwhh=(const float*)d_in[15];
  const float* lfbih=(const float*)d_in[16];
  const float* lfbhh=(const float*)d_in[17];

  char* wp = (char*)d_ws;
  auto alloc = [&](size_t bytes)->char*{ char* p = wp; wp += ((bytes+255)/256)*256; return p; };
  float* A     = (float*)alloc((size_t)NN*64*4);   // h0 -> t2
  float* B     = (float*)alloc((size_t)NN*64*4);   // xo
  float* C     = (float*)alloc((size_t)NN*64*4);   // x1
  float* D     = (float*)alloc((size_t)NN*64*4);   // y
  float* Ebuf  = (float*)alloc((size_t)NN*64*4);   // hp -> up-GCN input
  float* Hbuf  = (float*)alloc((size_t)NN*64*4);   // LSTM0 compact output
  float* XW    = (float*)alloc((size_t)NN*256*4);  // gate-x precompute (51.2 MB)
  float* WT0   = (float*)alloc((size_t)256*64*4);
  float* WTf   = (float*)alloc((size_t)256*64*4);
  float* bs0   = (float*)alloc((size_t)256*4);
  float* bsf   = (float*)alloc((size_t)256*4);
  float* score = (float*)alloc((size_t)NN*4);
  float* dinv0 = (float*)alloc((size_t)NN*4);
  float* dinv1 = (float*)alloc((size_t)NN*4);
  unsigned long long* keys = (unsigned long long*)alloc((size_t)NN*8);
  int* degcnt  = (int*)alloc((size_t)NN*4);
  int* diagint = (int*)alloc((size_t)NN*4);
  int* ts      = (int*)alloc((size_t)NN*4);
  int* cs      = (int*)alloc((size_t)NN*4);
  int* kp      = (int*)alloc((size_t)NN*4);
  int* mlist   = (int*)alloc((size_t)NN*4);
  int* minv    = (int*)alloc((size_t)NN*4);
  int* indptr  = (int*)alloc((size_t)(NN+1)*4);
  int* part    = (int*)alloc((size_t)NN*4);
  int* fillc   = (int*)alloc((size_t)NN*4);
  int* bsum    = (int*)alloc((size_t)256*4);
  int* boff    = (int*)alloc((size_t)256*4);
  int* csr_r   = (int*)alloc((size_t)EE*4);
  uint2* hash  = (uint2*)alloc((size_t)HASH_SIZE*8);
  unsigned* hist=(unsigned*)alloc((size_t)4*65536*4);
  unsigned* scal=(unsigned*)alloc(256);
  unsigned long long* selp = (unsigned long long*)(scal + 4);

  #define GRID1(n) dim3(((n)+255)/256), dim3(256), 0, stream
  #define GRIDW dim3((NN+3)/4), dim3(256), 0, stream

  // 1. merged init (hash, hist, per-node arrays, scalars, LSTM weight prep)
  k_init<<<GRID1(HASH_SIZE)>>>(hash, hist, degcnt, diagint, ts, cs, fillc, minv,
                               scal, selp, l0wih, l0bih, l0bhh, lfwih, lfbih, lfbhh,
                               WT0, WTf, bs0, bsf);
  // 2. degcnt + hash build + mask-dtype detect
  k_phase2<<<GRID1(EE)>>>(row, col, (const int*)mp, degcnt, hash, scal);
  // 3-5. indptr prefix sum (+dinv0)
  k_psum1<<<dim3(PSB),dim3(256),0,stream>>>(degcnt, part, bsum, dinv0);
  k_psum2<<<dim3(1),dim3(256),0,stream>>>(bsum, boff);
  k_psum3<<<dim3(PSB),dim3(256),0,stream>>>(part, boff, indptr);
  // 6. csr fill + A^2 diag + mask compact
  k_phase4<<<GRID1(EE+NN)>>>(row, col, indptr, fillc, csr_r, hash, diagint, mp, scal, mlist, minv);

  // GCN0 (+ fused TopK score/key)
  k_mm_h0v<<<GRID1(NN*16)>>>(x, W0, A);
  g_gcn0<<<GRIDW>>>(indptr, csr_r, dinv0, A, b0, pw, C, keys, score);

  // TopK radix select
  for (int r2=0;r2<4;r2++){
    k_hist<<<GRID1(NN)>>>(keys, hist + r2*65536, selp, r2);
    k_pick<<<dim3(1),dim3(256),0,stream>>>(hist + r2*65536, selp, scal);
  }
  // kpmark + pooled ts
  k_mid<<<GRID1(EE+NN)>>>(row, col, keys, selp, kp, ts);
  k_colsum<<<GRID1(EE+NN)>>>(row, col, ts, cs);
  k_dinv1<<<GRID1(NN)>>>(cs, diagint, kp, dinv1);

  // pooled GCN: hp then two gather passes
  k_mm64sv<<<GRID1(NN*16)>>>(C, W1, score, kp, Ebuf);
  g_t2<<<GRIDW>>>(indptr, csr_r, dinv1, Ebuf, A);

  // LSTM0 on x1 windows -> Hbuf (compact)
  k_xw<<<dim3(512),dim3(256),0,stream>>>(C, WT0, bs0, XW);
  k_rec<<<dim3(1024),dim3(256),0,stream>>>(XW, l0whh, bs0, mlist, scal, Hbuf, 0);

  // y = res + up (fused: base select + relu(x2))
  g_agg2y<<<GRIDW>>>(indptr, csr_r, A, Ebuf, dinv1, diagint, kp, b1, C, Hbuf, minv, D);

  // up-GCN -> xo (B) and d_out
  k_mm64v<<<GRID1(NN*16)>>>(D, Wu, Ebuf);
  g_up<<<GRIDW>>>(indptr, csr_r, dinv0, Ebuf, bu, B, (float*)d_out);

  // final LSTM on xo windows, scatter into d_out masked rows
  k_xw<<<dim3(512),dim3(256),0,stream>>>(B, WTf, bsf, XW);
  k_rec<<<dim3(1024),dim3(256),0,stream>>>(XW, lfwhh, bsf, mlist, scal, (float*)d_out, 1);
  #undef GRIDW
  #undef GRID1
}

// Round 7
// 716.472 us; speedup vs baseline: 3.7107x; 1.0747x over previous
//
#include <hip/hip_runtime.h>
#include <math.h>

// Problem constants (fixed by reference setup)
#define NN 50000
#define EE 400000
#define CINV 32
#define KKEEP 25000          // ceil(0.5*N)
#define SEQL 5
#define HASH_BITS 20
#define HASH_SIZE (1u<<HASH_BITS)
#define HASH_MASK (HASH_SIZE-1u)
#define HEMPTY 0xFFFFFFFFu
#define PSB 196              // ceil(NN/256)

typedef float vf4 __attribute__((ext_vector_type(4)));

__device__ __forceinline__ float sigm(float x){ return __builtin_amdgcn_rcpf(1.f+__expf(-x)); }
__device__ __forceinline__ float ftanh(float x){ return 1.f - 2.f*__builtin_amdgcn_rcpf(1.f+__expf(2.f*x)); }

// ---------------- merged init (+ LSTM weight prep) ----------------
__global__ void k_init(uint2* __restrict__ hash, unsigned* __restrict__ hist,
                       int* __restrict__ degcnt, int* __restrict__ diagint,
                       int* __restrict__ fillc, int* __restrict__ minv,
                       unsigned* scal, unsigned long long* selp,
                       const float* __restrict__ w0, const float* __restrict__ b0i,
                       const float* __restrict__ b0h, const float* __restrict__ wf,
                       const float* __restrict__ bfi, const float* __restrict__ bfh,
                       float* __restrict__ WT0, float* __restrict__ WTf,
                       float* __restrict__ bs0, float* __restrict__ bsf){
  int i = blockIdx.x*256 + threadIdx.x;
  if (i < (int)HASH_SIZE) hash[i] = make_uint2(HEMPTY, 0u);
  if (i < 4*65536) hist[i] = 0u;
  if (i < NN){ degcnt[i]=0; diagint[i]=0; fillc[i]=0; minv[i]=-1; }
  if (i < 256*64){
    int g = i>>6, k = i&63;
    WT0[k*256+g] = w0[i];
    WTf[k*256+g] = wf[i];
  }
  if (i < 256){ bs0[i]=b0i[i]+b0h[i]; bsf[i]=bfi[i]+bfh[i]; }
  if (i == 0){ scal[0]=0u; scal[1]=0u; scal[3]=KKEEP; selp[0]=0ull; }
}

// ---------------- degcnt + hash build + mask-dtype detect ----------------
__global__ void k_phase2(const int* __restrict__ row, const int* __restrict__ col,
                         const int* __restrict__ mp, int* __restrict__ degcnt,
                         uint2* __restrict__ tab, unsigned* scal){
  int e = blockIdx.x*256 + threadIdx.x;
  if (e < EE){
    int c = col[e];
    atomicAdd(&degcnt[c], 1);
    unsigned key = (unsigned)row[e]*50000u + (unsigned)c;
    unsigned h = (key*2654435761u) >> (32-HASH_BITS);
    for(;;){
      unsigned old = atomicCAS(&tab[h].x, HEMPTY, key);
      if (old==HEMPTY || old==key){ atomicAdd(&tab[h].y, 1u); break; }
      h = (h+1)&HASH_MASK;
    }
  }
  if (e < NN/4){ if ((unsigned)mp[e] > 1u) atomicOr(&scal[1], 1u); }
}

// ---------------- prefix sum (indptr) + dinv0 ----------------
__global__ void k_psum1(const int* __restrict__ deg, int* __restrict__ part,
                        int* __restrict__ bsum, float* __restrict__ dinv){
  __shared__ int sc[256];
  int b = blockIdx.x, t = threadIdx.x, i = b*256+t;
  int v = (i<NN) ? deg[i] : 0;
  if (i < NN) dinv[i] = rsqrtf((float)v + 2.0f);
  sc[t] = v; __syncthreads();
  for (int o=1;o<256;o<<=1){
    int x = (t>=o) ? sc[t-o] : 0;
    __syncthreads();
    sc[t] += x;
    __syncthreads();
  }
  if (i < NN) part[i] = sc[t]-v;
  if (t == 255) bsum[b] = sc[255];
}
__global__ void k_psum2(const int* __restrict__ bsum, int* __restrict__ boff){
  __shared__ int sc[256];
  int t = threadIdx.x;
  int v = (t<PSB) ? bsum[t] : 0;
  sc[t] = v; __syncthreads();
  for (int o=1;o<256;o<<=1){
    int x = (t>=o) ? sc[t-o] : 0;
    __syncthreads();
    sc[t] += x;
    __syncthreads();
  }
  if (t < PSB) boff[t] = sc[t]-v;
}
__global__ void k_psum3(const int* __restrict__ part, const int* __restrict__ boff,
                        int* __restrict__ indptr){
  int i = blockIdx.x*256 + threadIdx.x;
  if (i < NN) indptr[i] = part[i] + boff[blockIdx.x];
  if (i == 0) indptr[NN] = EE;
}

// ---------------- csr fill + A^2 diag + mask compact ----------------
__global__ void k_phase4(const int* __restrict__ row, const int* __restrict__ col,
                         const int* __restrict__ indptr, int* __restrict__ fillc,
                         int* __restrict__ csr_r, const uint2* __restrict__ tab,
                         int* __restrict__ diagint, const void* __restrict__ mp,
                         unsigned* scal, int* __restrict__ mlist, int* __restrict__ minv){
  int idx = blockIdx.x*256 + threadIdx.x;
  if (idx < EE){
    int r = row[idx], c = col[idx];
    int pos = indptr[c] + atomicAdd(&fillc[c], 1);
    csr_r[pos] = r;
    unsigned rkey = (unsigned)c*50000u + (unsigned)r;
    unsigned h = (rkey*2654435761u) >> (32-HASH_BITS);
    for(;;){
      unsigned kk = tab[h].x;
      if (kk==rkey){ atomicAdd(&diagint[r], (int)tab[h].y); break; }
      if (kk==HEMPTY) break;
      h = (h+1)&HASH_MASK;
    }
  } else {
    int i = idx - EE;
    if (i < NN){
      int mv = scal[1] ? (int)((const unsigned char*)mp)[i] : ((const int*)mp)[i];
      if (mv){ int p = (int)atomicAdd(&scal[0], 1u); mlist[p] = i; minv[i] = p; }
    }
  }
}

// ---------------- matmuls (float4 outputs) ----------------
__global__ void k_mm_h0v(const float* __restrict__ X, const float* __restrict__ W, float* __restrict__ Y){
  int idx = blockIdx.x*256 + threadIdx.x;
  if (idx >= NN*16) return;
  int i = idx>>4, fq = idx&15;
  const vf4* X4 = (const vf4*)&X[i*CINV];
  const vf4* W4 = (const vf4*)W;
  vf4 acc = {0.f,0.f,0.f,0.f};
  #pragma unroll
  for (int kq=0;kq<CINV/4;kq++){
    vf4 xv = X4[kq];
    #pragma unroll
    for (int u=0;u<4;u++) acc += xv[u] * W4[(kq*4+u)*16+fq];
  }
  ((vf4*)Y)[i*16+fq] = acc;
}
__global__ void k_mm64v(const float* __restrict__ X, const float* __restrict__ W, float* __restrict__ Y){
  int idx = blockIdx.x*256 + threadIdx.x;
  if (idx >= NN*16) return;
  int i = idx>>4, fq = idx&15;
  const vf4* X4 = (const vf4*)&X[i*64];
  const vf4* W4 = (const vf4*)W;
  vf4 acc = {0.f,0.f,0.f,0.f};
  #pragma unroll
  for (int kq=0;kq<16;kq++){
    vf4 xv = X4[kq];
    #pragma unroll
    for (int u=0;u<4;u++) acc += xv[u] * W4[(kq*4+u)*16+fq];
  }
  ((vf4*)Y)[i*16+fq] = acc;
}
__global__ void k_mm64sv(const float* __restrict__ X, const float* __restrict__ W,
                         const float* __restrict__ sc, const int* __restrict__ kp,
                         float* __restrict__ Y){
  int idx = blockIdx.x*256 + threadIdx.x;
  if (idx >= NN*16) return;
  int i = idx>>4, fq = idx&15;
  if (!kp[i]) return;
  const vf4* X4 = (const vf4*)&X[i*64];
  const vf4* W4 = (const vf4*)W;
  vf4 acc = {0.f,0.f,0.f,0.f};
  #pragma unroll
  for (int kq=0;kq<16;kq++){
    vf4 xv = X4[kq];
    #pragma unroll
    for (int u=0;u<4;u++) acc += xv[u] * W4[(kq*4+u)*16+fq];
  }
  float s = sc[i];
  acc *= s;
  ((vf4*)Y)[i*16+fq] = acc;
}

// ---------------- CSR gather GCN kernels (wave per node) ----------------
// g_gcn0 fused with TopK score/key computation AND radix round-0 histogram.
__global__ void g_gcn0(const int* __restrict__ indptr, const int* __restrict__ csr_r,
                       const float* __restrict__ dinv, const float* __restrict__ H,
                       const float* __restrict__ b, const float* __restrict__ pw,
                       float* __restrict__ out, unsigned long long* __restrict__ keys,
                       float* __restrict__ score, unsigned* __restrict__ hist){
  int node = blockIdx.x*4 + (threadIdx.x>>6), lane = threadIdx.x&63;
  if (node >= NN) return;
  int s = __builtin_amdgcn_readfirstlane(indptr[node]);
  int e = __builtin_amdgcn_readfirstlane(indptr[node+1]);
  float acc = 0.f;
  for (int j=s;j<e;j++){
    int r = __builtin_amdgcn_readfirstlane(csr_r[j]);
    acc += dinv[r]*H[r*64+lane];
  }
  float di = dinv[node];
  float v = di*acc + 2.f*di*di*H[node*64+lane] + b[lane];
  float x1v = fmaxf(v, 0.f);
  out[node*64+lane] = x1v;
  // fused TopK score: s = tanh((x1 . pw)/||pw||)
  float pv = pw[lane];
  float nq = pv*pv;
  float dq = x1v*pv;
  for (int o=32;o;o>>=1){ nq += __shfl_down(nq, o, 64); dq += __shfl_down(dq, o, 64); }
  if (lane==0){
    float sv = tanhf(dq / sqrtf(nq));
    sv = sv + 0.0f;               // canonicalize -0 -> +0
    score[node] = sv;
    unsigned u = __float_as_uint(sv);
    unsigned asc = (u>>31) ? ~u : (u | 0x80000000u);
    unsigned desc = ~asc;
    keys[node] = (((unsigned long long)desc)<<32) | (unsigned)node;
    atomicAdd(&hist[desc>>16], 1u);      // radix round-0 histogram
  }
}
__global__ void g_t2(const int* __restrict__ indptr, const int* __restrict__ csr_r,
                     const float* __restrict__ dinv1, const float* __restrict__ hp,
                     float* __restrict__ t2){
  int node = blockIdx.x*4 + (threadIdx.x>>6), lane = threadIdx.x&63;
  if (node >= NN) return;
  int s = __builtin_amdgcn_readfirstlane(indptr[node]);
  int e = __builtin_amdgcn_readfirstlane(indptr[node+1]);
  float acc = dinv1[node]*hp[node*64+lane];        // self loop
  for (int j=s;j<e;j++){
    int r = __builtin_amdgcn_readfirstlane(csr_r[j]);
    float dr = dinv1[r];
    if (dr != 0.f) acc += dr*hp[r*64+lane];
  }
  t2[node*64+lane] = acc;
}
// D[i] = (masked ? H0[minv[i]] : C[i]) + (kept ? relu(x2_i) : 0)
__global__ void g_agg2y(const int* __restrict__ indptr, const int* __restrict__ csr_r,
                        const float* __restrict__ t2, const float* __restrict__ hp,
                        const float* __restrict__ dinv1, const int* __restrict__ diagint,
                        const int* __restrict__ kp, const float* __restrict__ b1,
                        const float* __restrict__ C, const float* __restrict__ Hbuf,
                        const int* __restrict__ minv, float* __restrict__ D){
  int node = blockIdx.x*4 + (threadIdx.x>>6), lane = threadIdx.x&63;
  if (node >= NN) return;
  int mv = minv[node];
  float base = (mv >= 0) ? Hbuf[(size_t)mv*64+lane] : C[node*64+lane];
  float add = 0.f;
  if (kp[node]){
    int s = __builtin_amdgcn_readfirstlane(indptr[node]);
    int e = __builtin_amdgcn_readfirstlane(indptr[node+1]);
    float acc = t2[node*64+lane];                  // self loop
    for (int j=s;j<e;j++){
      int r = __builtin_amdgcn_readfirstlane(csr_r[j]);
      acc += t2[r*64+lane];
    }
    float di = dinv1[node], hv = hp[node*64+lane];
    float diag = (float)(diagint[node] + 1);
    float v = di*(acc - diag*di*hv) + 2.f*di*di*hv + b1[lane];
    add = fmaxf(v, 0.f);
  }
  D[node*64+lane] = base + add;
}
__global__ void g_up(const int* __restrict__ indptr, const int* __restrict__ csr_r,
                     const float* __restrict__ dinv, const float* __restrict__ H,
                     const float* __restrict__ b, float* __restrict__ xo, float* __restrict__ out){
  int node = blockIdx.x*4 + (threadIdx.x>>6), lane = threadIdx.x&63;
  if (node >= NN) return;
  int s = __builtin_amdgcn_readfirstlane(indptr[node]);
  int e = __builtin_amdgcn_readfirstlane(indptr[node+1]);
  float acc = 0.f;
  for (int j=s;j<e;j++){
    int r = __builtin_amdgcn_readfirstlane(csr_r[j]);
    acc += dinv[r]*H[r*64+lane];
  }
  float di = dinv[node];
  float v = di*acc + 2.f*di*di*H[node*64+lane] + b[lane];
  xo[node*64+lane] = v; out[node*64+lane] = v;
}

// ---------------- TopK radix select (round 0 hist fused into g_gcn0) ----------------
__global__ void k_hist(const unsigned long long* __restrict__ keys, unsigned* __restrict__ hist,
                       const unsigned long long* __restrict__ selp, int round){
  int i = blockIdx.x*256 + threadIdx.x;
  if (i >= NN) return;
  unsigned long long key = keys[i];
  int shift = 48 - 16*round;
  if ((key>>(shift+16)) == selp[0])
    atomicAdd(&hist[(unsigned)((key>>shift)&0xFFFFull)], 1u);
}
__global__ void k_pick(const unsigned* __restrict__ hist, unsigned long long* selp, unsigned* scal){
  __shared__ unsigned csum[256];
  __shared__ unsigned bins[256];
  __shared__ int schunk;
  int t = threadIdx.x;
  const uint4* h4 = (const uint4*)(hist + t*256);
  unsigned s = 0;
  #pragma unroll 8
  for (int j=0;j<64;j++){ uint4 v = h4[j]; s += v.x+v.y+v.z+v.w; }
  csum[t] = s;
  __syncthreads();
  if (t==0){
    unsigned rem = scal[3];
    int chunk = 255;
    for (int c2=0;c2<256;c2++){ unsigned cc=csum[c2]; if (rem>cc) rem-=cc; else { chunk=c2; break; } }
    schunk = chunk; scal[3] = rem;
  }
  __syncthreads();
  bins[t] = hist[schunk*256 + t];
  __syncthreads();
  if (t==0){
    unsigned rem = scal[3];
    int bin = schunk*256 + 255;
    for (int b=0;b<256;b++){ unsigned hv=bins[b]; if (rem>hv) rem-=hv; else { bin = schunk*256 + b; break; } }
    selp[0] = (selp[0]<<16) | (unsigned long long)(unsigned)bin;
    scal[3] = rem;
  }
}
// pooled degree pass 1 (CSR gather, duplicate edges preserved by multiplicity):
// kp[i] = keys[i]<=sp; ts[i] = sum_{r->i} kp[r] + kp[i]
__global__ void k_tsg(const int* __restrict__ indptr, const int* __restrict__ csr_r,
                      const unsigned long long* __restrict__ keys,
                      const unsigned long long* __restrict__ selp,
                      int* __restrict__ kp, int* __restrict__ ts){
  int i = blockIdx.x*256 + threadIdx.x;
  if (i >= NN) return;
  unsigned long long sp = selp[0];
  int s = indptr[i], e = indptr[i+1];
  int self = (keys[i] <= sp) ? 1 : 0;
  kp[i] = self;
  int acc = self;
  for (int j=s;j<e;j++) acc += (keys[csr_r[j]] <= sp) ? 1 : 0;
  ts[i] = acc;
}
// pooled degree pass 2 + dinv1: cs[i] = sum_{r->i} ts[r] + ts[i]
__global__ void k_csg(const int* __restrict__ indptr, const int* __restrict__ csr_r,
                      const int* __restrict__ ts, const int* __restrict__ diagint,
                      const int* __restrict__ kp, float* __restrict__ dinv1){
  int i = blockIdx.x*256 + threadIdx.x;
  if (i >= NN) return;
  int s = indptr[i], e = indptr[i+1];
  int acc = ts[i];
  for (int j=s;j<e;j++) acc += ts[csr_r[j]];
  dinv1[i] = kp[i] ? rsqrtf((float)(acc - diagint[i] - 1) + 2.0f) : 0.f;
}

// ---------------- LSTM part 1: XW[n] = src[n] @ W_ih^T + (b_ih+b_hh) ----------------
__global__ __launch_bounds__(256) void k_xw(const float* __restrict__ src,
        const float* __restrict__ WT, const float* __restrict__ bsum,
        float* __restrict__ XW){
  __shared__ vf4 Wl[4096];              // 64 KB: WT[k][g] as vf4[(k*4+u)*64+fq]
  int t = threadIdx.x;
  const vf4* Wg = (const vf4*)WT;
  for (int u=t; u<4096; u+=256) Wl[u] = Wg[u];
  int fq = t & 63, wv = t >> 6;
  vf4 bias = ((const vf4*)bsum)[fq];
  __syncthreads();
  for (int node = blockIdx.x*4 + wv; node < NN; node += gridDim.x*4){
    const vf4* X4 = (const vf4*)&src[(size_t)node*64];
    vf4 acc = bias;
    #pragma unroll 4
    for (int kq=0;kq<16;kq++){
      vf4 xv = X4[kq];
      acc += xv.x * Wl[(kq*4+0)*64+fq];
      acc += xv.y * Wl[(kq*4+1)*64+fq];
      acc += xv.z * Wl[(kq*4+2)*64+fq];
      acc += xv.w * Wl[(kq*4+3)*64+fq];
    }
    ((vf4*)XW)[(size_t)node*64+fq] = acc;
  }
}

// ---------------- LSTM part 2: recurrence (hh-half only) ----------------
// 4 nodes/block; wave w holds W_hh rows [w*64+lane] (16 vf4) and computes gate
// chunk w for all 4 nodes. Wave w also prefetches node w's XW row for timestep
// t BEFORE the gates FMA loop, so the global-load latency overlaps compute
// instead of stalling the post-barrier epilogue (R6: VALUBusy 48%).
__global__ __launch_bounds__(256) void k_rec(const float* __restrict__ XW,
        const float* __restrict__ whh, const float* __restrict__ bsum,
        const int* __restrict__ mlist, const unsigned* __restrict__ scal,
        float* __restrict__ dst, int scatter){
  int M = (int)scal[0];
  if (M < 0 || M > NN) M = 0;          // defensive (rocprof replay poisons scal)
  int w = threadIdx.x>>6, lane = threadIdx.x&63;
  int r = w*64 + lane;
  const vf4* g4 = (const vf4*)&whh[(size_t)r*64];
  vf4 wh[16];
  #pragma unroll
  for (int j=0;j<16;j++) wh[j] = g4[j];
  __shared__ float sh[4][64];
  __shared__ float gates[4][4][64];
  int ntask = (M+3)>>2;
  for (int task = blockIdx.x; task < ntask; task += gridDim.x){
    int m = task*4 + w;
    bool valid = (m < M);
    int node = mlist[valid ? m : (M-1)];
    node = min(max(node, 0), NN-1);    // defensive vs poisoned mlist in replay
    float c, h;
    float x0,x1,x2,x3;
    {   // t = 0: h==0, gates = XW row (bias-only if left-padded)
      int rowi = node - (SEQL-1);
      if (rowi >= 0){
        const float* p = &XW[(size_t)rowi*256];
        x0=p[lane]; x1=p[64+lane]; x2=p[128+lane]; x3=p[192+lane];
      } else {
        x0=bsum[lane]; x1=bsum[64+lane]; x2=bsum[128+lane]; x3=bsum[192+lane];
      }
      c = sigm(x0)*ftanh(x2);
      h = sigm(x3)*ftanh(c);
      sh[w][lane] = h;
    }
    __syncthreads();
    for (int t=1;t<SEQL;t++){
      // prefetch this timestep's gate-x row (wave w -> its own node)
      int rowi = node - (SEQL-1) + t;
      if (rowi >= 0){
        const float* p = &XW[(size_t)rowi*256];
        x0=p[lane]; x1=p[64+lane]; x2=p[128+lane]; x3=p[192+lane];
      } else {
        x0=bsum[lane]; x1=bsum[64+lane]; x2=bsum[128+lane]; x3=bsum[192+lane];
      }
      vf4 a0={0,0,0,0}, a1={0,0,0,0}, a2={0,0,0,0}, a3={0,0,0,0};
      #pragma unroll
      for (int j=0;j<16;j++){
        vf4 wj = wh[j];
        a0 += (*(const vf4*)&sh[0][j*4]) * wj;
        a1 += (*(const vf4*)&sh[1][j*4]) * wj;
        a2 += (*(const vf4*)&sh[2][j*4]) * wj;
        a3 += (*(const vf4*)&sh[3][j*4]) * wj;
      }
      gates[0][w][lane] = a0.x+a0.y+a0.z+a0.w;
      gates[1][w][lane] = a1.x+a1.y+a1.z+a1.w;
      gates[2][w][lane] = a2.x+a2.y+a2.z+a2.w;
      gates[3][w][lane] = a3.x+a3.y+a3.z+a3.w;
      __syncthreads();
      float gi = gates[w][0][lane] + x0;
      float gf = gates[w][1][lane] + x1;
      float gg = gates[w][2][lane] + x2;
      float go = gates[w][3][lane] + x3;
      c = sigm(gf)*c + sigm(gi)*ftanh(gg);
      h = sigm(go)*ftanh(c);
      sh[w][lane] = h;
      __syncthreads();
    }
    if (valid){
      size_t o = scatter ? ((size_t)node*64 + lane) : ((size_t)m*64 + lane);
      dst[o] = h;
    }
  }
}

// ==========================================================================
extern "C" void kernel_launch(void* const* d_in, const int* in_sizes, int n_in,
                              void* d_out, int out_size, void* d_ws, size_t ws_size,
                              hipStream_t stream) {
  const float* x   = (const float*)d_in[0];
  const int*   ei  = (const int*)d_in[1];
  const int*   row = ei;
  const int*   col = ei + EE;
  const void*  mp  = d_in[2];
  const float* W0  = (const float*)d_in[3];
  const float* b0  = (const float*)d_in[4];
  const float* W1  = (const float*)d_in[5];
  const float* b1  = (const float*)d_in[6];
  const float* pw  = (const float*)d_in[7];
  const float* Wu  = (const float*)d_in[8];
  const float* bu  = (const float*)d_in[9];
  const float* l0wih=(const float*)d_in[10];
  const float* l0whh=(const float*)d_in[11];
  const float* l0bih=(const float*)d_in[12];
  const float* l0bhh=(const float*)d_in[13];
  const float* lfwih=(const float*)d_in[14];
  const float* lfwhh=(const float*)d_in[15];
  const float* lfbih=(const float*)d_in[16];
  const float* lfbhh=(const float*)d_in[17];

  char* wp = (char*)d_ws;
  auto alloc = [&](size_t bytes)->char*{ char* p = wp; wp += ((bytes+255)/256)*256; return p; };
  float* A     = (float*)alloc((size_t)NN*64*4);   // h0 -> t2
  float* B     = (float*)alloc((size_t)NN*64*4);   // xo
  float* C     = (float*)alloc((size_t)NN*64*4);   // x1
  float* D     = (float*)alloc((size_t)NN*64*4);   // y
  float* Ebuf  = (float*)alloc((size_t)NN*64*4);   // hp -> up-GCN input
  float* Hbuf  = (float*)alloc((size_t)NN*64*4);   // LSTM0 compact output
  float* XW    = (float*)alloc((size_t)NN*256*4);  // gate-x precompute (51.2 MB)
  float* WT0   = (float*)alloc((size_t)256*64*4);
  float* WTf   = (float*)alloc((size_t)256*64*4);
  float* bs0   = (float*)alloc((size_t)256*4);
  float* bsf   = (float*)alloc((size_t)256*4);
  float* score = (float*)alloc((size_t)NN*4);
  float* dinv0 = (float*)alloc((size_t)NN*4);
  float* dinv1 = (float*)alloc((size_t)NN*4);
  unsigned long long* keys = (unsigned long long*)alloc((size_t)NN*8);
  int* degcnt  = (int*)alloc((size_t)NN*4);
  int* diagint = (int*)alloc((size_t)NN*4);
  int* ts      = (int*)alloc((size_t)NN*4);
  int* kp      = (int*)alloc((size_t)NN*4);
  int* mlist   = (int*)alloc((size_t)NN*4);
  int* minv    = (int*)alloc((size_t)NN*4);
  int* indptr  = (int*)alloc((size_t)(NN+1)*4);
  int* part    = (int*)alloc((size_t)NN*4);
  int* fillc   = (int*)alloc((size_t)NN*4);
  int* bsum    = (int*)alloc((size_t)256*4);
  int* boff    = (int*)alloc((size_t)256*4);
  int* csr_r   = (int*)alloc((size_t)EE*4);
  uint2* hash  = (uint2*)alloc((size_t)HASH_SIZE*8);
  unsigned* hist=(unsigned*)alloc((size_t)4*65536*4);
  unsigned* scal=(unsigned*)alloc(256);
  unsigned long long* selp = (unsigned long long*)(scal + 4);

  #define GRID1(n) dim3(((n)+255)/256), dim3(256), 0, stream
  #define GRIDW dim3((NN+3)/4), dim3(256), 0, stream

  // 1. merged init (hash, hist, per-node arrays, scalars, LSTM weight prep)
  k_init<<<GRID1(HASH_SIZE)>>>(hash, hist, degcnt, diagint, fillc, minv,
                               scal, selp, l0wih, l0bih, l0bhh, lfwih, lfbih, lfbhh,
                               WT0, WTf, bs0, bsf);
  // 2. degcnt + hash build + mask-dtype detect
  k_phase2<<<GRID1(EE)>>>(row, col, (const int*)mp, degcnt, hash, scal);
  // 3-5. indptr prefix sum (+dinv0)
  k_psum1<<<dim3(PSB),dim3(256),0,stream>>>(degcnt, part, bsum, dinv0);
  k_psum2<<<dim3(1),dim3(256),0,stream>>>(bsum, boff);
  k_psum3<<<dim3(PSB),dim3(256),0,stream>>>(part, boff, indptr);
  // 6. csr fill + A^2 diag + mask compact
  k_phase4<<<GRID1(EE+NN)>>>(row, col, indptr, fillc, csr_r, hash, diagint, mp, scal, mlist, minv);

  // GCN0 (+ fused TopK score/key + radix round-0 hist)
  k_mm_h0v<<<GRID1(NN*16)>>>(x, W0, A);
  g_gcn0<<<GRIDW>>>(indptr, csr_r, dinv0, A, b0, pw, C, keys, score, hist);

  // TopK radix select (round-0 hist already done)
  k_pick<<<dim3(1),dim3(256),0,stream>>>(hist, selp, scal);
  for (int r2=1;r2<4;r2++){
    k_hist<<<GRID1(NN)>>>(keys, hist + r2*65536, selp, r2);
    k_pick<<<dim3(1),dim3(256),0,stream>>>(hist + r2*65536, selp, scal);
  }
  // pooled degree: two CSR gathers (replaces edge-atomic mid/colsum/dinv1)
  k_tsg<<<GRID1(NN)>>>(indptr, csr_r, keys, selp, kp, ts);
  k_csg<<<GRID1(NN)>>>(indptr, csr_r, ts, diagint, kp, dinv1);

  // pooled GCN: hp then two gather passes
  k_mm64sv<<<GRID1(NN*16)>>>(C, W1, score, kp, Ebuf);
  g_t2<<<GRIDW>>>(indptr, csr_r, dinv1, Ebuf, A);

  // LSTM0 on x1 windows -> Hbuf (compact)
  k_xw<<<dim3(512),dim3(256),0,stream>>>(C, WT0, bs0, XW);
  k_rec<<<dim3(1024),dim3(256),0,stream>>>(XW, l0whh, bs0, mlist, scal, Hbuf, 0);

  // y = res + up (fused: base select + relu(x2))
  g_agg2y<<<GRIDW>>>(indptr, csr_r, A, Ebuf, dinv1, diagint, kp, b1, C, Hbuf, minv, D);

  // up-GCN -> xo (B) and d_out
  k_mm64v<<<GRID1(NN*16)>>>(D, Wu, Ebuf);
  g_up<<<GRIDW>>>(indptr, csr_r, dinv0, Ebuf, bu, B, (float*)d_out);

  // final LSTM on xo windows, scatter into d_out masked rows
  k_xw<<<dim3(512),dim3(256),0,stream>>>(B, WTf, bsf, XW);
  k_rec<<<dim3(1024),dim3(256),0,stream>>>(XW, lfwhh, bsf, mlist, scal, (float*)d_out, 1);
  #undef GRIDW
  #undef GRID1
}

// Round 8
// 702.381 us; speedup vs baseline: 3.7851x; 1.0201x over previous
//
#include <hip/hip_runtime.h>
#include <math.h>

// Problem constants (fixed by reference setup)
#define NN 50000
#define EE 400000
#define CINV 32
#define KKEEP 25000          // ceil(0.5*N)
#define SEQL 5
#define HASH_BITS 20
#define HASH_SIZE (1u<<HASH_BITS)
#define HASH_MASK (HASH_SIZE-1u)
#define HEMPTY 0xFFFFFFFFu
#define PSB 196              // ceil(NN/256)

typedef float vf4 __attribute__((ext_vector_type(4)));

__device__ __forceinline__ float sigm(float x){ return __builtin_amdgcn_rcpf(1.f+__expf(-x)); }
__device__ __forceinline__ float ftanh(float x){ return 1.f - 2.f*__builtin_amdgcn_rcpf(1.f+__expf(2.f*x)); }

// ---------------- merged init (+ LSTM weight prep) ----------------
__global__ void k_init(uint2* __restrict__ hash, unsigned* __restrict__ hist,
                       int* __restrict__ degcnt, int* __restrict__ diagint,
                       int* __restrict__ fillc, int* __restrict__ minv,
                       unsigned* scal, unsigned long long* selp,
                       const float* __restrict__ w0, const float* __restrict__ b0i,
                       const float* __restrict__ b0h, const float* __restrict__ wf,
                       const float* __restrict__ bfi, const float* __restrict__ bfh,
                       float* __restrict__ WT0, float* __restrict__ WTf,
                       float* __restrict__ bs0, float* __restrict__ bsf){
  int i = blockIdx.x*256 + threadIdx.x;
  if (i < (int)HASH_SIZE) hash[i] = make_uint2(HEMPTY, 0u);
  if (i < 4*65536) hist[i] = 0u;
  if (i < NN){ degcnt[i]=0; diagint[i]=0; fillc[i]=0; minv[i]=-1; }
  if (i < 256*64){
    int g = i>>6, k = i&63;
    WT0[k*256+g] = w0[i];
    WTf[k*256+g] = wf[i];
  }
  if (i < 256){ bs0[i]=b0i[i]+b0h[i]; bsf[i]=bfi[i]+bfh[i]; }
  if (i == 0){ scal[0]=0u; scal[1]=0u; scal[3]=KKEEP; selp[0]=0ull; }
}

// ---------------- degcnt + hash build + mask-dtype detect ----------------
__global__ void k_phase2(const int* __restrict__ row, const int* __restrict__ col,
                         const int* __restrict__ mp, int* __restrict__ degcnt,
                         uint2* __restrict__ tab, unsigned* scal){
  int e = blockIdx.x*256 + threadIdx.x;
  if (e < EE){
    int c = col[e];
    atomicAdd(&degcnt[c], 1);
    unsigned key = (unsigned)row[e]*50000u + (unsigned)c;
    unsigned h = (key*2654435761u) >> (32-HASH_BITS);
    for(;;){
      unsigned old = atomicCAS(&tab[h].x, HEMPTY, key);
      if (old==HEMPTY || old==key){ atomicAdd(&tab[h].y, 1u); break; }
      h = (h+1)&HASH_MASK;
    }
  }
  if (e < NN/4){ if ((unsigned)mp[e] > 1u) atomicOr(&scal[1], 1u); }
}

// ---------------- prefix sum (indptr) + dinv0 ----------------
__global__ void k_psum1(const int* __restrict__ deg, int* __restrict__ part,
                        int* __restrict__ bsum, float* __restrict__ dinv){
  __shared__ int sc[256];
  int b = blockIdx.x, t = threadIdx.x, i = b*256+t;
  int v = (i<NN) ? deg[i] : 0;
  if (i < NN) dinv[i] = rsqrtf((float)v + 2.0f);
  sc[t] = v; __syncthreads();
  for (int o=1;o<256;o<<=1){
    int x = (t>=o) ? sc[t-o] : 0;
    __syncthreads();
    sc[t] += x;
    __syncthreads();
  }
  if (i < NN) part[i] = sc[t]-v;
  if (t == 255) bsum[b] = sc[255];
}
__global__ void k_psum2(const int* __restrict__ bsum, int* __restrict__ boff){
  __shared__ int sc[256];
  int t = threadIdx.x;
  int v = (t<PSB) ? bsum[t] : 0;
  sc[t] = v; __syncthreads();
  for (int o=1;o<256;o<<=1){
    int x = (t>=o) ? sc[t-o] : 0;
    __syncthreads();
    sc[t] += x;
    __syncthreads();
  }
  if (t < PSB) boff[t] = sc[t]-v;
}
__global__ void k_psum3(const int* __restrict__ part, const int* __restrict__ boff,
                        int* __restrict__ indptr){
  int i = blockIdx.x*256 + threadIdx.x;
  if (i < NN) indptr[i] = part[i] + boff[blockIdx.x];
  if (i == 0) indptr[NN] = EE;
}

// ---------------- csr fill + A^2 diag + mask compact ----------------
__global__ void k_phase4(const int* __restrict__ row, const int* __restrict__ col,
                         const int* __restrict__ indptr, int* __restrict__ fillc,
                         int* __restrict__ csr_r, const uint2* __restrict__ tab,
                         int* __restrict__ diagint, const void* __restrict__ mp,
                         unsigned* scal, int* __restrict__ mlist, int* __restrict__ minv){
  int idx = blockIdx.x*256 + threadIdx.x;
  if (idx < EE){
    int r = row[idx], c = col[idx];
    int pos = indptr[c] + atomicAdd(&fillc[c], 1);
    csr_r[pos] = r;
    unsigned rkey = (unsigned)c*50000u + (unsigned)r;
    unsigned h = (rkey*2654435761u) >> (32-HASH_BITS);
    for(;;){
      unsigned kk = tab[h].x;
      if (kk==rkey){ atomicAdd(&diagint[r], (int)tab[h].y); break; }
      if (kk==HEMPTY) break;
      h = (h+1)&HASH_MASK;
    }
  } else {
    int i = idx - EE;
    if (i < NN){
      int mv = scal[1] ? (int)((const unsigned char*)mp)[i] : ((const int*)mp)[i];
      if (mv){ int p = (int)atomicAdd(&scal[0], 1u); mlist[p] = i; minv[i] = p; }
    }
  }
}

// ---------------- matmuls (float4 outputs) ----------------
__global__ void k_mm_h0v(const float* __restrict__ X, const float* __restrict__ W, float* __restrict__ Y){
  int idx = blockIdx.x*256 + threadIdx.x;
  if (idx >= NN*16) return;
  int i = idx>>4, fq = idx&15;
  const vf4* X4 = (const vf4*)&X[i*CINV];
  const vf4* W4 = (const vf4*)W;
  vf4 acc = {0.f,0.f,0.f,0.f};
  #pragma unroll
  for (int kq=0;kq<CINV/4;kq++){
    vf4 xv = X4[kq];
    #pragma unroll
    for (int u=0;u<4;u++) acc += xv[u] * W4[(kq*4+u)*16+fq];
  }
  ((vf4*)Y)[i*16+fq] = acc;
}
__global__ void k_mm64v(const float* __restrict__ X, const float* __restrict__ W, float* __restrict__ Y){
  int idx = blockIdx.x*256 + threadIdx.x;
  if (idx >= NN*16) return;
  int i = idx>>4, fq = idx&15;
  const vf4* X4 = (const vf4*)&X[i*64];
  const vf4* W4 = (const vf4*)W;
  vf4 acc = {0.f,0.f,0.f,0.f};
  #pragma unroll
  for (int kq=0;kq<16;kq++){
    vf4 xv = X4[kq];
    #pragma unroll
    for (int u=0;u<4;u++) acc += xv[u] * W4[(kq*4+u)*16+fq];
  }
  ((vf4*)Y)[i*16+fq] = acc;
}
__global__ void k_mm64sv(const float* __restrict__ X, const float* __restrict__ W,
                         const float* __restrict__ sc, const int* __restrict__ kp,
                         float* __restrict__ Y){
  int idx = blockIdx.x*256 + threadIdx.x;
  if (idx >= NN*16) return;
  int i = idx>>4, fq = idx&15;
  if (!kp[i]) return;
  const vf4* X4 = (const vf4*)&X[i*64];
  const vf4* W4 = (const vf4*)W;
  vf4 acc = {0.f,0.f,0.f,0.f};
  #pragma unroll
  for (int kq=0;kq<16;kq++){
    vf4 xv = X4[kq];
    #pragma unroll
    for (int u=0;u<4;u++) acc += xv[u] * W4[(kq*4+u)*16+fq];
  }
  float s = sc[i];
  acc *= s;
  ((vf4*)Y)[i*16+fq] = acc;
}

// ---------------- CSR gather GCN kernels (wave per node) ----------------
// g_gcn0 fused with TopK score/key computation AND radix round-0 histogram.
__global__ void g_gcn0(const int* __restrict__ indptr, const int* __restrict__ csr_r,
                       const float* __restrict__ dinv, const float* __restrict__ H,
                       const float* __restrict__ b, const float* __restrict__ pw,
                       float* __restrict__ out, unsigned long long* __restrict__ keys,
                       float* __restrict__ score, unsigned* __restrict__ hist){
  int node = blockIdx.x*4 + (threadIdx.x>>6), lane = threadIdx.x&63;
  if (node >= NN) return;
  int s = __builtin_amdgcn_readfirstlane(indptr[node]);
  int e = __builtin_amdgcn_readfirstlane(indptr[node+1]);
  float acc = 0.f;
  for (int j=s;j<e;j++){
    int r = __builtin_amdgcn_readfirstlane(csr_r[j]);
    acc += dinv[r]*H[r*64+lane];
  }
  float di = dinv[node];
  float v = di*acc + 2.f*di*di*H[node*64+lane] + b[lane];
  float x1v = fmaxf(v, 0.f);
  out[node*64+lane] = x1v;
  // fused TopK score: s = tanh((x1 . pw)/||pw||)
  float pv = pw[lane];
  float nq = pv*pv;
  float dq = x1v*pv;
  for (int o=32;o;o>>=1){ nq += __shfl_down(nq, o, 64); dq += __shfl_down(dq, o, 64); }
  if (lane==0){
    float sv = tanhf(dq / sqrtf(nq));
    sv = sv + 0.0f;               // canonicalize -0 -> +0
    score[node] = sv;
    unsigned u = __float_as_uint(sv);
    unsigned asc = (u>>31) ? ~u : (u | 0x80000000u);
    unsigned desc = ~asc;
    keys[node] = (((unsigned long long)desc)<<32) | (unsigned)node;
    atomicAdd(&hist[desc>>16], 1u);      // radix round-0 histogram
  }
}
__global__ void g_t2(const int* __restrict__ indptr, const int* __restrict__ csr_r,
                     const float* __restrict__ dinv1, const float* __restrict__ hp,
                     float* __restrict__ t2){
  int node = blockIdx.x*4 + (threadIdx.x>>6), lane = threadIdx.x&63;
  if (node >= NN) return;
  int s = __builtin_amdgcn_readfirstlane(indptr[node]);
  int e = __builtin_amdgcn_readfirstlane(indptr[node+1]);
  float acc = dinv1[node]*hp[node*64+lane];        // self loop
  for (int j=s;j<e;j++){
    int r = __builtin_amdgcn_readfirstlane(csr_r[j]);
    float dr = dinv1[r];
    if (dr != 0.f) acc += dr*hp[r*64+lane];
  }
  t2[node*64+lane] = acc;
}
// D[i] = (masked ? H0[minv[i]] : C[i]) + (kept ? relu(x2_i) : 0)
__global__ void g_agg2y(const int* __restrict__ indptr, const int* __restrict__ csr_r,
                        const float* __restrict__ t2, const float* __restrict__ hp,
                        const float* __restrict__ dinv1, const int* __restrict__ diagint,
                        const int* __restrict__ kp, const float* __restrict__ b1,
                        const float* __restrict__ C, const float* __restrict__ Hbuf,
                        const int* __restrict__ minv, float* __restrict__ D){
  int node = blockIdx.x*4 + (threadIdx.x>>6), lane = threadIdx.x&63;
  if (node >= NN) return;
  int mv = minv[node];
  float base = (mv >= 0) ? Hbuf[(size_t)mv*64+lane] : C[node*64+lane];
  float add = 0.f;
  if (kp[node]){
    int s = __builtin_amdgcn_readfirstlane(indptr[node]);
    int e = __builtin_amdgcn_readfirstlane(indptr[node+1]);
    float acc = t2[node*64+lane];                  // self loop
    for (int j=s;j<e;j++){
      int r = __builtin_amdgcn_readfirstlane(csr_r[j]);
      acc += t2[r*64+lane];
    }
    float di = dinv1[node], hv = hp[node*64+lane];
    float diag = (float)(diagint[node] + 1);
    float v = di*(acc - diag*di*hv) + 2.f*di*di*hv + b1[lane];
    add = fmaxf(v, 0.f);
  }
  D[node*64+lane] = base + add;
}
__global__ void g_up(const int* __restrict__ indptr, const int* __restrict__ csr_r,
                     const float* __restrict__ dinv, const float* __restrict__ H,
                     const float* __restrict__ b, float* __restrict__ xo, float* __restrict__ out){
  int node = blockIdx.x*4 + (threadIdx.x>>6), lane = threadIdx.x&63;
  if (node >= NN) return;
  int s = __builtin_amdgcn_readfirstlane(indptr[node]);
  int e = __builtin_amdgcn_readfirstlane(indptr[node+1]);
  float acc = 0.f;
  for (int j=s;j<e;j++){
    int r = __builtin_amdgcn_readfirstlane(csr_r[j]);
    acc += dinv[r]*H[r*64+lane];
  }
  float di = dinv[node];
  float v = di*acc + 2.f*di*di*H[node*64+lane] + b[lane];
  xo[node*64+lane] = v; out[node*64+lane] = v;
}

// ---------------- TopK radix select (round 0 hist fused into g_gcn0) ----------------
__global__ void k_hist(const unsigned long long* __restrict__ keys, unsigned* __restrict__ hist,
                       const unsigned long long* __restrict__ selp, int round){
  int i = blockIdx.x*256 + threadIdx.x;
  if (i >= NN) return;
  unsigned long long key = keys[i];
  int shift = 48 - 16*round;
  if ((key>>(shift+16)) == selp[0])
    atomicAdd(&hist[(unsigned)((key>>shift)&0xFFFFull)], 1u);
}
__global__ void k_pick(const unsigned* __restrict__ hist, unsigned long long* selp, unsigned* scal){
  __shared__ unsigned csum[256];
  __shared__ unsigned bins[256];
  __shared__ int schunk;
  int t = threadIdx.x;
  const uint4* h4 = (const uint4*)(hist + t*256);
  unsigned s = 0;
  #pragma unroll 8
  for (int j=0;j<64;j++){ uint4 v = h4[j]; s += v.x+v.y+v.z+v.w; }
  csum[t] = s;
  __syncthreads();
  if (t==0){
    unsigned rem = scal[3];
    int chunk = 255;
    for (int c2=0;c2<256;c2++){ unsigned cc=csum[c2]; if (rem>cc) rem-=cc; else { chunk=c2; break; } }
    schunk = chunk; scal[3] = rem;
  }
  __syncthreads();
  bins[t] = hist[schunk*256 + t];
  __syncthreads();
  if (t==0){
    unsigned rem = scal[3];
    int bin = schunk*256 + 255;
    for (int b=0;b<256;b++){ unsigned hv=bins[b]; if (rem>hv) rem-=hv; else { bin = schunk*256 + b; break; } }
    selp[0] = (selp[0]<<16) | (unsigned long long)(unsigned)bin;
    scal[3] = rem;
  }
}
// pooled degree pass 1 (CSR gather): kp[i]; ts[i] = sum_{r->i} kp[r] + kp[i]
__global__ void k_tsg(const int* __restrict__ indptr, const int* __restrict__ csr_r,
                      const unsigned long long* __restrict__ keys,
                      const unsigned long long* __restrict__ selp,
                      int* __restrict__ kp, int* __restrict__ ts){
  int i = blockIdx.x*256 + threadIdx.x;
  if (i >= NN) return;
  unsigned long long sp = selp[0];
  int s = indptr[i], e = indptr[i+1];
  int self = (keys[i] <= sp) ? 1 : 0;
  kp[i] = self;
  int acc = self;
  for (int j=s;j<e;j++) acc += (keys[csr_r[j]] <= sp) ? 1 : 0;
  ts[i] = acc;
}
// pooled degree pass 2 + dinv1: cs[i] = sum_{r->i} ts[r] + ts[i]
__global__ void k_csg(const int* __restrict__ indptr, const int* __restrict__ csr_r,
                      const int* __restrict__ ts, const int* __restrict__ diagint,
                      const int* __restrict__ kp, float* __restrict__ dinv1){
  int i = blockIdx.x*256 + threadIdx.x;
  if (i >= NN) return;
  int s = indptr[i], e = indptr[i+1];
  int acc = ts[i];
  for (int j=s;j<e;j++) acc += ts[csr_r[j]];
  dinv1[i] = kp[i] ? rsqrtf((float)(acc - diagint[i] - 1) + 2.0f) : 0.f;
}

// ---------------- LSTM part 1: XW[n] = src[n] @ W_ih^T + (b_ih+b_hh) ----------------
// Weights staged once per block in 64 KB LDS. Each WAVE processes 4 nodes per
// weight pass: one Wl read feeds 4 accumulators (R7 version was LDS-BW bound
// at 64 KB of per-lane LDS reads per node; this cuts LDS traffic 4x).
__global__ __launch_bounds__(256) void k_xw(const float* __restrict__ src,
        const float* __restrict__ WT, const float* __restrict__ bsum,
        float* __restrict__ XW){
  __shared__ vf4 Wl[4096];              // 64 KB: WT[k][g] as vf4[(k*4+u)*64+fq]
  int t = threadIdx.x;
  const vf4* Wg = (const vf4*)WT;
  for (int u=t; u<4096; u+=256) Wl[u] = Wg[u];
  int fq = t & 63, wv = t >> 6;
  vf4 bias = ((const vf4*)bsum)[fq];
  __syncthreads();
  for (int g = blockIdx.x*4 + wv; g < NN/4; g += gridDim.x*4){
    int n0 = g*4;
    const vf4* X4 = (const vf4*)&src[(size_t)n0*64];   // 4 rows x 16 vf4
    vf4 a0=bias, a1=bias, a2=bias, a3=bias;
    #pragma unroll 4
    for (int kq=0;kq<16;kq++){
      vf4 x0 = X4[kq], x1 = X4[16+kq], x2 = X4[32+kq], x3 = X4[48+kq];
      vf4 w0 = Wl[(kq*4+0)*64+fq];
      vf4 w1 = Wl[(kq*4+1)*64+fq];
      vf4 w2 = Wl[(kq*4+2)*64+fq];
      vf4 w3 = Wl[(kq*4+3)*64+fq];
      a0 += x0.x*w0 + x0.y*w1 + x0.z*w2 + x0.w*w3;
      a1 += x1.x*w0 + x1.y*w1 + x1.z*w2 + x1.w*w3;
      a2 += x2.x*w0 + x2.y*w1 + x2.z*w2 + x2.w*w3;
      a3 += x3.x*w0 + x3.y*w1 + x3.z*w2 + x3.w*w3;
    }
    vf4* Y = (vf4*)XW;
    Y[(size_t)n0*64 + fq]       = a0;
    Y[(size_t)n0*64 + 64 + fq]  = a1;
    Y[(size_t)n0*64 + 128 + fq] = a2;
    Y[(size_t)n0*64 + 192 + fq] = a3;
  }
}

// ---------------- LSTM part 2: recurrence (hh-half only) ----------------
// 4 nodes/block; wave w holds W_hh rows [w*64+lane] (16 vf4) and computes gate
// chunk w for all 4 nodes; prefetches its node's XW row before the FMA loop.
// Grid 2048 (R7's 1024 capped occupancy at 4 waves/SIMD — grid-limited).
__global__ __launch_bounds__(256) void k_rec(const float* __restrict__ XW,
        const float* __restrict__ whh, const float* __restrict__ bsum,
        const int* __restrict__ mlist, const unsigned* __restrict__ scal,
        float* __restrict__ dst, int scatter){
  int M = (int)scal[0];
  if (M < 0 || M > NN) M = 0;          // defensive (rocprof replay poisons scal)
  int w = threadIdx.x>>6, lane = threadIdx.x&63;
  int r = w*64 + lane;
  const vf4* g4 = (const vf4*)&whh[(size_t)r*64];
  vf4 wh[16];
  #pragma unroll
  for (int j=0;j<16;j++) wh[j] = g4[j];
  __shared__ float sh[4][64];
  __shared__ float gates[4][4][64];
  int ntask = (M+3)>>2;
  for (int task = blockIdx.x; task < ntask; task += gridDim.x){
    int m = task*4 + w;
    bool valid = (m < M);
    int node = mlist[valid ? m : (M-1)];
    node = min(max(node, 0), NN-1);    // defensive vs poisoned mlist in replay
    float c, h;
    float x0,x1,x2,x3;
    {   // t = 0: h==0, gates = XW row (bias-only if left-padded)
      int rowi = node - (SEQL-1);
      if (rowi >= 0){
        const float* p = &XW[(size_t)rowi*256];
        x0=p[lane]; x1=p[64+lane]; x2=p[128+lane]; x3=p[192+lane];
      } else {
        x0=bsum[lane]; x1=bsum[64+lane]; x2=bsum[128+lane]; x3=bsum[192+lane];
      }
      c = sigm(x0)*ftanh(x2);
      h = sigm(x3)*ftanh(c);
      sh[w][lane] = h;
    }
    __syncthreads();
    for (int t=1;t<SEQL;t++){
      // prefetch this timestep's gate-x row (wave w -> its own node)
      int rowi = node - (SEQL-1) + t;
      if (rowi >= 0){
        const float* p = &XW[(size_t)rowi*256];
        x0=p[lane]; x1=p[64+lane]; x2=p[128+lane]; x3=p[192+lane];
      } else {
        x0=bsum[lane]; x1=bsum[64+lane]; x2=bsum[128+lane]; x3=bsum[192+lane];
      }
      vf4 a0={0,0,0,0}, a1={0,0,0,0}, a2={0,0,0,0}, a3={0,0,0,0};
      #pragma unroll
      for (int j=0;j<16;j++){
        vf4 wj = wh[j];
        a0 += (*(const vf4*)&sh[0][j*4]) * wj;
        a1 += (*(const vf4*)&sh[1][j*4]) * wj;
        a2 += (*(const vf4*)&sh[2][j*4]) * wj;
        a3 += (*(const vf4*)&sh[3][j*4]) * wj;
      }
      gates[0][w][lane] = a0.x+a0.y+a0.z+a0.w;
      gates[1][w][lane] = a1.x+a1.y+a1.z+a1.w;
      gates[2][w][lane] = a2.x+a2.y+a2.z+a2.w;
      gates[3][w][lane] = a3.x+a3.y+a3.z+a3.w;
      __syncthreads();
      float gi = gates[w][0][lane] + x0;
      float gf = gates[w][1][lane] + x1;
      float gg = gates[w][2][lane] + x2;
      float go = gates[w][3][lane] + x3;
      c = sigm(gf)*c + sigm(gi)*ftanh(gg);
      h = sigm(go)*ftanh(c);
      sh[w][lane] = h;
      __syncthreads();
    }
    if (valid){
      size_t o = scatter ? ((size_t)node*64 + lane) : ((size_t)m*64 + lane);
      dst[o] = h;
    }
  }
}

// ==========================================================================
extern "C" void kernel_launch(void* const* d_in, const int* in_sizes, int n_in,
                              void* d_out, int out_size, void* d_ws, size_t ws_size,
                              hipStream_t stream) {
  const float* x   = (const float*)d_in[0];
  const int*   ei  = (const int*)d_in[1];
  const int*   row = ei;
  const int*   col = ei + EE;
  const void*  mp  = d_in[2];
  const float* W0  = (const float*)d_in[3];
  const float* b0  = (const float*)d_in[4];
  const float* W1  = (const float*)d_in[5];
  const float* b1  = (const float*)d_in[6];
  const float* pw  = (const float*)d_in[7];
  const float* Wu  = (const float*)d_in[8];
  const float* bu  = (const float*)d_in[9];
  const float* l0wih=(const float*)d_in[10];
  const float* l0whh=(const float*)d_in[11];
  const float* l0bih=(const float*)d_in[12];
  const float* l0bhh=(const float*)d_in[13];
  const float* lfwih=(const float*)d_in[14];
  const float* lfwhh=(const float*)d_in[15];
  const float* lfbih=(const float*)d_in[16];
  const float* lfbhh=(const float*)d_in[17];

  char* wp = (char*)d_ws;
  auto alloc = [&](size_t bytes)->char*{ char* p = wp; wp += ((bytes+255)/256)*256; return p; };
  float* A     = (float*)alloc((size_t)NN*64*4);   // h0 -> t2
  float* B     = (float*)alloc((size_t)NN*64*4);   // xo
  float* C     = (float*)alloc((size_t)NN*64*4);   // x1
  float* D     = (float*)alloc((size_t)NN*64*4);   // y
  float* Ebuf  = (float*)alloc((size_t)NN*64*4);   // hp -> up-GCN input
  float* Hbuf  = (float*)alloc((size_t)NN*64*4);   // LSTM0 compact output
  float* XW    = (float*)alloc((size_t)NN*256*4);  // gate-x precompute (51.2 MB)
  float* WT0   = (float*)alloc((size_t)256*64*4);
  float* WTf   = (float*)alloc((size_t)256*64*4);
  float* bs0   = (float*)alloc((size_t)256*4);
  float* bsf   = (float*)alloc((size_t)256*4);
  float* score = (float*)alloc((size_t)NN*4);
  float* dinv0 = (float*)alloc((size_t)NN*4);
  float* dinv1 = (float*)alloc((size_t)NN*4);
  unsigned long long* keys = (unsigned long long*)alloc((size_t)NN*8);
  int* degcnt  = (int*)alloc((size_t)NN*4);
  int* diagint = (int*)alloc((size_t)NN*4);
  int* ts      = (int*)alloc((size_t)NN*4);
  int* kp      = (int*)alloc((size_t)NN*4);
  int* mlist   = (int*)alloc((size_t)NN*4);
  int* minv    = (int*)alloc((size_t)NN*4);
  int* indptr  = (int*)alloc((size_t)(NN+1)*4);
  int* part    = (int*)alloc((size_t)NN*4);
  int* fillc   = (int*)alloc((size_t)NN*4);
  int* bsum    = (int*)alloc((size_t)256*4);
  int* boff    = (int*)alloc((size_t)256*4);
  int* csr_r   = (int*)alloc((size_t)EE*4);
  uint2* hash  = (uint2*)alloc((size_t)HASH_SIZE*8);
  unsigned* hist=(unsigned*)alloc((size_t)4*65536*4);
  unsigned* scal=(unsigned*)alloc(256);
  unsigned long long* selp = (unsigned long long*)(scal + 4);

  #define GRID1(n) dim3(((n)+255)/256), dim3(256), 0, stream
  #define GRIDW dim3((NN+3)/4), dim3(256), 0, stream

  // 1. merged init (hash, hist, per-node arrays, scalars, LSTM weight prep)
  k_init<<<GRID1(HASH_SIZE)>>>(hash, hist, degcnt, diagint, fillc, minv,
                               scal, selp, l0wih, l0bih, l0bhh, lfwih, lfbih, lfbhh,
                               WT0, WTf, bs0, bsf);
  // 2. degcnt + hash build + mask-dtype detect
  k_phase2<<<GRID1(EE)>>>(row, col, (const int*)mp, degcnt, hash, scal);
  // 3-5. indptr prefix sum (+dinv0)
  k_psum1<<<dim3(PSB),dim3(256),0,stream>>>(degcnt, part, bsum, dinv0);
  k_psum2<<<dim3(1),dim3(256),0,stream>>>(bsum, boff);
  k_psum3<<<dim3(PSB),dim3(256),0,stream>>>(part, boff, indptr);
  // 6. csr fill + A^2 diag + mask compact
  k_phase4<<<GRID1(EE+NN)>>>(row, col, indptr, fillc, csr_r, hash, diagint, mp, scal, mlist, minv);

  // GCN0 (+ fused TopK score/key + radix round-0 hist)
  k_mm_h0v<<<GRID1(NN*16)>>>(x, W0, A);
  g_gcn0<<<GRIDW>>>(indptr, csr_r, dinv0, A, b0, pw, C, keys, score, hist);

  // TopK radix select (round-0 hist already done)
  k_pick<<<dim3(1),dim3(256),0,stream>>>(hist, selp, scal);
  for (int r2=1;r2<4;r2++){
    k_hist<<<GRID1(NN)>>>(keys, hist + r2*65536, selp, r2);
    k_pick<<<dim3(1),dim3(256),0,stream>>>(hist + r2*65536, selp, scal);
  }
  // pooled degree: two CSR gathers
  k_tsg<<<GRID1(NN)>>>(indptr, csr_r, keys, selp, kp, ts);
  k_csg<<<GRID1(NN)>>>(indptr, csr_r, ts, diagint, kp, dinv1);

  // pooled GCN: hp then two gather passes
  k_mm64sv<<<GRID1(NN*16)>>>(C, W1, score, kp, Ebuf);
  g_t2<<<GRIDW>>>(indptr, csr_r, dinv1, Ebuf, A);

  // LSTM0 on x1 windows -> Hbuf (compact)
  k_xw<<<dim3(512),dim3(256),0,stream>>>(C, WT0, bs0, XW);
  k_rec<<<dim3(2048),dim3(256),0,stream>>>(XW, l0whh, bs0, mlist, scal, Hbuf, 0);

  // y = res + up (fused: base select + relu(x2))
  g_agg2y<<<GRIDW>>>(indptr, csr_r, A, Ebuf, dinv1, diagint, kp, b1, C, Hbuf, minv, D);

  // up-GCN -> xo (B) and d_out
  k_mm64v<<<GRID1(NN*16)>>>(D, Wu, Ebuf);
  g_up<<<GRIDW>>>(indptr, csr_r, dinv0, Ebuf, bu, B, (float*)d_out);

  // final LSTM on xo windows, scatter into d_out masked rows
  k_xw<<<dim3(512),dim3(256),0,stream>>>(B, WTf, bsf, XW);
  k_rec<<<dim3(2048),dim3(256),0,stream>>>(XW, lfwhh, bsf, mlist, scal, (float*)d_out, 1);
  #undef GRIDW
  #undef GRID1
}

// Round 9
// 688.747 us; speedup vs baseline: 3.8601x; 1.0198x over previous
//
#include <hip/hip_runtime.h>
#include <math.h>

// Problem constants (fixed by reference setup)
#define NN 50000
#define EE 400000
#define CINV 32
#define KKEEP 25000          // ceil(0.5*N)
#define SEQL 5
#define HASH_BITS 20
#define HASH_SIZE (1u<<HASH_BITS)
#define HASH_MASK (HASH_SIZE-1u)
#define HEMPTY 0xFFFFFFFFu
#define PSB 196              // ceil(NN/256)

typedef float vf4 __attribute__((ext_vector_type(4)));

__device__ __forceinline__ float sigm(float x){ return __builtin_amdgcn_rcpf(1.f+__expf(-x)); }
__device__ __forceinline__ float ftanh(float x){ return 1.f - 2.f*__builtin_amdgcn_rcpf(1.f+__expf(2.f*x)); }

// ---------------- merged init (+ LSTM weight prep) ----------------
__global__ void k_init(uint2* __restrict__ hash, unsigned* __restrict__ hist,
                       int* __restrict__ degcnt, int* __restrict__ diagint,
                       int* __restrict__ fillc, int* __restrict__ minv,
                       unsigned* scal, unsigned long long* selp,
                       const float* __restrict__ w0, const float* __restrict__ b0i,
                       const float* __restrict__ b0h, const float* __restrict__ wf,
                       const float* __restrict__ bfi, const float* __restrict__ bfh,
                       float* __restrict__ WT0, float* __restrict__ WTf,
                       float* __restrict__ bs0, float* __restrict__ bsf){
  int i = blockIdx.x*256 + threadIdx.x;
  if (i < (int)HASH_SIZE) hash[i] = make_uint2(HEMPTY, 0u);
  if (i < 4*65536) hist[i] = 0u;
  if (i < NN){ degcnt[i]=0; diagint[i]=0; fillc[i]=0; minv[i]=-1; }
  if (i < 256*64){
    int g = i>>6, k = i&63;
    WT0[k*256+g] = w0[i];
    WTf[k*256+g] = wf[i];
  }
  if (i < 256){ bs0[i]=b0i[i]+b0h[i]; bsf[i]=bfi[i]+bfh[i]; }
  if (i == 0){ scal[0]=0u; scal[1]=0u; scal[3]=KKEEP; selp[0]=0ull; }
}

// ---------------- degcnt + hash build + mask-dtype detect ----------------
__global__ void k_phase2(const int* __restrict__ row, const int* __restrict__ col,
                         const int* __restrict__ mp, int* __restrict__ degcnt,
                         uint2* __restrict__ tab, unsigned* scal){
  int e = blockIdx.x*256 + threadIdx.x;
  if (e < EE){
    int c = col[e];
    atomicAdd(&degcnt[c], 1);
    unsigned key = (unsigned)row[e]*50000u + (unsigned)c;
    unsigned h = (key*2654435761u) >> (32-HASH_BITS);
    for(;;){
      unsigned old = atomicCAS(&tab[h].x, HEMPTY, key);
      if (old==HEMPTY || old==key){ atomicAdd(&tab[h].y, 1u); break; }
      h = (h+1)&HASH_MASK;
    }
  }
  if (e < NN/4){ if ((unsigned)mp[e] > 1u) atomicOr(&scal[1], 1u); }
}

// ---------------- prefix sum (indptr) + dinv0 ----------------
__global__ void k_psum1(const int* __restrict__ deg, int* __restrict__ part,
                        int* __restrict__ bsum, float* __restrict__ dinv){
  __shared__ int sc[256];
  int b = blockIdx.x, t = threadIdx.x, i = b*256+t;
  int v = (i<NN) ? deg[i] : 0;
  if (i < NN) dinv[i] = rsqrtf((float)v + 2.0f);
  sc[t] = v; __syncthreads();
  for (int o=1;o<256;o<<=1){
    int x = (t>=o) ? sc[t-o] : 0;
    __syncthreads();
    sc[t] += x;
    __syncthreads();
  }
  if (i < NN) part[i] = sc[t]-v;
  if (t == 255) bsum[b] = sc[255];
}
__global__ void k_psum2(const int* __restrict__ bsum, int* __restrict__ boff){
  __shared__ int sc[256];
  int t = threadIdx.x;
  int v = (t<PSB) ? bsum[t] : 0;
  sc[t] = v; __syncthreads();
  for (int o=1;o<256;o<<=1){
    int x = (t>=o) ? sc[t-o] : 0;
    __syncthreads();
    sc[t] += x;
    __syncthreads();
  }
  if (t < PSB) boff[t] = sc[t]-v;
}
__global__ void k_psum3(const int* __restrict__ part, const int* __restrict__ boff,
                        int* __restrict__ indptr){
  int i = blockIdx.x*256 + threadIdx.x;
  if (i < NN) indptr[i] = part[i] + boff[blockIdx.x];
  if (i == 0) indptr[NN] = EE;
}

// ---------------- csr fill + A^2 diag + mask compact ----------------
__global__ void k_phase4(const int* __restrict__ row, const int* __restrict__ col,
                         const int* __restrict__ indptr, int* __restrict__ fillc,
                         int* __restrict__ csr_r, const uint2* __restrict__ tab,
                         int* __restrict__ diagint, const void* __restrict__ mp,
                         unsigned* scal, int* __restrict__ mlist, int* __restrict__ minv){
  int idx = blockIdx.x*256 + threadIdx.x;
  if (idx < EE){
    int r = row[idx], c = col[idx];
    int pos = indptr[c] + atomicAdd(&fillc[c], 1);
    csr_r[pos] = r;
    unsigned rkey = (unsigned)c*50000u + (unsigned)r;
    unsigned h = (rkey*2654435761u) >> (32-HASH_BITS);
    for(;;){
      unsigned kk = tab[h].x;
      if (kk==rkey){ atomicAdd(&diagint[r], (int)tab[h].y); break; }
      if (kk==HEMPTY) break;
      h = (h+1)&HASH_MASK;
    }
  } else {
    int i = idx - EE;
    if (i < NN){
      int mv = scal[1] ? (int)((const unsigned char*)mp)[i] : ((const int*)mp)[i];
      if (mv){ int p = (int)atomicAdd(&scal[0], 1u); mlist[p] = i; minv[i] = p; }
    }
  }
}

// ---------------- matmuls (float4 outputs) ----------------
__global__ void k_mm_h0v(const float* __restrict__ X, const float* __restrict__ W, float* __restrict__ Y){
  int idx = blockIdx.x*256 + threadIdx.x;
  if (idx >= NN*16) return;
  int i = idx>>4, fq = idx&15;
  const vf4* X4 = (const vf4*)&X[i*CINV];
  const vf4* W4 = (const vf4*)W;
  vf4 acc = {0.f,0.f,0.f,0.f};
  #pragma unroll
  for (int kq=0;kq<CINV/4;kq++){
    vf4 xv = X4[kq];
    #pragma unroll
    for (int u=0;u<4;u++) acc += xv[u] * W4[(kq*4+u)*16+fq];
  }
  ((vf4*)Y)[i*16+fq] = acc;
}
__global__ void k_mm64v(const float* __restrict__ X, const float* __restrict__ W, float* __restrict__ Y){
  int idx = blockIdx.x*256 + threadIdx.x;
  if (idx >= NN*16) return;
  int i = idx>>4, fq = idx&15;
  const vf4* X4 = (const vf4*)&X[i*64];
  const vf4* W4 = (const vf4*)W;
  vf4 acc = {0.f,0.f,0.f,0.f};
  #pragma unroll
  for (int kq=0;kq<16;kq++){
    vf4 xv = X4[kq];
    #pragma unroll
    for (int u=0;u<4;u++) acc += xv[u] * W4[(kq*4+u)*16+fq];
  }
  ((vf4*)Y)[i*16+fq] = acc;
}
__global__ void k_mm64sv(const float* __restrict__ X, const float* __restrict__ W,
                         const float* __restrict__ sc, const int* __restrict__ kp,
                         float* __restrict__ Y){
  int idx = blockIdx.x*256 + threadIdx.x;
  if (idx >= NN*16) return;
  int i = idx>>4, fq = idx&15;
  if (!kp[i]) return;
  const vf4* X4 = (const vf4*)&X[i*64];
  const vf4* W4 = (const vf4*)W;
  vf4 acc = {0.f,0.f,0.f,0.f};
  #pragma unroll
  for (int kq=0;kq<16;kq++){
    vf4 xv = X4[kq];
    #pragma unroll
    for (int u=0;u<4;u++) acc += xv[u] * W4[(kq*4+u)*16+fq];
  }
  float s = sc[i];
  acc *= s;
  ((vf4*)Y)[i*16+fq] = acc;
}

// ---------------- CSR gather GCN kernels (wave per node) ----------------
// Gather pattern: load up to 64 edge indices with ONE coalesced vector load,
// broadcast via __shfl, unroll x4 with independent accumulators so 4 row
// loads are in flight (replaces R8's serial dependent-load chain).
__global__ void g_gcn0(const int* __restrict__ indptr, const int* __restrict__ csr_r,
                       const float* __restrict__ dinv, const float* __restrict__ H,
                       const float* __restrict__ b, const float* __restrict__ pw,
                       float* __restrict__ out, unsigned long long* __restrict__ keys,
                       float* __restrict__ score, unsigned* __restrict__ hist){
  int node = blockIdx.x*4 + (threadIdx.x>>6), lane = threadIdx.x&63;
  if (node >= NN) return;
  int s = __builtin_amdgcn_readfirstlane(indptr[node]);
  int e = __builtin_amdgcn_readfirstlane(indptr[node+1]);
  int deg = e - s;
  float a0=0.f,a1=0.f,a2=0.f,a3=0.f;
  for (int base=0; base<deg; base+=64){
    int take = min(64, deg-base);
    bool act = lane < take;
    int ii = act ? csr_r[s+base+lane] : 0;
    float dv = act ? dinv[ii] : 0.f;
    int j=0;
    for (; j+4<=take; j+=4){
      int r0=__shfl(ii,j,64), r1=__shfl(ii,j+1,64), r2=__shfl(ii,j+2,64), r3=__shfl(ii,j+3,64);
      float d0=__shfl(dv,j,64), d1=__shfl(dv,j+1,64), d2=__shfl(dv,j+2,64), d3=__shfl(dv,j+3,64);
      a0 += d0*H[(size_t)r0*64+lane];
      a1 += d1*H[(size_t)r1*64+lane];
      a2 += d2*H[(size_t)r2*64+lane];
      a3 += d3*H[(size_t)r3*64+lane];
    }
    for (; j<take; j++){
      int r0=__shfl(ii,j,64); float d0=__shfl(dv,j,64);
      a0 += d0*H[(size_t)r0*64+lane];
    }
  }
  float acc = (a0+a1)+(a2+a3);
  float di = dinv[node];
  float v = di*acc + 2.f*di*di*H[(size_t)node*64+lane] + b[lane];
  float x1v = fmaxf(v, 0.f);
  out[(size_t)node*64+lane] = x1v;
  // fused TopK score: s = tanh((x1 . pw)/||pw||)
  float pv = pw[lane];
  float nq = pv*pv;
  float dq = x1v*pv;
  for (int o=32;o;o>>=1){ nq += __shfl_down(nq, o, 64); dq += __shfl_down(dq, o, 64); }
  if (lane==0){
    float sv = tanhf(dq / sqrtf(nq));
    sv = sv + 0.0f;               // canonicalize -0 -> +0
    score[node] = sv;
    unsigned u = __float_as_uint(sv);
    unsigned asc = (u>>31) ? ~u : (u | 0x80000000u);
    unsigned desc = ~asc;
    keys[node] = (((unsigned long long)desc)<<32) | (unsigned)node;
    atomicAdd(&hist[desc>>16], 1u);      // radix round-0 histogram
  }
}
__global__ void g_t2(const int* __restrict__ indptr, const int* __restrict__ csr_r,
                     const float* __restrict__ dinv1, const float* __restrict__ hp,
                     float* __restrict__ t2){
  int node = blockIdx.x*4 + (threadIdx.x>>6), lane = threadIdx.x&63;
  if (node >= NN) return;
  int s = __builtin_amdgcn_readfirstlane(indptr[node]);
  int e = __builtin_amdgcn_readfirstlane(indptr[node+1]);
  int deg = e - s;
  float a0 = dinv1[node]*hp[(size_t)node*64+lane];   // self loop
  float a1 = 0.f;
  for (int base=0; base<deg; base+=64){
    int take = min(64, deg-base);
    bool act = lane < take;
    int ii = act ? csr_r[s+base+lane] : 0;
    float dv = act ? dinv1[ii] : 0.f;
    int j=0;
    for (; j+2<=take; j+=2){
      float d0=__shfl(dv,j,64), d1=__shfl(dv,j+1,64);
      int r0=__shfl(ii,j,64), r1=__shfl(ii,j+1,64);
      if (d0!=0.f) a0 += d0*hp[(size_t)r0*64+lane];
      if (d1!=0.f) a1 += d1*hp[(size_t)r1*64+lane];
    }
    for (; j<take; j++){
      float d0=__shfl(dv,j,64); int r0=__shfl(ii,j,64);
      if (d0!=0.f) a0 += d0*hp[(size_t)r0*64+lane];
    }
  }
  t2[(size_t)node*64+lane] = a0+a1;
}
// D[i] = (masked ? H0[minv[i]] : C[i]) + (kept ? relu(x2_i) : 0)
__global__ void g_agg2y(const int* __restrict__ indptr, const int* __restrict__ csr_r,
                        const float* __restrict__ t2, const float* __restrict__ hp,
                        const float* __restrict__ dinv1, const int* __restrict__ diagint,
                        const int* __restrict__ kp, const float* __restrict__ b1,
                        const float* __restrict__ C, const float* __restrict__ Hbuf,
                        const int* __restrict__ minv, float* __restrict__ D){
  int node = blockIdx.x*4 + (threadIdx.x>>6), lane = threadIdx.x&63;
  if (node >= NN) return;
  int mv = minv[node];
  float base = (mv >= 0) ? Hbuf[(size_t)mv*64+lane] : C[(size_t)node*64+lane];
  float add = 0.f;
  if (kp[node]){
    int s = __builtin_amdgcn_readfirstlane(indptr[node]);
    int e = __builtin_amdgcn_readfirstlane(indptr[node+1]);
    int deg = e - s;
    float a0 = t2[(size_t)node*64+lane];             // self loop
    float a1=0.f,a2=0.f,a3=0.f;
    for (int bs2=0; bs2<deg; bs2+=64){
      int take = min(64, deg-bs2);
      bool act = lane < take;
      int ii = act ? csr_r[s+bs2+lane] : 0;
      int j=0;
      for (; j+4<=take; j+=4){
        int r0=__shfl(ii,j,64), r1=__shfl(ii,j+1,64), r2=__shfl(ii,j+2,64), r3=__shfl(ii,j+3,64);
        a0 += t2[(size_t)r0*64+lane];
        a1 += t2[(size_t)r1*64+lane];
        a2 += t2[(size_t)r2*64+lane];
        a3 += t2[(size_t)r3*64+lane];
      }
      for (; j<take; j++){
        int r0=__shfl(ii,j,64);
        a0 += t2[(size_t)r0*64+lane];
      }
    }
    float acc = (a0+a1)+(a2+a3);
    float di = dinv1[node], hv = hp[(size_t)node*64+lane];
    float diag = (float)(diagint[node] + 1);
    float v = di*(acc - diag*di*hv) + 2.f*di*di*hv + b1[lane];
    add = fmaxf(v, 0.f);
  }
  D[(size_t)node*64+lane] = base + add;
}
__global__ void g_up(const int* __restrict__ indptr, const int* __restrict__ csr_r,
                     const float* __restrict__ dinv, const float* __restrict__ H,
                     const float* __restrict__ b, float* __restrict__ xo, float* __restrict__ out){
  int node = blockIdx.x*4 + (threadIdx.x>>6), lane = threadIdx.x&63;
  if (node >= NN) return;
  int s = __builtin_amdgcn_readfirstlane(indptr[node]);
  int e = __builtin_amdgcn_readfirstlane(indptr[node+1]);
  int deg = e - s;
  float a0=0.f,a1=0.f,a2=0.f,a3=0.f;
  for (int base=0; base<deg; base+=64){
    int take = min(64, deg-base);
    bool act = lane < take;
    int ii = act ? csr_r[s+base+lane] : 0;
    float dv = act ? dinv[ii] : 0.f;
    int j=0;
    for (; j+4<=take; j+=4){
      int r0=__shfl(ii,j,64), r1=__shfl(ii,j+1,64), r2=__shfl(ii,j+2,64), r3=__shfl(ii,j+3,64);
      float d0=__shfl(dv,j,64), d1=__shfl(dv,j+1,64), d2=__shfl(dv,j+2,64), d3=__shfl(dv,j+3,64);
      a0 += d0*H[(size_t)r0*64+lane];
      a1 += d1*H[(size_t)r1*64+lane];
      a2 += d2*H[(size_t)r2*64+lane];
      a3 += d3*H[(size_t)r3*64+lane];
    }
    for (; j<take; j++){
      int r0=__shfl(ii,j,64); float d0=__shfl(dv,j,64);
      a0 += d0*H[(size_t)r0*64+lane];
    }
  }
  float acc = (a0+a1)+(a2+a3);
  float di = dinv[node];
  float v = di*acc + 2.f*di*di*H[(size_t)node*64+lane] + b[lane];
  xo[(size_t)node*64+lane] = v; out[(size_t)node*64+lane] = v;
}

// ---------------- TopK radix select (round 0 hist fused into g_gcn0) ----------------
__global__ void k_hist(const unsigned long long* __restrict__ keys, unsigned* __restrict__ hist,
                       const unsigned long long* __restrict__ selp, int round){
  int i = blockIdx.x*256 + threadIdx.x;
  if (i >= NN) return;
  unsigned long long key = keys[i];
  int shift = 48 - 16*round;
  if ((key>>(shift+16)) == selp[0])
    atomicAdd(&hist[(unsigned)((key>>shift)&0xFFFFull)], 1u);
}
__global__ void k_pick(const unsigned* __restrict__ hist, unsigned long long* selp, unsigned* scal){
  __shared__ unsigned csum[256];
  __shared__ unsigned bins[256];
  __shared__ int schunk;
  int t = threadIdx.x;
  const uint4* h4 = (const uint4*)(hist + t*256);
  unsigned s = 0;
  #pragma unroll 8
  for (int j=0;j<64;j++){ uint4 v = h4[j]; s += v.x+v.y+v.z+v.w; }
  csum[t] = s;
  __syncthreads();
  if (t==0){
    unsigned rem = scal[3];
    int chunk = 255;
    for (int c2=0;c2<256;c2++){ unsigned cc=csum[c2]; if (rem>cc) rem-=cc; else { chunk=c2; break; } }
    schunk = chunk; scal[3] = rem;
  }
  __syncthreads();
  bins[t] = hist[schunk*256 + t];
  __syncthreads();
  if (t==0){
    unsigned rem = scal[3];
    int bin = schunk*256 + 255;
    for (int b=0;b<256;b++){ unsigned hv=bins[b]; if (rem>hv) rem-=hv; else { bin = schunk*256 + b; break; } }
    selp[0] = (selp[0]<<16) | (unsigned long long)(unsigned)bin;
    scal[3] = rem;
  }
}
// pooled degree pass 1 (CSR gather): kp[i]; ts[i] = sum_{r->i} kp[r] + kp[i]
__global__ void k_tsg(const int* __restrict__ indptr, const int* __restrict__ csr_r,
                      const unsigned long long* __restrict__ keys,
                      const unsigned long long* __restrict__ selp,
                      int* __restrict__ kp, int* __restrict__ ts){
  int i = blockIdx.x*256 + threadIdx.x;
  if (i >= NN) return;
  unsigned long long sp = selp[0];
  int s = indptr[i], e = indptr[i+1];
  int self = (keys[i] <= sp) ? 1 : 0;
  kp[i] = self;
  int acc = self;
  for (int j=s;j<e;j++) acc += (keys[csr_r[j]] <= sp) ? 1 : 0;
  ts[i] = acc;
}
// pooled degree pass 2 + dinv1: cs[i] = sum_{r->i} ts[r] + ts[i]
__global__ void k_csg(const int* __restrict__ indptr, const int* __restrict__ csr_r,
                      const int* __restrict__ ts, const int* __restrict__ diagint,
                      const int* __restrict__ kp, float* __restrict__ dinv1){
  int i = blockIdx.x*256 + threadIdx.x;
  if (i >= NN) return;
  int s = indptr[i], e = indptr[i+1];
  int acc = ts[i];
  for (int j=s;j<e;j++) acc += ts[csr_r[j]];
  dinv1[i] = kp[i] ? rsqrtf((float)(acc - diagint[i] - 1) + 2.0f) : 0.f;
}

// ---------------- LSTM part 1: XW[n] = src[n] @ W_ih^T + (b_ih+b_hh) ----------------
__global__ __launch_bounds__(256) void k_xw(const float* __restrict__ src,
        const float* __restrict__ WT, const float* __restrict__ bsum,
        float* __restrict__ XW){
  __shared__ vf4 Wl[4096];              // 64 KB: WT[k][g] as vf4[(k*4+u)*64+fq]
  int t = threadIdx.x;
  const vf4* Wg = (const vf4*)WT;
  for (int u=t; u<4096; u+=256) Wl[u] = Wg[u];
  int fq = t & 63, wv = t >> 6;
  vf4 bias = ((const vf4*)bsum)[fq];
  __syncthreads();
  for (int g = blockIdx.x*4 + wv; g < NN/4; g += gridDim.x*4){
    int n0 = g*4;
    const vf4* X4 = (const vf4*)&src[(size_t)n0*64];   // 4 rows x 16 vf4
    vf4 a0=bias, a1=bias, a2=bias, a3=bias;
    #pragma unroll 4
    for (int kq=0;kq<16;kq++){
      vf4 x0 = X4[kq], x1 = X4[16+kq], x2 = X4[32+kq], x3 = X4[48+kq];
      vf4 w0 = Wl[(kq*4+0)*64+fq];
      vf4 w1 = Wl[(kq*4+1)*64+fq];
      vf4 w2 = Wl[(kq*4+2)*64+fq];
      vf4 w3 = Wl[(kq*4+3)*64+fq];
      a0 += x0.x*w0 + x0.y*w1 + x0.z*w2 + x0.w*w3;
      a1 += x1.x*w0 + x1.y*w1 + x1.z*w2 + x1.w*w3;
      a2 += x2.x*w0 + x2.y*w1 + x2.z*w2 + x2.w*w3;
      a3 += x3.x*w0 + x3.y*w1 + x3.z*w2 + x3.w*w3;
    }
    vf4* Y = (vf4*)XW;
    Y[(size_t)n0*64 + fq]       = a0;
    Y[(size_t)n0*64 + 64 + fq]  = a1;
    Y[(size_t)n0*64 + 128 + fq] = a2;
    Y[(size_t)n0*64 + 192 + fq] = a3;
  }
}

// ---------------- LSTM part 2: recurrence (hh-half only) ----------------
// 8 nodes/block (R8 was 4): wave w computes gate chunk w for all 8 nodes —
// 512 FMA-inst between barriers instead of 256, halving barrier/exchange
// overhead per node. Wave w owns epilogue for nodes 2w, 2w+1 and prefetches
// their XW rows before the FMA loop. Occupancy is register-limited at
// ~3 waves/SIMD (weights AGPR-demoted); barrier amortization is the lever.
__global__ __launch_bounds__(256) void k_rec(const float* __restrict__ XW,
        const float* __restrict__ whh, const float* __restrict__ bsum,
        const int* __restrict__ mlist, const unsigned* __restrict__ scal,
        float* __restrict__ dst, int scatter){
  int M = (int)scal[0];
  if (M < 0 || M > NN) M = 0;          // defensive (rocprof replay poisons scal)
  int w = threadIdx.x>>6, lane = threadIdx.x&63;
  int r = w*64 + lane;
  const vf4* g4 = (const vf4*)&whh[(size_t)r*64];
  vf4 wh[16];
  #pragma unroll
  for (int j=0;j<16;j++) wh[j] = g4[j];
  __shared__ float sh[8][64];
  __shared__ float gates[8][4][64];
  int ntask = (M+7)>>3;
  for (int task = blockIdx.x; task < ntask; task += gridDim.x){
    int m0 = task*8 + 2*w, m1 = m0+1;
    bool v0 = (m0 < M), v1 = (m1 < M);
    int n0 = mlist[v0 ? m0 : (M-1)];
    int n1 = mlist[v1 ? m1 : (M-1)];
    n0 = min(max(n0, 0), NN-1);        // defensive vs poisoned mlist in replay
    n1 = min(max(n1, 0), NN-1);
    float c0, h0, c1, h1;
    float x0,x1,x2,x3, y0,y1,y2,y3;
    {   // t = 0: h==0, gates = XW row (bias-only if left-padded)
      int ra = n0 - (SEQL-1), rb = n1 - (SEQL-1);
      if (ra >= 0){
        const float* p = &XW[(size_t)ra*256];
        x0=p[lane]; x1=p[64+lane]; x2=p[128+lane]; x3=p[192+lane];
      } else { x0=bsum[lane]; x1=bsum[64+lane]; x2=bsum[128+lane]; x3=bsum[192+lane]; }
      if (rb >= 0){
        const float* p = &XW[(size_t)rb*256];
        y0=p[lane]; y1=p[64+lane]; y2=p[128+lane]; y3=p[192+lane];
      } else { y0=bsum[lane]; y1=bsum[64+lane]; y2=bsum[128+lane]; y3=bsum[192+lane]; }
      c0 = sigm(x0)*ftanh(x2); h0 = sigm(x3)*ftanh(c0);
      c1 = sigm(y0)*ftanh(y2); h1 = sigm(y3)*ftanh(c1);
      sh[2*w][lane] = h0;
      sh[2*w+1][lane] = h1;
    }
    __syncthreads();
    for (int t=1;t<SEQL;t++){
      // prefetch this timestep's gate-x rows for this wave's two nodes
      int ra = n0 - (SEQL-1) + t, rb = n1 - (SEQL-1) + t;
      if (ra >= 0){
        const float* p = &XW[(size_t)ra*256];
        x0=p[lane]; x1=p[64+lane]; x2=p[128+lane]; x3=p[192+lane];
      } else { x0=bsum[lane]; x1=bsum[64+lane]; x2=bsum[128+lane]; x3=bsum[192+lane]; }
      if (rb >= 0){
        const float* p = &XW[(size_t)rb*256];
        y0=p[lane]; y1=p[64+lane]; y2=p[128+lane]; y3=p[192+lane];
      } else { y0=bsum[lane]; y1=bsum[64+lane]; y2=bsum[128+lane]; y3=bsum[192+lane]; }
      vf4 a0={0,0,0,0},a1={0,0,0,0},a2={0,0,0,0},a3={0,0,0,0};
      vf4 a4={0,0,0,0},a5={0,0,0,0},a6={0,0,0,0},a7={0,0,0,0};
      #pragma unroll
      for (int j=0;j<16;j++){
        vf4 wj = wh[j];
        a0 += (*(const vf4*)&sh[0][j*4]) * wj;
        a1 += (*(const vf4*)&sh[1][j*4]) * wj;
        a2 += (*(const vf4*)&sh[2][j*4]) * wj;
        a3 += (*(const vf4*)&sh[3][j*4]) * wj;
        a4 += (*(const vf4*)&sh[4][j*4]) * wj;
        a5 += (*(const vf4*)&sh[5][j*4]) * wj;
        a6 += (*(const vf4*)&sh[6][j*4]) * wj;
        a7 += (*(const vf4*)&sh[7][j*4]) * wj;
      }
      gates[0][w][lane] = a0.x+a0.y+a0.z+a0.w;
      gates[1][w][lane] = a1.x+a1.y+a1.z+a1.w;
      gates[2][w][lane] = a2.x+a2.y+a2.z+a2.w;
      gates[3][w][lane] = a3.x+a3.y+a3.z+a3.w;
      gates[4][w][lane] = a4.x+a4.y+a4.z+a4.w;
      gates[5][w][lane] = a5.x+a5.y+a5.z+a5.w;
      gates[6][w][lane] = a6.x+a6.y+a6.z+a6.w;
      gates[7][w][lane] = a7.x+a7.y+a7.z+a7.w;
      __syncthreads();
      int p0 = 2*w, p1 = 2*w+1;
      float gi = gates[p0][0][lane] + x0;
      float gf = gates[p0][1][lane] + x1;
      float gg = gates[p0][2][lane] + x2;
      float go = gates[p0][3][lane] + x3;
      c0 = sigm(gf)*c0 + sigm(gi)*ftanh(gg);
      h0 = sigm(go)*ftanh(c0);
      sh[p0][lane] = h0;
      gi = gates[p1][0][lane] + y0;
      gf = gates[p1][1][lane] + y1;
      gg = gates[p1][2][lane] + y2;
      go = gates[p1][3][lane] + y3;
      c1 = sigm(gf)*c1 + sigm(gi)*ftanh(gg);
      h1 = sigm(go)*ftanh(c1);
      sh[p1][lane] = h1;
      __syncthreads();
    }
    if (v0){
      size_t o = scatter ? ((size_t)n0*64 + lane) : ((size_t)m0*64 + lane);
      dst[o] = h0;
    }
    if (v1){
      size_t o = scatter ? ((size_t)n1*64 + lane) : ((size_t)m1*64 + lane);
      dst[o] = h1;
    }
  }
}

// ==========================================================================
extern "C" void kernel_launch(void* const* d_in, const int* in_sizes, int n_in,
                              void* d_out, int out_size, void* d_ws, size_t ws_size,
                              hipStream_t stream) {
  const float* x   = (const float*)d_in[0];
  const int*   ei  = (const int*)d_in[1];
  const int*   row = ei;
  const int*   col = ei + EE;
  const void*  mp  = d_in[2];
  const float* W0  = (const float*)d_in[3];
  const float* b0  = (const float*)d_in[4];
  const float* W1  = (const float*)d_in[5];
  const float* b1  = (const float*)d_in[6];
  const float* pw  = (const float*)d_in[7];
  const float* Wu  = (const float*)d_in[8];
  const float* bu  = (const float*)d_in[9];
  const float* l0wih=(const float*)d_in[10];
  const float* l0whh=(const float*)d_in[11];
  const float* l0bih=(const float*)d_in[12];
  const float* l0bhh=(const float*)d_in[13];
  const float* lfwih=(const float*)d_in[14];
  const float* lfwhh=(const float*)d_in[15];
  const float* lfbih=(const float*)d_in[16];
  const float* lfbhh=(const float*)d_in[17];

  char* wp = (char*)d_ws;
  auto alloc = [&](size_t bytes)->char*{ char* p = wp; wp += ((bytes+255)/256)*256; return p; };
  float* A     = (float*)alloc((size_t)NN*64*4);   // h0 -> t2
  float* B     = (float*)alloc((size_t)NN*64*4);   // xo
  float* C     = (float*)alloc((size_t)NN*64*4);   // x1
  float* D     = (float*)alloc((size_t)NN*64*4);   // y
  float* Ebuf  = (float*)alloc((size_t)NN*64*4);   // hp -> up-GCN input
  float* Hbuf  = (float*)alloc((size_t)NN*64*4);   // LSTM0 compact output
  float* XW    = (float*)alloc((size_t)NN*256*4);  // gate-x precompute (51.2 MB)
  float* WT0   = (float*)alloc((size_t)256*64*4);
  float* WTf   = (float*)alloc((size_t)256*64*4);
  float* bs0   = (float*)alloc((size_t)256*4);
  float* bsf   = (float*)alloc((size_t)256*4);
  float* score = (float*)alloc((size_t)NN*4);
  float* dinv0 = (float*)alloc((size_t)NN*4);
  float* dinv1 = (float*)alloc((size_t)NN*4);
  unsigned long long* keys = (unsigned long long*)alloc((size_t)NN*8);
  int* degcnt  = (int*)alloc((size_t)NN*4);
  int* diagint = (int*)alloc((size_t)NN*4);
  int* ts      = (int*)alloc((size_t)NN*4);
  int* kp      = (int*)alloc((size_t)NN*4);
  int* mlist   = (int*)alloc((size_t)NN*4);
  int* minv    = (int*)alloc((size_t)NN*4);
  int* indptr  = (int*)alloc((size_t)(NN+1)*4);
  int* part    = (int*)alloc((size_t)NN*4);
  int* fillc   = (int*)alloc((size_t)NN*4);
  int* bsum    = (int*)alloc((size_t)256*4);
  int* boff    = (int*)alloc((size_t)256*4);
  int* csr_r   = (int*)alloc((size_t)EE*4);
  uint2* hash  = (uint2*)alloc((size_t)HASH_SIZE*8);
  unsigned* hist=(unsigned*)alloc((size_t)4*65536*4);
  unsigned* scal=(unsigned*)alloc(256);
  unsigned long long* selp = (unsigned long long*)(scal + 4);

  #define GRID1(n) dim3(((n)+255)/256), dim3(256), 0, stream
  #define GRIDW dim3((NN+3)/4), dim3(256), 0, stream

  // 1. merged init (hash, hist, per-node arrays, scalars, LSTM weight prep)
  k_init<<<GRID1(HASH_SIZE)>>>(hash, hist, degcnt, diagint, fillc, minv,
                               scal, selp, l0wih, l0bih, l0bhh, lfwih, lfbih, lfbhh,
                               WT0, WTf, bs0, bsf);
  // 2. degcnt + hash build + mask-dtype detect
  k_phase2<<<GRID1(EE)>>>(row, col, (const int*)mp, degcnt, hash, scal);
  // 3-5. indptr prefix sum (+dinv0)
  k_psum1<<<dim3(PSB),dim3(256),0,stream>>>(degcnt, part, bsum, dinv0);
  k_psum2<<<dim3(1),dim3(256),0,stream>>>(bsum, boff);
  k_psum3<<<dim3(PSB),dim3(256),0,stream>>>(part, boff, indptr);
  // 6. csr fill + A^2 diag + mask compact
  k_phase4<<<GRID1(EE+NN)>>>(row, col, indptr, fillc, csr_r, hash, diagint, mp, scal, mlist, minv);

  // GCN0 (+ fused TopK score/key + radix round-0 hist)
  k_mm_h0v<<<GRID1(NN*16)>>>(x, W0, A);
  g_gcn0<<<GRIDW>>>(indptr, csr_r, dinv0, A, b0, pw, C, keys, score, hist);

  // TopK radix select (round-0 hist already done)
  k_pick<<<dim3(1),dim3(256),0,stream>>>(hist, selp, scal);
  for (int r2=1;r2<4;r2++){
    k_hist<<<GRID1(NN)>>>(keys, hist + r2*65536, selp, r2);
    k_pick<<<dim3(1),dim3(256),0,stream>>>(hist + r2*65536, selp, scal);
  }
  // pooled degree: two CSR gathers
  k_tsg<<<GRID1(NN)>>>(indptr, csr_r, keys, selp, kp, ts);
  k_csg<<<GRID1(NN)>>>(indptr, csr_r, ts, diagint, kp, dinv1);

  // pooled GCN: hp then two gather passes
  k_mm64sv<<<GRID1(NN*16)>>>(C, W1, score, kp, Ebuf);
  g_t2<<<GRIDW>>>(indptr, csr_r, dinv1, Ebuf, A);

  // LSTM0 on x1 windows -> Hbuf (compact)
  k_xw<<<dim3(512),dim3(256),0,stream>>>(C, WT0, bs0, XW);
  k_rec<<<dim3(2048),dim3(256),0,stream>>>(XW, l0whh, bs0, mlist, scal, Hbuf, 0);

  // y = res + up (fused: base select + relu(x2))
  g_agg2y<<<GRIDW>>>(indptr, csr_r, A, Ebuf, dinv1, diagint, kp, b1, C, Hbuf, minv, D);

  // up-GCN -> xo (B) and d_out
  k_mm64v<<<GRID1(NN*16)>>>(D, Wu, Ebuf);
  g_up<<<GRIDW>>>(indptr, csr_r, dinv0, Ebuf, bu, B, (float*)d_out);

  // final LSTM on xo windows, scatter into d_out masked rows
  k_xw<<<dim3(512),dim3(256),0,stream>>>(B, WTf, bsf, XW);
  k_rec<<<dim3(2048),dim3(256),0,stream>>>(XW, lfwhh, bsf, mlist, scal, (float*)d_out, 1);
  #undef GRIDW
  #undef GRID1
}

// Round 10
// 661.006 us; speedup vs baseline: 4.0221x; 1.0420x over previous
//
#include <hip/hip_runtime.h>
#include <math.h>

// Problem constants (fixed by reference setup)
#define NN 50000
#define EE 400000
#define CINV 32
#define KKEEP 25000          // ceil(0.5*N)
#define SEQL 5
#define HASH_BITS 20
#define HASH_SIZE (1u<<HASH_BITS)
#define HASH_MASK (HASH_SIZE-1u)
#define HEMPTY 0xFFFFFFFFu
#define PSB 196              // ceil(NN/256)

typedef float vf4 __attribute__((ext_vector_type(4)));

__device__ __forceinline__ float sigm(float x){ return __builtin_amdgcn_rcpf(1.f+__expf(-x)); }
__device__ __forceinline__ float ftanh(float x){ return 1.f - 2.f*__builtin_amdgcn_rcpf(1.f+__expf(2.f*x)); }

// ---------------- merged init (+ LSTM weight prep) ----------------
__global__ void k_init(uint2* __restrict__ hash, unsigned* __restrict__ hist,
                       int* __restrict__ degcnt, int* __restrict__ diagint,
                       int* __restrict__ fillc, int* __restrict__ minv,
                       unsigned* scal, unsigned long long* selp,
                       const float* __restrict__ w0, const float* __restrict__ b0i,
                       const float* __restrict__ b0h, const float* __restrict__ wf,
                       const float* __restrict__ bfi, const float* __restrict__ bfh,
                       float* __restrict__ WT0, float* __restrict__ WTf,
                       float* __restrict__ bs0, float* __restrict__ bsf){
  int i = blockIdx.x*256 + threadIdx.x;
  if (i < (int)HASH_SIZE) hash[i] = make_uint2(HEMPTY, 0u);
  if (i < 4*65536) hist[i] = 0u;
  if (i < NN){ degcnt[i]=0; diagint[i]=0; fillc[i]=0; minv[i]=-1; }
  if (i < 256*64){
    int g = i>>6, k = i&63;
    WT0[k*256+g] = w0[i];
    WTf[k*256+g] = wf[i];
  }
  if (i < 256){ bs0[i]=b0i[i]+b0h[i]; bsf[i]=bfi[i]+bfh[i]; }
  if (i == 0){ scal[0]=0u; scal[1]=0u; scal[3]=KKEEP; selp[0]=0ull; }
}

// ---------------- phase2: degcnt + hash build + mask detect + GCN0 matmul ----------------
// (edge work and the independent x@W0 matmul merged into one launch)
__global__ void k_phase2(const int* __restrict__ row, const int* __restrict__ col,
                         const int* __restrict__ mp, int* __restrict__ degcnt,
                         uint2* __restrict__ tab, unsigned* scal,
                         const float* __restrict__ X, const float* __restrict__ W,
                         float* __restrict__ Y){
  int idx = blockIdx.x*256 + threadIdx.x;
  if (idx < EE){
    int c = col[idx];
    atomicAdd(&degcnt[c], 1);
    unsigned key = (unsigned)row[idx]*50000u + (unsigned)c;
    unsigned h = (key*2654435761u) >> (32-HASH_BITS);
    for(;;){
      unsigned old = atomicCAS(&tab[h].x, HEMPTY, key);
      if (old==HEMPTY || old==key){ atomicAdd(&tab[h].y, 1u); break; }
      h = (h+1)&HASH_MASK;
    }
  }
  if (idx < NN/4){ if ((unsigned)mp[idx] > 1u) atomicOr(&scal[1], 1u); }
  if (idx < NN*16){
    int i = idx>>4, fq = idx&15;
    const vf4* X4 = (const vf4*)&X[i*CINV];
    const vf4* W4 = (const vf4*)W;
    vf4 acc = {0.f,0.f,0.f,0.f};
    #pragma unroll
    for (int kq=0;kq<CINV/4;kq++){
      vf4 xv = X4[kq];
      #pragma unroll
      for (int u=0;u<4;u++) acc += xv[u] * W4[(kq*4+u)*16+fq];
    }
    ((vf4*)Y)[i*16+fq] = acc;
  }
}

// ---------------- prefix sum (indptr) + dinv0 ----------------
__global__ void k_psum1(const int* __restrict__ deg, int* __restrict__ part,
                        int* __restrict__ bsum, float* __restrict__ dinv){
  __shared__ int sc[256];
  int b = blockIdx.x, t = threadIdx.x, i = b*256+t;
  int v = (i<NN) ? deg[i] : 0;
  if (i < NN) dinv[i] = rsqrtf((float)v + 2.0f);
  sc[t] = v; __syncthreads();
  for (int o=1;o<256;o<<=1){
    int x = (t>=o) ? sc[t-o] : 0;
    __syncthreads();
    sc[t] += x;
    __syncthreads();
  }
  if (i < NN) part[i] = sc[t]-v;
  if (t == 255) bsum[b] = sc[255];
}
// psum3 with per-block redundant scan of bsum (kills the separate psum2 launch)
__global__ void k_psum3(const int* __restrict__ part, const int* __restrict__ bsum,
                        int* __restrict__ indptr){
  __shared__ int sc[256];
  int t = threadIdx.x;
  int v = (t<PSB) ? bsum[t] : 0;
  sc[t] = v; __syncthreads();
  for (int o=1;o<256;o<<=1){
    int x = (t>=o) ? sc[t-o] : 0;
    __syncthreads();
    sc[t] += x;
    __syncthreads();
  }
  int bb = blockIdx.x;
  int ex = sc[bb] - ((bb<PSB) ? bsum[bb] : 0);   // exclusive prefix for this block
  int i = bb*256 + t;
  if (i < NN) indptr[i] = part[i] + ex;
  if (i == 0) indptr[NN] = EE;
}

// ---------------- csr fill + A^2 diag + mask compact ----------------
__global__ void k_phase4(const int* __restrict__ row, const int* __restrict__ col,
                         const int* __restrict__ indptr, int* __restrict__ fillc,
                         int* __restrict__ csr_r, const uint2* __restrict__ tab,
                         int* __restrict__ diagint, const void* __restrict__ mp,
                         unsigned* scal, int* __restrict__ mlist, int* __restrict__ minv){
  int idx = blockIdx.x*256 + threadIdx.x;
  if (idx < EE){
    int r = row[idx], c = col[idx];
    int pos = indptr[c] + atomicAdd(&fillc[c], 1);
    csr_r[pos] = r;
    unsigned rkey = (unsigned)c*50000u + (unsigned)r;
    unsigned h = (rkey*2654435761u) >> (32-HASH_BITS);
    for(;;){
      unsigned kk = tab[h].x;
      if (kk==rkey){ atomicAdd(&diagint[r], (int)tab[h].y); break; }
      if (kk==HEMPTY) break;
      h = (h+1)&HASH_MASK;
    }
  } else {
    int i = idx - EE;
    if (i < NN){
      int mv = scal[1] ? (int)((const unsigned char*)mp)[i] : ((const int*)mp)[i];
      if (mv){ int p = (int)atomicAdd(&scal[0], 1u); mlist[p] = i; minv[i] = p; }
    }
  }
}

// ---------------- remaining matmul (up-GCN input) ----------------
__global__ void k_mm64v(const float* __restrict__ X, const float* __restrict__ W, float* __restrict__ Y){
  int idx = blockIdx.x*256 + threadIdx.x;
  if (idx >= NN*16) return;
  int i = idx>>4, fq = idx&15;
  const vf4* X4 = (const vf4*)&X[i*64];
  const vf4* W4 = (const vf4*)W;
  vf4 acc = {0.f,0.f,0.f,0.f};
  #pragma unroll
  for (int kq=0;kq<16;kq++){
    vf4 xv = X4[kq];
    #pragma unroll
    for (int u=0;u<4;u++) acc += xv[u] * W4[(kq*4+u)*16+fq];
  }
  ((vf4*)Y)[i*16+fq] = acc;
}

// ---------------- CSR gather GCN kernels (wave per node, shuffle-pipelined) ----------------
__global__ void g_gcn0(const int* __restrict__ indptr, const int* __restrict__ csr_r,
                       const float* __restrict__ dinv, const float* __restrict__ H,
                       const float* __restrict__ b, const float* __restrict__ pw,
                       float* __restrict__ out, unsigned long long* __restrict__ keys,
                       float* __restrict__ score, unsigned* __restrict__ hist){
  int node = blockIdx.x*4 + (threadIdx.x>>6), lane = threadIdx.x&63;
  if (node >= NN) return;
  int s = __builtin_amdgcn_readfirstlane(indptr[node]);
  int e = __builtin_amdgcn_readfirstlane(indptr[node+1]);
  int deg = e - s;
  float a0=0.f,a1=0.f,a2=0.f,a3=0.f;
  for (int base=0; base<deg; base+=64){
    int take = min(64, deg-base);
    bool act = lane < take;
    int ii = act ? csr_r[s+base+lane] : 0;
    float dv = act ? dinv[ii] : 0.f;
    int j=0;
    for (; j+4<=take; j+=4){
      int r0=__shfl(ii,j,64), r1=__shfl(ii,j+1,64), r2=__shfl(ii,j+2,64), r3=__shfl(ii,j+3,64);
      float d0=__shfl(dv,j,64), d1=__shfl(dv,j+1,64), d2=__shfl(dv,j+2,64), d3=__shfl(dv,j+3,64);
      a0 += d0*H[(size_t)r0*64+lane];
      a1 += d1*H[(size_t)r1*64+lane];
      a2 += d2*H[(size_t)r2*64+lane];
      a3 += d3*H[(size_t)r3*64+lane];
    }
    for (; j<take; j++){
      int r0=__shfl(ii,j,64); float d0=__shfl(dv,j,64);
      a0 += d0*H[(size_t)r0*64+lane];
    }
  }
  float acc = (a0+a1)+(a2+a3);
  float di = dinv[node];
  float v = di*acc + 2.f*di*di*H[(size_t)node*64+lane] + b[lane];
  float x1v = fmaxf(v, 0.f);
  out[(size_t)node*64+lane] = x1v;
  // fused TopK score: s = tanh((x1 . pw)/||pw||)
  float pv = pw[lane];
  float nq = pv*pv;
  float dq = x1v*pv;
  for (int o=32;o;o>>=1){ nq += __shfl_down(nq, o, 64); dq += __shfl_down(dq, o, 64); }
  if (lane==0){
    float sv = tanhf(dq / sqrtf(nq));
    sv = sv + 0.0f;               // canonicalize -0 -> +0
    score[node] = sv;
    unsigned u = __float_as_uint(sv);
    unsigned asc = (u>>31) ? ~u : (u | 0x80000000u);
    unsigned desc = ~asc;
    keys[node] = (((unsigned long long)desc)<<32) | (unsigned)node;
    atomicAdd(&hist[desc>>16], 1u);      // radix round-0 histogram
  }
}
__global__ void g_t2(const int* __restrict__ indptr, const int* __restrict__ csr_r,
                     const float* __restrict__ dinv1, const float* __restrict__ hp,
                     float* __restrict__ t2){
  int node = blockIdx.x*4 + (threadIdx.x>>6), lane = threadIdx.x&63;
  if (node >= NN) return;
  int s = __builtin_amdgcn_readfirstlane(indptr[node]);
  int e = __builtin_amdgcn_readfirstlane(indptr[node+1]);
  int deg = e - s;
  float a0 = dinv1[node]*hp[(size_t)node*64+lane];   // self loop
  float a1 = 0.f;
  for (int base=0; base<deg; base+=64){
    int take = min(64, deg-base);
    bool act = lane < take;
    int ii = act ? csr_r[s+base+lane] : 0;
    float dv = act ? dinv1[ii] : 0.f;
    int j=0;
    for (; j+2<=take; j+=2){
      float d0=__shfl(dv,j,64), d1=__shfl(dv,j+1,64);
      int r0=__shfl(ii,j,64), r1=__shfl(ii,j+1,64);
      if (d0!=0.f) a0 += d0*hp[(size_t)r0*64+lane];
      if (d1!=0.f) a1 += d1*hp[(size_t)r1*64+lane];
    }
    for (; j<take; j++){
      float d0=__shfl(dv,j,64); int r0=__shfl(ii,j,64);
      if (d0!=0.f) a0 += d0*hp[(size_t)r0*64+lane];
    }
  }
  t2[(size_t)node*64+lane] = a0+a1;
}
// D[i] = (masked ? H0[minv[i]] : C[i]) + (kept ? relu(x2_i) : 0)
__global__ void g_agg2y(const int* __restrict__ indptr, const int* __restrict__ csr_r,
                        const float* __restrict__ t2, const float* __restrict__ hp,
                        const float* __restrict__ dinv1, const int* __restrict__ diagint,
                        const int* __restrict__ kp, const float* __restrict__ b1,
                        const float* __restrict__ C, const float* __restrict__ Hbuf,
                        const int* __restrict__ minv, float* __restrict__ D){
  int node = blockIdx.x*4 + (threadIdx.x>>6), lane = threadIdx.x&63;
  if (node >= NN) return;
  int mv = minv[node];
  float base = (mv >= 0) ? Hbuf[(size_t)mv*64+lane] : C[(size_t)node*64+lane];
  float add = 0.f;
  if (kp[node]){
    int s = __builtin_amdgcn_readfirstlane(indptr[node]);
    int e = __builtin_amdgcn_readfirstlane(indptr[node+1]);
    int deg = e - s;
    float a0 = t2[(size_t)node*64+lane];             // self loop
    float a1=0.f,a2=0.f,a3=0.f;
    for (int bs2=0; bs2<deg; bs2+=64){
      int take = min(64, deg-bs2);
      bool act = lane < take;
      int ii = act ? csr_r[s+bs2+lane] : 0;
      int j=0;
      for (; j+4<=take; j+=4){
        int r0=__shfl(ii,j,64), r1=__shfl(ii,j+1,64), r2=__shfl(ii,j+2,64), r3=__shfl(ii,j+3,64);
        a0 += t2[(size_t)r0*64+lane];
        a1 += t2[(size_t)r1*64+lane];
        a2 += t2[(size_t)r2*64+lane];
        a3 += t2[(size_t)r3*64+lane];
      }
      for (; j<take; j++){
        int r0=__shfl(ii,j,64);
        a0 += t2[(size_t)r0*64+lane];
      }
    }
    float acc = (a0+a1)+(a2+a3);
    float di = dinv1[node], hv = hp[(size_t)node*64+lane];
    float diag = (float)(diagint[node] + 1);
    float v = di*(acc - diag*di*hv) + 2.f*di*di*hv + b1[lane];
    add = fmaxf(v, 0.f);
  }
  D[(size_t)node*64+lane] = base + add;
}
__global__ void g_up(const int* __restrict__ indptr, const int* __restrict__ csr_r,
                     const float* __restrict__ dinv, const float* __restrict__ H,
                     const float* __restrict__ b, float* __restrict__ xo, float* __restrict__ out){
  int node = blockIdx.x*4 + (threadIdx.x>>6), lane = threadIdx.x&63;
  if (node >= NN) return;
  int s = __builtin_amdgcn_readfirstlane(indptr[node]);
  int e = __builtin_amdgcn_readfirstlane(indptr[node+1]);
  int deg = e - s;
  float a0=0.f,a1=0.f,a2=0.f,a3=0.f;
  for (int base=0; base<deg; base+=64){
    int take = min(64, deg-base);
    bool act = lane < take;
    int ii = act ? csr_r[s+base+lane] : 0;
    float dv = act ? dinv[ii] : 0.f;
    int j=0;
    for (; j+4<=take; j+=4){
      int r0=__shfl(ii,j,64), r1=__shfl(ii,j+1,64), r2=__shfl(ii,j+2,64), r3=__shfl(ii,j+3,64);
      float d0=__shfl(dv,j,64), d1=__shfl(dv,j+1,64), d2=__shfl(dv,j+2,64), d3=__shfl(dv,j+3,64);
      a0 += d0*H[(size_t)r0*64+lane];
      a1 += d1*H[(size_t)r1*64+lane];
      a2 += d2*H[(size_t)r2*64+lane];
      a3 += d3*H[(size_t)r3*64+lane];
    }
    for (; j<take; j++){
      int r0=__shfl(ii,j,64); float d0=__shfl(dv,j,64);
      a0 += d0*H[(size_t)r0*64+lane];
    }
  }
  float acc = (a0+a1)+(a2+a3);
  float di = dinv[node];
  float v = di*acc + 2.f*di*di*H[(size_t)node*64+lane] + b[lane];
  xo[(size_t)node*64+lane] = v; out[(size_t)node*64+lane] = v;
}

// ---------------- TopK radix select (round 0 hist fused into g_gcn0) ----------------
__global__ void k_hist(const unsigned long long* __restrict__ keys, unsigned* __restrict__ hist,
                       const unsigned long long* __restrict__ selp, int round){
  int i = blockIdx.x*256 + threadIdx.x;
  if (i >= NN) return;
  unsigned long long key = keys[i];
  int shift = 48 - 16*round;
  if ((key>>(shift+16)) == selp[0])
    atomicAdd(&hist[(unsigned)((key>>shift)&0xFFFFull)], 1u);
}
__global__ void k_pick(const unsigned* __restrict__ hist, unsigned long long* selp, unsigned* scal){
  __shared__ unsigned csum[256];
  __shared__ unsigned bins[256];
  __shared__ int schunk;
  int t = threadIdx.x;
  const uint4* h4 = (const uint4*)(hist + t*256);
  unsigned s = 0;
  #pragma unroll 8
  for (int j=0;j<64;j++){ uint4 v = h4[j]; s += v.x+v.y+v.z+v.w; }
  csum[t] = s;
  __syncthreads();
  if (t==0){
    unsigned rem = scal[3];
    int chunk = 255;
    for (int c2=0;c2<256;c2++){ unsigned cc=csum[c2]; if (rem>cc) rem-=cc; else { chunk=c2; break; } }
    schunk = chunk; scal[3] = rem;
  }
  __syncthreads();
  bins[t] = hist[schunk*256 + t];
  __syncthreads();
  if (t==0){
    unsigned rem = scal[3];
    int bin = schunk*256 + 255;
    for (int b=0;b<256;b++){ unsigned hv=bins[b]; if (rem>hv) rem-=hv; else { bin = schunk*256 + b; break; } }
    selp[0] = (selp[0]<<16) | (unsigned long long)(unsigned)bin;
    scal[3] = rem;
  }
}
// pooled degree pass 1 (CSR gather): kp[i]; ts[i] = sum_{r->i} kp[r] + kp[i]
__global__ void k_tsg(const int* __restrict__ indptr, const int* __restrict__ csr_r,
                      const unsigned long long* __restrict__ keys,
                      const unsigned long long* __restrict__ selp,
                      int* __restrict__ kp, int* __restrict__ ts){
  int i = blockIdx.x*256 + threadIdx.x;
  if (i >= NN) return;
  unsigned long long sp = selp[0];
  int s = indptr[i], e = indptr[i+1];
  int self = (keys[i] <= sp) ? 1 : 0;
  kp[i] = self;
  int acc = self;
  for (int j=s;j<e;j++) acc += (keys[csr_r[j]] <= sp) ? 1 : 0;
  ts[i] = acc;
}
// pooled degree pass 2 + dinv1 MERGED with hp = (x1*score)@W1 (both depend only on tsg)
__global__ void k_csgmm(const int* __restrict__ indptr, const int* __restrict__ csr_r,
                        const int* __restrict__ ts, const int* __restrict__ diagint,
                        const int* __restrict__ kp, float* __restrict__ dinv1,
                        const float* __restrict__ X, const float* __restrict__ W,
                        const float* __restrict__ sc, float* __restrict__ Y){
  int idx = blockIdx.x*256 + threadIdx.x;
  if (idx < NN*16){
    int i = idx>>4, fq = idx&15;
    if (!kp[i]) return;
    const vf4* X4 = (const vf4*)&X[i*64];
    const vf4* W4 = (const vf4*)W;
    vf4 acc = {0.f,0.f,0.f,0.f};
    #pragma unroll
    for (int kq=0;kq<16;kq++){
      vf4 xv = X4[kq];
      #pragma unroll
      for (int u=0;u<4;u++) acc += xv[u] * W4[(kq*4+u)*16+fq];
    }
    acc *= sc[i];
    ((vf4*)Y)[i*16+fq] = acc;
  } else {
    int i = idx - NN*16;
    if (i >= NN) return;
    int s = indptr[i], e = indptr[i+1];
    int acc = ts[i];
    for (int j=s;j<e;j++) acc += ts[csr_r[j]];
    dinv1[i] = kp[i] ? rsqrtf((float)(acc - diagint[i] - 1) + 2.0f) : 0.f;
  }
}

// ---------------- LSTM part 1: XW[n] = src[n] @ W_ih^T + (b_ih+b_hh) ----------------
__global__ __launch_bounds__(256) void k_xw(const float* __restrict__ src,
        const float* __restrict__ WT, const float* __restrict__ bsum,
        float* __restrict__ XW){
  __shared__ vf4 Wl[4096];              // 64 KB: WT[k][g] as vf4[(k*4+u)*64+fq]
  int t = threadIdx.x;
  const vf4* Wg = (const vf4*)WT;
  for (int u=t; u<4096; u+=256) Wl[u] = Wg[u];
  int fq = t & 63, wv = t >> 6;
  vf4 bias = ((const vf4*)bsum)[fq];
  __syncthreads();
  for (int g = blockIdx.x*4 + wv; g < NN/4; g += gridDim.x*4){
    int n0 = g*4;
    const vf4* X4 = (const vf4*)&src[(size_t)n0*64];   // 4 rows x 16 vf4
    vf4 a0=bias, a1=bias, a2=bias, a3=bias;
    #pragma unroll 4
    for (int kq=0;kq<16;kq++){
      vf4 x0 = X4[kq], x1 = X4[16+kq], x2 = X4[32+kq], x3 = X4[48+kq];
      vf4 w0 = Wl[(kq*4+0)*64+fq];
      vf4 w1 = Wl[(kq*4+1)*64+fq];
      vf4 w2 = Wl[(kq*4+2)*64+fq];
      vf4 w3 = Wl[(kq*4+3)*64+fq];
      a0 += x0.x*w0 + x0.y*w1 + x0.z*w2 + x0.w*w3;
      a1 += x1.x*w0 + x1.y*w1 + x1.z*w2 + x1.w*w3;
      a2 += x2.x*w0 + x2.y*w1 + x2.z*w2 + x2.w*w3;
      a3 += x3.x*w0 + x3.y*w1 + x3.z*w2 + x3.w*w3;
    }
    vf4* Y = (vf4*)XW;
    Y[(size_t)n0*64 + fq]       = a0;
    Y[(size_t)n0*64 + 64 + fq]  = a1;
    Y[(size_t)n0*64 + 128 + fq] = a2;
    Y[(size_t)n0*64 + 192 + fq] = a3;
  }
}

// ---------------- LSTM part 2: recurrence (hh-half only) ----------------
// R7-proven config: 4 nodes/block, grid 1024, per-wave XW-row prefetch.
// (R8 grid=2048 and R9 8-node variants both regressed — register/occupancy
// cliff; 3 waves/SIMD is the AGPR-demoted weights' limit.)
__global__ __launch_bounds__(256) void k_rec(const float* __restrict__ XW,
        const float* __restrict__ whh, const float* __restrict__ bsum,
        const int* __restrict__ mlist, const unsigned* __restrict__ scal,
        float* __restrict__ dst, int scatter){
  int M = (int)scal[0];
  if (M < 0 || M > NN) M = 0;          // defensive (rocprof replay poisons scal)
  int w = threadIdx.x>>6, lane = threadIdx.x&63;
  int r = w*64 + lane;
  const vf4* g4 = (const vf4*)&whh[(size_t)r*64];
  vf4 wh[16];
  #pragma unroll
  for (int j=0;j<16;j++) wh[j] = g4[j];
  __shared__ float sh[4][64];
  __shared__ float gates[4][4][64];
  int ntask = (M+3)>>2;
  for (int task = blockIdx.x; task < ntask; task += gridDim.x){
    int m = task*4 + w;
    bool valid = (m < M);
    int node = mlist[valid ? m : (M-1)];
    node = min(max(node, 0), NN-1);    // defensive vs poisoned mlist in replay
    float c, h;
    float x0,x1,x2,x3;
    {   // t = 0: h==0, gates = XW row (bias-only if left-padded)
      int rowi = node - (SEQL-1);
      if (rowi >= 0){
        const float* p = &XW[(size_t)rowi*256];
        x0=p[lane]; x1=p[64+lane]; x2=p[128+lane]; x3=p[192+lane];
      } else {
        x0=bsum[lane]; x1=bsum[64+lane]; x2=bsum[128+lane]; x3=bsum[192+lane];
      }
      c = sigm(x0)*ftanh(x2);
      h = sigm(x3)*ftanh(c);
      sh[w][lane] = h;
    }
    __syncthreads();
    for (int t=1;t<SEQL;t++){
      // prefetch this timestep's gate-x row (wave w -> its own node)
      int rowi = node - (SEQL-1) + t;
      if (rowi >= 0){
        const float* p = &XW[(size_t)rowi*256];
        x0=p[lane]; x1=p[64+lane]; x2=p[128+lane]; x3=p[192+lane];
      } else {
        x0=bsum[lane]; x1=bsum[64+lane]; x2=bsum[128+lane]; x3=bsum[192+lane];
      }
      vf4 a0={0,0,0,0}, a1={0,0,0,0}, a2={0,0,0,0}, a3={0,0,0,0};
      #pragma unroll
      for (int j=0;j<16;j++){
        vf4 wj = wh[j];
        a0 += (*(const vf4*)&sh[0][j*4]) * wj;
        a1 += (*(const vf4*)&sh[1][j*4]) * wj;
        a2 += (*(const vf4*)&sh[2][j*4]) * wj;
        a3 += (*(const vf4*)&sh[3][j*4]) * wj;
      }
      gates[0][w][lane] = a0.x+a0.y+a0.z+a0.w;
      gates[1][w][lane] = a1.x+a1.y+a1.z+a1.w;
      gates[2][w][lane] = a2.x+a2.y+a2.z+a2.w;
      gates[3][w][lane] = a3.x+a3.y+a3.z+a3.w;
      __syncthreads();
      float gi = gates[w][0][lane] + x0;
      float gf = gates[w][1][lane] + x1;
      float gg = gates[w][2][lane] + x2;
      float go = gates[w][3][lane] + x3;
      c = sigm(gf)*c + sigm(gi)*ftanh(gg);
      h = sigm(go)*ftanh(c);
      sh[w][lane] = h;
      __syncthreads();
    }
    if (valid){
      size_t o = scatter ? ((size_t)node*64 + lane) : ((size_t)m*64 + lane);
      dst[o] = h;
    }
  }
}

// ==========================================================================
extern "C" void kernel_launch(void* const* d_in, const int* in_sizes, int n_in,
                              void* d_out, int out_size, void* d_ws, size_t ws_size,
                              hipStream_t stream) {
  const float* x   = (const float*)d_in[0];
  const int*   ei  = (const int*)d_in[1];
  const int*   row = ei;
  const int*   col = ei + EE;
  const void*  mp  = d_in[2];
  const float* W0  = (const float*)d_in[3];
  const float* b0  = (const float*)d_in[4];
  const float* W1  = (const float*)d_in[5];
  const float* b1  = (const float*)d_in[6];
  const float* pw  = (const float*)d_in[7];
  const float* Wu  = (const float*)d_in[8];
  const float* bu  = (const float*)d_in[9];
  const float* l0wih=(const float*)d_in[10];
  const float* l0whh=(const float*)d_in[11];
  const float* l0bih=(const float*)d_in[12];
  const float* l0bhh=(const float*)d_in[13];
  const float* lfwih=(const float*)d_in[14];
  const float* lfwhh=(const float*)d_in[15];
  const float* lfbih=(const float*)d_in[16];
  const float* lfbhh=(const float*)d_in[17];

  char* wp = (char*)d_ws;
  auto alloc = [&](size_t bytes)->char*{ char* p = wp; wp += ((bytes+255)/256)*256; return p; };
  float* A     = (float*)alloc((size_t)NN*64*4);   // h0 -> t2
  float* B     = (float*)alloc((size_t)NN*64*4);   // xo
  float* C     = (float*)alloc((size_t)NN*64*4);   // x1
  float* D     = (float*)alloc((size_t)NN*64*4);   // y
  float* Ebuf  = (float*)alloc((size_t)NN*64*4);   // hp -> up-GCN input
  float* Hbuf  = (float*)alloc((size_t)NN*64*4);   // LSTM0 compact output
  float* XW    = (float*)alloc((size_t)NN*256*4);  // gate-x precompute (51.2 MB)
  float* WT0   = (float*)alloc((size_t)256*64*4);
  float* WTf   = (float*)alloc((size_t)256*64*4);
  float* bs0   = (float*)alloc((size_t)256*4);
  float* bsf   = (float*)alloc((size_t)256*4);
  float* score = (float*)alloc((size_t)NN*4);
  float* dinv0 = (float*)alloc((size_t)NN*4);
  float* dinv1 = (float*)alloc((size_t)NN*4);
  unsigned long long* keys = (unsigned long long*)alloc((size_t)NN*8);
  int* degcnt  = (int*)alloc((size_t)NN*4);
  int* diagint = (int*)alloc((size_t)NN*4);
  int* ts      = (int*)alloc((size_t)NN*4);
  int* kp      = (int*)alloc((size_t)NN*4);
  int* mlist   = (int*)alloc((size_t)NN*4);
  int* minv    = (int*)alloc((size_t)NN*4);
  int* indptr  = (int*)alloc((size_t)(NN+1)*4);
  int* part    = (int*)alloc((size_t)NN*4);
  int* fillc   = (int*)alloc((size_t)NN*4);
  int* bsum    = (int*)alloc((size_t)256*4);
  int* csr_r   = (int*)alloc((size_t)EE*4);
  uint2* hash  = (uint2*)alloc((size_t)HASH_SIZE*8);
  unsigned* hist=(unsigned*)alloc((size_t)4*65536*4);
  unsigned* scal=(unsigned*)alloc(256);
  unsigned long long* selp = (unsigned long long*)(scal + 4);

  #define GRID1(n) dim3(((n)+255)/256), dim3(256), 0, stream
  #define GRIDW dim3((NN+3)/4), dim3(256), 0, stream

  // 1. merged init (hash, hist, per-node arrays, scalars, LSTM weight prep)
  k_init<<<GRID1(HASH_SIZE)>>>(hash, hist, degcnt, diagint, fillc, minv,
                               scal, selp, l0wih, l0bih, l0bhh, lfwih, lfbih, lfbhh,
                               WT0, WTf, bs0, bsf);
  // 2. degcnt + hash build + mask detect + GCN0 matmul (merged)
  k_phase2<<<GRID1(NN*16)>>>(row, col, (const int*)mp, degcnt, hash, scal, x, W0, A);
  // 3-4. indptr prefix sum (+dinv0); psum3 self-computes block offsets
  k_psum1<<<dim3(PSB),dim3(256),0,stream>>>(degcnt, part, bsum, dinv0);
  k_psum3<<<dim3(PSB),dim3(256),0,stream>>>(part, bsum, indptr);
  // 5. csr fill + A^2 diag + mask compact
  k_phase4<<<GRID1(EE+NN)>>>(row, col, indptr, fillc, csr_r, hash, diagint, mp, scal, mlist, minv);

  // GCN0 gather (+ fused TopK score/key + radix round-0 hist)
  g_gcn0<<<GRIDW>>>(indptr, csr_r, dinv0, A, b0, pw, C, keys, score, hist);

  // TopK radix select (round-0 hist already done)
  k_pick<<<dim3(1),dim3(256),0,stream>>>(hist, selp, scal);
  for (int r2=1;r2<4;r2++){
    k_hist<<<GRID1(NN)>>>(keys, hist + r2*65536, selp, r2);
    k_pick<<<dim3(1),dim3(256),0,stream>>>(hist + r2*65536, selp, scal);
  }
  // pooled degree pass 1, then pass2+dinv1 merged with hp matmul
  k_tsg<<<GRID1(NN)>>>(indptr, csr_r, keys, selp, kp, ts);
  k_csgmm<<<GRID1(NN*16+NN)>>>(indptr, csr_r, ts, diagint, kp, dinv1, C, W1, score, Ebuf);
  g_t2<<<GRIDW>>>(indptr, csr_r, dinv1, Ebuf, A);

  // LSTM0 on x1 windows -> Hbuf (compact)
  k_xw<<<dim3(512),dim3(256),0,stream>>>(C, WT0, bs0, XW);
  k_rec<<<dim3(1024),dim3(256),0,stream>>>(XW, l0whh, bs0, mlist, scal, Hbuf, 0);

  // y = res + up (fused: base select + relu(x2))
  g_agg2y<<<GRIDW>>>(indptr, csr_r, A, Ebuf, dinv1, diagint, kp, b1, C, Hbuf, minv, D);

  // up-GCN -> xo (B) and d_out
  k_mm64v<<<GRID1(NN*16)>>>(D, Wu, Ebuf);
  g_up<<<GRIDW>>>(indptr, csr_r, dinv0, Ebuf, bu, B, (float*)d_out);

  // final LSTM on xo windows, scatter into d_out masked rows
  k_xw<<<dim3(512),dim3(256),0,stream>>>(B, WTf, bsf, XW);
  k_rec<<<dim3(1024),dim3(256),0,stream>>>(XW, lfwhh, bsf, mlist, scal, (float*)d_out, 1);
  #undef GRIDW
  #undef GRID1
}